// Round 1
// baseline (1592.305 us; speedup 1.0000x reference)
//
#include <hip/hip_runtime.h>
#include <hip/hip_bf16.h>

#define N_NODES 100000
#define N_EDGES 400000
#define F_NODE_ 64
#define F_EDGE_ 16
#define HID_ 128
#define N_GRAPH 1024
#define N_TASK 5

typedef unsigned short u16;
typedef __attribute__((ext_vector_type(8))) short frag8;   // 8 bf16 = 4 VGPRs
typedef __attribute__((ext_vector_type(4))) float f32x4;   // MFMA C/D
typedef __attribute__((ext_vector_type(2))) float f32x2;

__device__ __forceinline__ float bu2f(u16 v){ return __uint_as_float(((unsigned)v) << 16); }
__device__ __forceinline__ float2 bp2f(unsigned u){
  return make_float2(__uint_as_float(u << 16), __uint_as_float(u & 0xFFFF0000u));
}
__device__ __forceinline__ f32x2 bp2v(unsigned u){
  f32x2 r; r.x = __uint_as_float(u << 16); r.y = __uint_as_float(u & 0xFFFF0000u); return r;
}
__device__ __forceinline__ u16 f2bu(float f){
  __hip_bfloat16 h = __float2bfloat16(f);
  return *(u16*)&h;
}
__device__ __forceinline__ unsigned packbf(float a, float b){
  return (unsigned)f2bu(a) | ((unsigned)f2bu(b) << 16);
}

// ---------------- cast f32 -> bf16 fused with edge histogram + graph offsets ----------------
#define CAST_BLKS ((N_NODES*F_NODE_ + 255)/256)
#define EG256 ((N_EDGES + 255)/256)
#define GOFF_BLKS ((N_GRAPH + 1 + 255)/256)
__global__ __launch_bounds__(256) void k_cast_hist(const float* __restrict__ s, u16* __restrict__ d,
                                                   const int* __restrict__ ei, int* __restrict__ counts,
                                                   const int* __restrict__ batch, int* __restrict__ goff){
  int b = blockIdx.x;
  if (b < CAST_BLKS){
    int i = b*256 + threadIdx.x;
    if (i < N_NODES*F_NODE_) d[i] = f2bu(s[i]);
  } else if (b < CAST_BLKS + EG256){
    int e = (b - CAST_BLKS)*256 + threadIdx.x;
    if (e < N_EDGES) atomicAdd(&counts[ei[N_EDGES + e]], 1);
  } else {
    // graph offsets via binary search on sorted batch (was a serial single-block job)
    int g = (b - CAST_BLKS - EG256)*256 + threadIdx.x;
    if (g <= N_GRAPH){
      int lo = 0, hi = N_NODES;
      while (lo < hi){
        int mid = (lo + hi) >> 1;
        if (batch[mid] < g) lo = mid + 1; else hi = mid;
      }
      goff[g] = lo;
    }
  }
}

// ---------------- batched pre-swizzle: 8 W (K=64/128) ----------------
struct WZ8 { const float* src[8]; u16* dst[8]; int Ks[8]; int Kd[8]; };
__global__ __launch_bounds__(256) void k_wswz_all(WZ8 p){
  const int s = blockIdx.y;
  const int Kd = p.Kd[s], Ks = p.Ks[s];
  int i = blockIdx.x*256 + threadIdx.x;
  if (i >= Kd*128) return;
  int k = i >> 7, n = i & 127;
  float v = (k < Ks) ? p.src[s][k*128 + n] : 0.f;
  int kk = k & 31, c = k >> 5;
  int quad = kk >> 3, j = kk & 7;
  int nt = n >> 4;
  int lane = quad*16 + (n & 15);
  p.dst[s][(((c*8 + nt)*64) + lane)*8 + j] = f2bu(v);
}

// ---------------- paired MFMA GEMMs (xl, xr) ----------------
#define GEMM_GRID ((N_NODES + 127)/128)   // 782
__global__ __launch_bounds__(256) void k_gemm2(const u16* __restrict__ A,
                                               const u16* __restrict__ Wzl,
                                               const u16* __restrict__ Wzr,
                                               const float* __restrict__ bl,
                                               const float* __restrict__ br,
                                               u16* __restrict__ Cl,
                                               u16* Cr,
                                               int M, int K){
  __shared__ u16 WS[128*128];
  const int t = threadIdx.x;
  const int b = blockIdx.x;
  const int which = (b >= GEMM_GRID);
  const int bx = which ? b - GEMM_GRID : b;
  const u16*   Wz   = which ? Wzr : Wzl;
  const float* bias = which ? br  : bl;
  u16*         C    = which ? Cr  : Cl;
  {
    const uint4* src = (const uint4*)Wz;
    uint4* dst = (uint4*)WS;
    const int n = (K*128) >> 3;
    for (int i = t; i < n; i += 256) dst[i] = src[i];
  }
  __syncthreads();
  const int w = t >> 6, l = t & 63;
  const int m = l & 15, quad = l >> 4;
  const int rowA0 = bx*128 + w*32 + m;
  const int rowA1 = rowA0 + 16;
  f32x4 acc[2][8];
  #pragma unroll
  for (int i=0;i<2;i++)
    #pragma unroll
    for (int j=0;j<8;j++) acc[i][j] = (f32x4){0.f,0.f,0.f,0.f};
  const int KC = K >> 5;
  for (int c = 0; c < KC; c++){
    frag8 a0 = {}, a1 = {};
    if (rowA0 < M) a0 = *(const frag8*)(A + (size_t)rowA0*K + c*32 + quad*8);
    if (rowA1 < M) a1 = *(const frag8*)(A + (size_t)rowA1*K + c*32 + quad*8);
    #pragma unroll
    for (int nt = 0; nt < 8; nt++){
      frag8 bfr = *(const frag8*)&WS[(((c*8 + nt)*64) + l)*8];
      acc[0][nt] = __builtin_amdgcn_mfma_f32_16x16x32_bf16(a0, bfr, acc[0][nt], 0,0,0);
      acc[1][nt] = __builtin_amdgcn_mfma_f32_16x16x32_bf16(a1, bfr, acc[1][nt], 0,0,0);
    }
  }
  #pragma unroll
  for (int rt = 0; rt < 2; rt++){
    int rbase = bx*128 + w*32 + rt*16 + quad*4;
    #pragma unroll
    for (int nt = 0; nt < 8; nt++){
      int col = nt*16 + m;
      float bc = bias[col];
      #pragma unroll
      for (int r = 0; r < 4; r++){
        int row = rbase + r;
        if (row < M) C[(size_t)row*128 + col] = f2bu(acc[rt][nt][r] + bc);
      }
    }
  }
}

__global__ __launch_bounds__(512) void k_scan1(const int* __restrict__ counts,
                                               int* __restrict__ incl,
                                               int* __restrict__ bsum){
  __shared__ int s[512];
  const int t = threadIdx.x;
  int i = blockIdx.x*512 + t;
  int v = (i < N_NODES) ? counts[i] : 0;
  s[t] = v;
  __syncthreads();
  for (int off = 1; off < 512; off <<= 1){
    int x = (t >= off) ? s[t - off] : 0;
    __syncthreads();
    s[t] += x;
    __syncthreads();
  }
  if (i < N_NODES) incl[i] = s[t];
  if (t == 511) bsum[blockIdx.x] = s[511];
}

// scan of block sums only (goff moved to k_cast_hist)
__global__ __launch_bounds__(256) void k_scan2(int* __restrict__ bsum, int nb){
  __shared__ int s[256];
  const int t = threadIdx.x;
  int v = (t < nb) ? bsum[t] : 0;
  s[t] = v;
  __syncthreads();
  for (int off = 1; off < 256; off <<= 1){
    int x = (t >= off) ? s[t - off] : 0;
    __syncthreads();
    s[t] += x;
    __syncthreads();
  }
  if (t < nb) bsum[t] = s[t] - v;
}

__global__ __launch_bounds__(512) void k_scan3(const int* __restrict__ counts,
                                               const int* __restrict__ incl,
                                               const int* __restrict__ bsum,
                                               int* __restrict__ offsets,
                                               int* __restrict__ cursor){
  int i = blockIdx.x*512 + threadIdx.x;
  if (i >= N_NODES) return;
  int o = bsum[blockIdx.x] + incl[i];
  offsets[i + 1] = o;
  cursor[i]      = o - counts[i];
  if (i == 0) offsets[0] = 0;
}

// scatter: src index + bf16 edge features into CSR order ([E][16] bf16, no pad)
__global__ __launch_bounds__(256) void k_scatter(const int* __restrict__ ei,
                                                 int* __restrict__ cursor,
                                                 int* __restrict__ ssrc,
                                                 const float* __restrict__ ea,
                                                 u16* __restrict__ ea16){
  int e = blockIdx.x*256 + threadIdx.x;
  if (e >= N_EDGES) return;
  int dst = ei[N_EDGES + e];
  int pos = atomicAdd(&cursor[dst], 1);
  ssrc[pos] = ei[e];
  const float* s = ea + (size_t)e*F_EDGE_;
  unsigned p[8];
  #pragma unroll
  for (int k=0;k<8;k++) p[k] = packbf(s[2*k], s[2*k+1]);
  uint4* d4 = (uint4*)(ea16 + (size_t)pos*16);
  d4[0] = make_uint4(p[0],p[1],p[2],p[3]);
  d4[1] = make_uint4(p[4],p[5],p[6],p[7]);
}

// ---------------- Fused GAT v11: ee computed on the fly (rank-16, wave-uniform edge) ----------------
// Per lane: ee[c0:c0+2] = sum_k ea[e][k] * We[k][c0:c0+2]; We slice held in 32 VGPRs (f32, exact).
__device__ __forceinline__ f32x2 eeval(uint4 a, uint4 b, const f32x2* we){
  f32x2 acc = {0.f, 0.f};
  f32x2 p;
  p = bp2v(a.x); acc += p.x*we[0];  acc += p.y*we[1];
  p = bp2v(a.y); acc += p.x*we[2];  acc += p.y*we[3];
  p = bp2v(a.z); acc += p.x*we[4];  acc += p.y*we[5];
  p = bp2v(a.w); acc += p.x*we[6];  acc += p.y*we[7];
  p = bp2v(b.x); acc += p.x*we[8];  acc += p.y*we[9];
  p = bp2v(b.y); acc += p.x*we[10]; acc += p.y*we[11];
  p = bp2v(b.z); acc += p.x*we[12]; acc += p.y*we[13];
  p = bp2v(b.w); acc += p.x*we[14]; acc += p.y*we[15];
  return acc;
}

#define GAT_GRID 25000
__global__ __launch_bounds__(256) void k_gat_ep(const u16* __restrict__ xl,
                                                unsigned* xr_aggr,
                                                const u16* __restrict__ ea16,
                                                const float* __restrict__ Wef,
                                                const float* __restrict__ att,
                                                const int* __restrict__ offsets,
                                                const int* __restrict__ ssrc){
  const int t = threadIdx.x;
  const int wave = t >> 6, lane = t & 63;
  const int c0 = lane*2;
  const int node = blockIdx.x*4 + wave;
  if (node >= N_NODES) return;
  const float a0 = att[c0], a1 = att[c0+1];
  f32x2 we[16];
  #pragma unroll
  for (int k=0;k<16;k++){
    float2 wv = *(const float2*)(Wef + k*HID_ + c0);
    we[k].x = wv.x; we[k].y = wv.y;
  }
  const f32x2 xrv = bp2v(xr_aggr[(size_t)node*64 + lane]);
  f32x2 accv = {0.f, 0.f};
  float den = 0.f;
  const int beg = offsets[node], end = offsets[node+1];
  for (int i = beg; i < end; i += 4){
    const int mm = end - i;
    const int i1 = (mm > 1) ? i+1 : i;
    const int i2 = (mm > 2) ? i+2 : i;
    const int i3 = (mm > 3) ? i+3 : i;
    int s0 = ssrc[i], s1 = ssrc[i1], s2 = ssrc[i2], s3 = ssrc[i3];
    uint4 qa0 = *(const uint4*)(ea16 + (size_t)i *16);
    uint4 qb0 = *(const uint4*)(ea16 + (size_t)i *16 + 8);
    uint4 qa1 = *(const uint4*)(ea16 + (size_t)i1*16);
    uint4 qb1 = *(const uint4*)(ea16 + (size_t)i1*16 + 8);
    uint4 qa2 = *(const uint4*)(ea16 + (size_t)i2*16);
    uint4 qb2 = *(const uint4*)(ea16 + (size_t)i2*16 + 8);
    uint4 qa3 = *(const uint4*)(ea16 + (size_t)i3*16);
    uint4 qb3 = *(const uint4*)(ea16 + (size_t)i3*16 + 8);
    f32x2 vl0 = bp2v(*(const unsigned*)(xl + (size_t)s0*HID_ + c0));
    f32x2 vl1 = bp2v(*(const unsigned*)(xl + (size_t)s1*HID_ + c0));
    f32x2 vl2 = bp2v(*(const unsigned*)(xl + (size_t)s2*HID_ + c0));
    f32x2 vl3 = bp2v(*(const unsigned*)(xl + (size_t)s3*HID_ + c0));
    f32x2 v0 = vl0 + xrv + eeval(qa0, qb0, we);
    f32x2 v1 = vl1 + xrv + eeval(qa1, qb1, we);
    f32x2 v2 = vl2 + xrv + eeval(qa2, qb2, we);
    f32x2 v3 = vl3 + xrv + eeval(qa3, qb3, we);
    f32x2 w0 = v0*0.2f, w1 = v1*0.2f, w2 = v2*0.2f, w3 = v3*0.2f;
    v0.x = fmaxf(v0.x,w0.x); v0.y = fmaxf(v0.y,w0.y);
    v1.x = fmaxf(v1.x,w1.x); v1.y = fmaxf(v1.y,w1.y);
    v2.x = fmaxf(v2.x,w2.x); v2.y = fmaxf(v2.y,w2.y);
    v3.x = fmaxf(v3.x,w3.x); v3.y = fmaxf(v3.y,w3.y);
    float sc0 = v0.x*a0 + v0.y*a1;
    float sc1 = v1.x*a0 + v1.y*a1;
    float sc2 = v2.x*a0 + v2.y*a1;
    float sc3 = v3.x*a0 + v3.y*a1;
    sc0 += __shfl_xor(sc0, 1); sc1 += __shfl_xor(sc1, 1); sc2 += __shfl_xor(sc2, 1); sc3 += __shfl_xor(sc3, 1);
    sc0 += __shfl_xor(sc0, 2); sc1 += __shfl_xor(sc1, 2); sc2 += __shfl_xor(sc2, 2); sc3 += __shfl_xor(sc3, 2);
    sc0 += __shfl_xor(sc0, 4); sc1 += __shfl_xor(sc1, 4); sc2 += __shfl_xor(sc2, 4); sc3 += __shfl_xor(sc3, 4);
    sc0 += __shfl_xor(sc0, 8); sc1 += __shfl_xor(sc1, 8); sc2 += __shfl_xor(sc2, 8); sc3 += __shfl_xor(sc3, 8);
    float p0 = __expf(sc0);
    float p1 = (mm > 1) ? __expf(sc1) : 0.f;
    float p2 = (mm > 2) ? __expf(sc2) : 0.f;
    float p3 = (mm > 3) ? __expf(sc3) : 0.f;
    accv += p0*vl0 + p1*vl1 + p2*vl2 + p3*vl3;
    den  += p0 + p1 + p2 + p3;
  }
  float inv = 1.0f / (den + 1e-16f);
  xr_aggr[(size_t)node*64 + lane] = packbf(accv.x*inv, accv.y*inv);
}

// ---------------- BN stats (bf16 aggr input) ----------------
__global__ __launch_bounds__(256) void k_bn_stats(const unsigned* __restrict__ aggr_b,
                                                  float* __restrict__ stats){
  __shared__ float redS[4][128], redQ[4][128];
  const int t = threadIdx.x;
  const int p = t & 63, rg = t >> 6;
  const int c0 = p*2;
  float s0=0.f, s1=0.f, q0=0.f, q1=0.f;
  for (int r = blockIdx.x*4 + rg; r < N_NODES; r += gridDim.x*4){
    float2 v = bp2f(aggr_b[(size_t)r*64 + p]);
    s0 += v.x; s1 += v.y; q0 += v.x*v.x; q1 += v.y*v.y;
  }
  redS[rg][c0] = s0; redS[rg][c0+1] = s1;
  redQ[rg][c0] = q0; redQ[rg][c0+1] = q1;
  __syncthreads();
  if (rg == 0){
    #pragma unroll
    for (int g=1; g<4; g++){
      s0 += redS[g][c0]; s1 += redS[g][c0+1];
      q0 += redQ[g][c0]; q1 += redQ[g][c0+1];
    }
    atomicAdd(&stats[c0],     s0);
    atomicAdd(&stats[c0+1],   s1);
    atomicAdd(&stats[128+c0],   q0);
    atomicAdd(&stats[128+c0+1], q1);
  }
}

// ---------------- BN apply + ELU (+ residual), uint4-vectorized ----------------
__global__ __launch_bounds__(256) void k_bn_apply(const unsigned* __restrict__ aggr_b,
                                                  const float* __restrict__ stats,
                                                  const float* __restrict__ gamma,
                                                  const float* __restrict__ beta,
                                                  u16* __restrict__ h, int residual){
  size_t i = (size_t)blockIdx.x*256 + threadIdx.x;   // uint4-group index (8 channels)
  if (i >= (size_t)N_NODES*16) return;
  const int c = (int)((i & 15) * 8);
  const float invn = 1.0f / (float)N_NODES;
  uint4 v4 = ((const uint4*)aggr_b)[i];
  uint4* hp = (uint4*)h + i;
  uint4 hv4 = make_uint4(0,0,0,0);
  if (residual) hv4 = *hp;
  unsigned vin[4]  = {v4.x, v4.y, v4.z, v4.w};
  unsigned hin[4]  = {hv4.x, hv4.y, hv4.z, hv4.w};
  unsigned outw[4];
  #pragma unroll
  for (int j=0;j<4;j++){
    int cc = c + j*2;
    float mu0  = stats[cc]   * invn,  mu1  = stats[cc+1]   * invn;
    float var0 = stats[128+cc]*invn - mu0*mu0;
    float var1 = stats[129+cc]*invn - mu1*mu1;
    float sc0 = rsqrtf(var0 + 1e-5f) * gamma[cc];
    float sc1 = rsqrtf(var1 + 1e-5f) * gamma[cc+1];
    float2 v = bp2f(vin[j]);
    float val0 = (v.x - mu0) * sc0 + beta[cc];
    float val1 = (v.y - mu1) * sc1 + beta[cc+1];
    val0 = val0 > 0.f ? val0 : expm1f(val0);
    val1 = val1 > 0.f ? val1 : expm1f(val1);
    if (residual){
      float2 hv = bp2f(hin[j]);
      val0 += hv.x; val1 += hv.y;
    }
    outw[j] = packbf(val0, val1);
  }
  *hp = make_uint4(outw[0], outw[1], outw[2], outw[3]);
}

// ---------------- Pool: segmented mean, 4 row-groups in flight ----------------
__global__ __launch_bounds__(256) void k_pool_seg(const unsigned* __restrict__ h2,
                                                  const int* __restrict__ goff,
                                                  float* __restrict__ emb){
  __shared__ float redS[4][128];
  const int g = blockIdx.x, t = threadIdx.x;
  const int p = t & 63, rg = t >> 6;
  const int beg = goff[g], end = goff[g+1];
  float a0 = 0.f, a1 = 0.f;
  for (int r = beg + rg; r < end; r += 4){
    float2 v = bp2f(h2[(size_t)r*64 + p]);
    a0 += v.x; a1 += v.y;
  }
  redS[rg][p*2] = a0; redS[rg][p*2+1] = a1;
  __syncthreads();
  if (rg == 0){
    #pragma unroll
    for (int k=1;k<4;k++){ a0 += redS[k][p*2]; a1 += redS[k][p*2+1]; }
    float n = fmaxf((float)(end - beg), 1.f);
    emb[(size_t)g*HID_ + p*2]     = a0 / n;
    emb[(size_t)g*HID_ + p*2 + 1] = a1 / n;
  }
}

// ---------------- Per-task heads: 8 graphs per block ----------------
#define HG 8
__global__ __launch_bounds__(128) void k_heads(const float* __restrict__ emb,
                                               const float* __restrict__ mf,
                                               const int* __restrict__ fpi,
                                               const float* __restrict__ tw1,
                                               const float* __restrict__ tb1,
                                               const float* __restrict__ tw2,
                                               const float* __restrict__ tb2,
                                               float* __restrict__ out){
  const int task = blockIdx.y, g0 = blockIdx.x*HG;
  const int j = threadIdx.x;
  __shared__ float fused[HG][160];
  __shared__ float red[HG][128];
  for (int idx = j; idx < HG*160; idx += 128){
    int g = idx / 160, i = idx % 160;
    float v;
    if (i < 128) v = emb[(size_t)(g0+g)*HID_ + i];
    else         v = mf[(size_t)(g0+g)*2048 + fpi[task*32 + (i-128)]];
    fused[g][i] = v;
  }
  __syncthreads();
  const float* w1 = tw1 + (size_t)task*160*128;
  float acc[HG];
  float b1 = tb1[task*128 + j];
  #pragma unroll
  for (int g=0; g<HG; g++) acc[g] = b1;
  for (int i=0; i<160; i++){
    float wv = w1[(size_t)i*128 + j];
    #pragma unroll
    for (int g=0; g<HG; g++) acc[g] += fused[g][i] * wv;
  }
  float t2 = tw2[task*128 + j];
  #pragma unroll
  for (int g=0; g<HG; g++){
    float v = acc[g] > 0.f ? acc[g] : 0.f;
    red[g][j] = v * t2;
  }
  __syncthreads();
  int g = j >> 4, l16 = j & 15;
  float s = 0.f;
  #pragma unroll
  for (int k=0;k<8;k++) s += red[g][l16 + k*16];
  s += __shfl_xor(s, 1, 16);
  s += __shfl_xor(s, 2, 16);
  s += __shfl_xor(s, 4, 16);
  s += __shfl_xor(s, 8, 16);
  if (l16 == 0) out[(size_t)(g0+g)*N_TASK + task] = s + tb2[task];
}

extern "C" void kernel_launch(void* const* d_in, const int* in_sizes, int n_in,
                              void* d_out, int out_size, void* d_ws, size_t ws_size,
                              hipStream_t stream){
  const float* x    = (const float*)d_in[0];
  const int*   ei   = (const int*)  d_in[1];
  const float* ea   = (const float*)d_in[2];
  const int*   batch= (const int*)  d_in[3];
  const float* mf   = (const float*)d_in[4];
  const int*   fpi  = (const int*)  d_in[5];
  const float* Wl0  = (const float*)d_in[6];
  const float* bl0  = (const float*)d_in[7];
  const float* Wr0  = (const float*)d_in[8];
  const float* br0  = (const float*)d_in[9];
  const float* We0  = (const float*)d_in[10];
  const float* att0 = (const float*)d_in[11];
  const float* g0   = (const float*)d_in[13];
  const float* b0   = (const float*)d_in[14];
  const float* Wl   = (const float*)d_in[15];
  const float* bl   = (const float*)d_in[16];
  const float* Wr   = (const float*)d_in[17];
  const float* br   = (const float*)d_in[18];
  const float* We   = (const float*)d_in[19];
  const float* att  = (const float*)d_in[20];
  const float* gg   = (const float*)d_in[22];
  const float* bb   = (const float*)d_in[23];
  const float* tw1  = (const float*)d_in[24];
  const float* tb1  = (const float*)d_in[25];
  const float* tw2  = (const float*)d_in[26];
  const float* tb2  = (const float*)d_in[27];
  float* out = (float*)d_out;

  char* w = (char*)d_ws;
  auto alloc = [&](size_t bytes)->char*{ char* r = w; w += (bytes + 255) & ~(size_t)255; return r; };
  u16*   xl     = (u16*)  alloc((size_t)N_NODES*HID_*2);
  unsigned* xr_aggr = (unsigned*)alloc((size_t)N_NODES*64*4);
  u16*   h      = (u16*)  alloc((size_t)N_NODES*HID_*2);
  u16*   ea16   = (u16*)  alloc((size_t)N_EDGES*16*2);
  int*   counts = (int*)  alloc((size_t)N_NODES*4);
  float* stats4 = (float*)alloc(4*256*4);
  int*   offsets= (int*)  alloc((size_t)(N_NODES+1)*4);
  int*   cursor = (int*)  alloc((size_t)N_NODES*4);
  int*   incl   = (int*)  alloc((size_t)N_NODES*4);
  int*   bsum   = (int*)  alloc(256*4);
  int*   ssrc   = (int*)  alloc((size_t)N_EDGES*4);
  int*   goff   = (int*)  alloc((size_t)(N_GRAPH+1)*4);
  float* emb    = (float*)alloc((size_t)N_GRAPH*HID_*4);
  u16*   Wzl0   = (u16*)  alloc((size_t)F_NODE_*128*2);
  u16*   Wzr0   = (u16*)  alloc((size_t)F_NODE_*128*2);
  u16*   Wzl123 = (u16*)  alloc((size_t)3*HID_*128*2);
  u16*   Wzr123 = (u16*)  alloc((size_t)3*HID_*128*2);
  u16*   xbf    = (u16*)  alloc((size_t)N_NODES*F_NODE_*2);

  const size_t zlen = (size_t)((char*)(stats4 + 4*256) - (char*)counts);
  const int nscan = (N_NODES + 511)/512;

  // prelude
  {
    WZ8 p;
    p.src[0] = Wl0; p.dst[0] = Wzl0; p.Ks[0] = F_NODE_; p.Kd[0] = F_NODE_;
    p.src[1] = Wr0; p.dst[1] = Wzr0; p.Ks[1] = F_NODE_; p.Kd[1] = F_NODE_;
    for (int i=0;i<3;i++){
      p.src[2+i] = Wl + (size_t)i*HID_*HID_; p.dst[2+i] = Wzl123 + (size_t)i*HID_*128; p.Ks[2+i] = HID_; p.Kd[2+i] = HID_;
      p.src[5+i] = Wr + (size_t)i*HID_*HID_; p.dst[5+i] = Wzr123 + (size_t)i*HID_*128; p.Ks[5+i] = HID_; p.Kd[5+i] = HID_;
    }
    hipLaunchKernelGGL(k_wswz_all, dim3((HID_*128 + 255)/256, 8), dim3(256), 0, stream, p);
  }
  hipMemsetAsync(counts, 0, zlen, stream);
  hipLaunchKernelGGL(k_cast_hist, dim3(CAST_BLKS + EG256 + GOFF_BLKS), dim3(256), 0, stream,
                     x, xbf, ei, counts, batch, goff);
  hipLaunchKernelGGL(k_scan1,  dim3(nscan), dim3(512), 0, stream, counts, incl, bsum);
  hipLaunchKernelGGL(k_scan2,  dim3(1),     dim3(256), 0, stream, bsum, nscan);
  hipLaunchKernelGGL(k_scan3,  dim3(nscan), dim3(512), 0, stream, counts, incl, bsum, offsets, cursor);
  hipLaunchKernelGGL(k_scatter,dim3(EG256), dim3(256), 0, stream, ei, cursor, ssrc, ea, ea16);

  for (int layer = 0; layer < 4; layer++){
    const float *bl_, *br_, *att_, *g_, *b_, *We_;
    const u16 *Wzl_, *Wzr_, *Ain;
    int K;
    if (layer == 0){
      bl_=bl0; br_=br0; att_=att0; g_=g0; b_=b0; We_ = We0;
      Wzl_ = Wzl0; Wzr_ = Wzr0; Ain = xbf; K = F_NODE_;
    } else {
      int i = layer - 1;
      bl_ = bl + (size_t)i*HID_;  br_ = br + (size_t)i*HID_;
      att_= att + (size_t)i*HID_;
      g_  = gg + (size_t)i*HID_;  b_  = bb + (size_t)i*HID_;
      We_ = We + (size_t)i*F_EDGE_*HID_;
      Wzl_ = Wzl123 + (size_t)i*HID_*128;
      Wzr_ = Wzr123 + (size_t)i*HID_*128;
      Ain = h; K = HID_;
    }
    float* stats = stats4 + layer*256;
    hipLaunchKernelGGL(k_gemm2, dim3(2*GEMM_GRID), dim3(256), 0, stream,
                       Ain, Wzl_, Wzr_, bl_, br_, xl, (u16*)xr_aggr, N_NODES, K);
    hipLaunchKernelGGL(k_gat_ep, dim3(GAT_GRID), dim3(256), 0, stream,
                       xl, xr_aggr, ea16, We_, att_, offsets, ssrc);
    hipLaunchKernelGGL(k_bn_stats, dim3(512), dim3(256), 0, stream, xr_aggr, stats);
    hipLaunchKernelGGL(k_bn_apply, dim3((N_NODES*16 + 255)/256), dim3(256), 0, stream,
                       xr_aggr, stats, g_, b_, h, layer > 0 ? 1 : 0);
  }
  hipLaunchKernelGGL(k_pool_seg, dim3(N_GRAPH), dim3(256), 0, stream, (const unsigned*)h, goff, emb);
  hipLaunchKernelGGL(k_heads, dim3(N_GRAPH/HG, N_TASK), dim3(128), 0, stream, emb, mf, fpi, tw1, tb1, tw2, tb2, out);
}

// Round 2
// 1122.710 us; speedup vs baseline: 1.4183x; 1.4183x over previous
//
#include <hip/hip_runtime.h>
#include <hip/hip_bf16.h>

#define N_NODES 100000
#define N_EDGES 400000
#define F_NODE_ 64
#define F_EDGE_ 16
#define HID_ 128
#define N_GRAPH 1024
#define N_TASK 5

typedef unsigned short u16;
typedef __attribute__((ext_vector_type(8))) short frag8;   // 8 bf16 = 4 VGPRs
typedef __attribute__((ext_vector_type(4))) float f32x4;   // MFMA C/D
typedef __attribute__((ext_vector_type(2))) float f32x2;

__device__ __forceinline__ float bu2f(u16 v){ return __uint_as_float(((unsigned)v) << 16); }
__device__ __forceinline__ float2 bp2f(unsigned u){
  return make_float2(__uint_as_float(u << 16), __uint_as_float(u & 0xFFFF0000u));
}
__device__ __forceinline__ f32x2 bp2v(unsigned u){
  f32x2 r; r.x = __uint_as_float(u << 16); r.y = __uint_as_float(u & 0xFFFF0000u); return r;
}
__device__ __forceinline__ u16 f2bu(float f){
  __hip_bfloat16 h = __float2bfloat16(f);
  return *(u16*)&h;
}
__device__ __forceinline__ unsigned packbf(float a, float b){
  return (unsigned)f2bu(a) | ((unsigned)f2bu(b) << 16);
}

// ---------------- cast f32 -> bf16 fused with edge histogram + graph offsets ----------------
#define CAST_BLKS ((N_NODES*F_NODE_ + 255)/256)
#define EG256 ((N_EDGES + 255)/256)
#define GOFF_BLKS ((N_GRAPH + 1 + 255)/256)
__global__ __launch_bounds__(256) void k_cast_hist(const float* __restrict__ s, u16* __restrict__ d,
                                                   const int* __restrict__ ei, int* __restrict__ counts,
                                                   const int* __restrict__ batch, int* __restrict__ goff){
  int b = blockIdx.x;
  if (b < CAST_BLKS){
    int i = b*256 + threadIdx.x;
    if (i < N_NODES*F_NODE_) d[i] = f2bu(s[i]);
  } else if (b < CAST_BLKS + EG256){
    int e = (b - CAST_BLKS)*256 + threadIdx.x;
    if (e < N_EDGES) atomicAdd(&counts[ei[N_EDGES + e]], 1);
  } else {
    int g = (b - CAST_BLKS - EG256)*256 + threadIdx.x;
    if (g <= N_GRAPH){
      int lo = 0, hi = N_NODES;
      while (lo < hi){
        int mid = (lo + hi) >> 1;
        if (batch[mid] < g) lo = mid + 1; else hi = mid;
      }
      goff[g] = lo;
    }
  }
}

// ---------------- batched pre-swizzle: 8 W (K=64/128) + 4 We (K=16 zero-padded to 32) ----------------
struct WZ12 { const float* src[12]; u16* dst[12]; int Ks[12]; int Kd[12]; };
__global__ __launch_bounds__(256) void k_wswz_all(WZ12 p){
  const int s = blockIdx.y;
  const int Kd = p.Kd[s], Ks = p.Ks[s];
  int i = blockIdx.x*256 + threadIdx.x;
  if (i >= Kd*128) return;
  int k = i >> 7, n = i & 127;
  float v = (k < Ks) ? p.src[s][k*128 + n] : 0.f;
  int kk = k & 31, c = k >> 5;
  int quad = kk >> 3, j = kk & 7;
  int nt = n >> 4;
  int lane = quad*16 + (n & 15);
  p.dst[s][(((c*8 + nt)*64) + lane)*8 + j] = f2bu(v);
}

// ---------------- paired MFMA GEMMs (xl, xr) ----------------
#define GEMM_GRID ((N_NODES + 127)/128)   // 782
__global__ __launch_bounds__(256) void k_gemm2(const u16* __restrict__ A,
                                               const u16* __restrict__ Wzl,
                                               const u16* __restrict__ Wzr,
                                               const float* __restrict__ bl,
                                               const float* __restrict__ br,
                                               u16* __restrict__ Cl,
                                               u16* Cr,
                                               int M, int K){
  __shared__ u16 WS[128*128];
  const int t = threadIdx.x;
  const int b = blockIdx.x;
  const int which = (b >= GEMM_GRID);
  const int bx = which ? b - GEMM_GRID : b;
  const u16*   Wz   = which ? Wzr : Wzl;
  const float* bias = which ? br  : bl;
  u16*         C    = which ? Cr  : Cl;
  {
    const uint4* src = (const uint4*)Wz;
    uint4* dst = (uint4*)WS;
    const int n = (K*128) >> 3;
    for (int i = t; i < n; i += 256) dst[i] = src[i];
  }
  __syncthreads();
  const int w = t >> 6, l = t & 63;
  const int m = l & 15, quad = l >> 4;
  const int rowA0 = bx*128 + w*32 + m;
  const int rowA1 = rowA0 + 16;
  f32x4 acc[2][8];
  #pragma unroll
  for (int i=0;i<2;i++)
    #pragma unroll
    for (int j=0;j<8;j++) acc[i][j] = (f32x4){0.f,0.f,0.f,0.f};
  const int KC = K >> 5;
  for (int c = 0; c < KC; c++){
    frag8 a0 = {}, a1 = {};
    if (rowA0 < M) a0 = *(const frag8*)(A + (size_t)rowA0*K + c*32 + quad*8);
    if (rowA1 < M) a1 = *(const frag8*)(A + (size_t)rowA1*K + c*32 + quad*8);
    #pragma unroll
    for (int nt = 0; nt < 8; nt++){
      frag8 bfr = *(const frag8*)&WS[(((c*8 + nt)*64) + l)*8];
      acc[0][nt] = __builtin_amdgcn_mfma_f32_16x16x32_bf16(a0, bfr, acc[0][nt], 0,0,0);
      acc[1][nt] = __builtin_amdgcn_mfma_f32_16x16x32_bf16(a1, bfr, acc[1][nt], 0,0,0);
    }
  }
  #pragma unroll
  for (int rt = 0; rt < 2; rt++){
    int rbase = bx*128 + w*32 + rt*16 + quad*4;
    #pragma unroll
    for (int nt = 0; nt < 8; nt++){
      int col = nt*16 + m;
      float bc = bias[col];
      #pragma unroll
      for (int r = 0; r < 4; r++){
        int row = rbase + r;
        if (row < M) C[(size_t)row*128 + col] = f2bu(acc[rt][nt][r] + bc);
      }
    }
  }
}

__global__ __launch_bounds__(512) void k_scan1(const int* __restrict__ counts,
                                               int* __restrict__ incl,
                                               int* __restrict__ bsum){
  __shared__ int s[512];
  const int t = threadIdx.x;
  int i = blockIdx.x*512 + t;
  int v = (i < N_NODES) ? counts[i] : 0;
  s[t] = v;
  __syncthreads();
  for (int off = 1; off < 512; off <<= 1){
    int x = (t >= off) ? s[t - off] : 0;
    __syncthreads();
    s[t] += x;
    __syncthreads();
  }
  if (i < N_NODES) incl[i] = s[t];
  if (t == 511) bsum[blockIdx.x] = s[511];
}

__global__ __launch_bounds__(256) void k_scan2(int* __restrict__ bsum, int nb){
  __shared__ int s[256];
  const int t = threadIdx.x;
  int v = (t < nb) ? bsum[t] : 0;
  s[t] = v;
  __syncthreads();
  for (int off = 1; off < 256; off <<= 1){
    int x = (t >= off) ? s[t - off] : 0;
    __syncthreads();
    s[t] += x;
    __syncthreads();
  }
  if (t < nb) bsum[t] = s[t] - v;
}

__global__ __launch_bounds__(512) void k_scan3(const int* __restrict__ counts,
                                               const int* __restrict__ incl,
                                               const int* __restrict__ bsum,
                                               int* __restrict__ offsets,
                                               int* __restrict__ cursor){
  int i = blockIdx.x*512 + threadIdx.x;
  if (i >= N_NODES) return;
  int o = bsum[blockIdx.x] + incl[i];
  offsets[i + 1] = o;
  cursor[i]      = o - counts[i];
  if (i == 0) offsets[0] = 0;
}

// scatter: src index + bf16 edge features into CSR order ([E][16] bf16)
__global__ __launch_bounds__(256) void k_scatter(const int* __restrict__ ei,
                                                 int* __restrict__ cursor,
                                                 int* __restrict__ ssrc,
                                                 const float* __restrict__ ea,
                                                 u16* __restrict__ ea16){
  int e = blockIdx.x*256 + threadIdx.x;
  if (e >= N_EDGES) return;
  int dst = ei[N_EDGES + e];
  int pos = atomicAdd(&cursor[dst], 1);
  ssrc[pos] = ei[e];
  const float* s = ea + (size_t)e*F_EDGE_;
  unsigned p[8];
  #pragma unroll
  for (int k=0;k<8;k++) p[k] = packbf(s[2*k], s[2*k+1]);
  uint4* d4 = (uint4*)(ea16 + (size_t)pos*16);
  d4[0] = make_uint4(p[0],p[1],p[2],p[3]);
  d4[1] = make_uint4(p[4],p[5],p[6],p[7]);
}

// ---------------- Fused GAT v12: per-block ee via MFMA into LDS (no eproj HBM round trip) ----------------
// Block covers nodes 4b..4b+3 whose CSR edges are contiguous [offsets[4b], offsets[4b+4]).
// Phase 1: stage ea rows into LDS (K padded to 32 with zeros).
// Phase 2: ee = ea @ We via MFMA (identical math to old eproj GEMM: bf16 in, Wez zero-padded swizzle, bf16 out).
// Phase 3: per-node wave gat loop reading ee from LDS (same consumption as old eproj read).
#define GAT_GRID 25000
#define ECAP 96
__device__ __forceinline__ f32x2 ld_ee(int li, const u16* ee_lds, int c0,
                                       const u16* ea16, const float* Wef, int beg0){
  if (li < ECAP) return bp2v(*(const unsigned*)&ee_lds[li*128 + c0]);
  // cold fallback (block with >ECAP edges: probabilistically never, but correct)
  f32x2 acc = {0.f, 0.f};
  const u16* er = ea16 + (size_t)(beg0 + li)*16;
  #pragma unroll
  for (int k = 0; k < 16; k++){
    float ev = bu2f(er[k]);
    acc.x += ev * Wef[k*HID_ + c0];
    acc.y += ev * Wef[k*HID_ + c0 + 1];
  }
  return acc;
}

__global__ __launch_bounds__(256) void k_gat_ep(const u16* __restrict__ xl,
                                                unsigned* xr_aggr,
                                                const u16* __restrict__ ea16,
                                                const u16* __restrict__ Wez,
                                                const float* __restrict__ Wef,
                                                const float* __restrict__ att,
                                                const int* __restrict__ offsets,
                                                const int* __restrict__ ssrc){
  __shared__ u16 ea_lds[ECAP*40];    // row stride 40 u16: 16 data + 16 zero pad + 8 slack (bank spread)
  __shared__ u16 ee_lds[ECAP*128];
  const int t = threadIdx.x;
  const int wave = t >> 6, lane = t & 63;
  const int m = lane & 15, quad = lane >> 4;
  const int node0 = blockIdx.x*4;
  const int beg0 = offsets[node0];
  const int cnt  = offsets[node0+4] - beg0;
  const int stg  = cnt < ECAP ? cnt : ECAP;
  // stage ea rows (16 u16 each, 8B chunks) + zero-pad cols 16..31
  for (int idx = t; idx < stg*4; idx += 256){
    int r = idx >> 2, part = idx & 3;
    *(uint2*)&ea_lds[r*40 + part*4] = *(const uint2*)(ea16 + ((size_t)(beg0 + r))*16 + part*4);
  }
  for (int idx = t; idx < stg*2; idx += 256){
    int r = idx >> 1, half = idx & 1;
    *(uint4*)&ea_lds[r*40 + 16 + half*8] = make_uint4(0,0,0,0);
  }
  __syncthreads();
  {
    frag8 bf0 = *(const frag8*)(Wez + (((2*wave  )*64) + lane)*8);
    frag8 bf1 = *(const frag8*)(Wez + (((2*wave+1)*64) + lane)*8);
    const int ng = (stg + 15) >> 4;
    for (int g = 0; g < ng; g++){
      frag8 a = *(const frag8*)&ea_lds[(g*16 + m)*40 + quad*8];
      f32x4 acc0 = (f32x4){0.f,0.f,0.f,0.f}, acc1 = (f32x4){0.f,0.f,0.f,0.f};
      acc0 = __builtin_amdgcn_mfma_f32_16x16x32_bf16(a, bf0, acc0, 0,0,0);
      acc1 = __builtin_amdgcn_mfma_f32_16x16x32_bf16(a, bf1, acc1, 0,0,0);
      #pragma unroll
      for (int r = 0; r < 4; r++){
        int row = g*16 + quad*4 + r;
        ee_lds[row*128 + (2*wave  )*16 + m] = f2bu(acc0[r]);
        ee_lds[row*128 + (2*wave+1)*16 + m] = f2bu(acc1[r]);
      }
    }
  }
  __syncthreads();

  const int c0 = lane*2;
  const float a0 = att[c0], a1 = att[c0+1];
  const int node = node0 + wave;
  const f32x2 xrv = bp2v(xr_aggr[(size_t)node*64 + lane]);
  f32x2 accv = {0.f, 0.f};
  float den = 0.f;
  const int beg = offsets[node], end = offsets[node+1];
  for (int i = beg; i < end; i += 4){
    const int mm = end - i;
    const int i1 = (mm > 1) ? i+1 : i;
    const int i2 = (mm > 2) ? i+2 : i;
    const int i3 = (mm > 3) ? i+3 : i;
    int s0 = ssrc[i], s1 = ssrc[i1], s2 = ssrc[i2], s3 = ssrc[i3];
    f32x2 ee0 = ld_ee(i  - beg0, ee_lds, c0, ea16, Wef, beg0);
    f32x2 ee1 = ld_ee(i1 - beg0, ee_lds, c0, ea16, Wef, beg0);
    f32x2 ee2 = ld_ee(i2 - beg0, ee_lds, c0, ea16, Wef, beg0);
    f32x2 ee3 = ld_ee(i3 - beg0, ee_lds, c0, ea16, Wef, beg0);
    f32x2 vl0 = bp2v(*(const unsigned*)(xl + (size_t)s0*HID_ + c0));
    f32x2 vl1 = bp2v(*(const unsigned*)(xl + (size_t)s1*HID_ + c0));
    f32x2 vl2 = bp2v(*(const unsigned*)(xl + (size_t)s2*HID_ + c0));
    f32x2 vl3 = bp2v(*(const unsigned*)(xl + (size_t)s3*HID_ + c0));
    f32x2 v0 = vl0 + xrv + ee0;
    f32x2 v1 = vl1 + xrv + ee1;
    f32x2 v2 = vl2 + xrv + ee2;
    f32x2 v3 = vl3 + xrv + ee3;
    f32x2 w0 = v0*0.2f, w1 = v1*0.2f, w2 = v2*0.2f, w3 = v3*0.2f;
    v0.x = fmaxf(v0.x,w0.x); v0.y = fmaxf(v0.y,w0.y);
    v1.x = fmaxf(v1.x,w1.x); v1.y = fmaxf(v1.y,w1.y);
    v2.x = fmaxf(v2.x,w2.x); v2.y = fmaxf(v2.y,w2.y);
    v3.x = fmaxf(v3.x,w3.x); v3.y = fmaxf(v3.y,w3.y);
    float sc0 = v0.x*a0 + v0.y*a1;
    float sc1 = v1.x*a0 + v1.y*a1;
    float sc2 = v2.x*a0 + v2.y*a1;
    float sc3 = v3.x*a0 + v3.y*a1;
    sc0 += __shfl_xor(sc0, 1); sc1 += __shfl_xor(sc1, 1); sc2 += __shfl_xor(sc2, 1); sc3 += __shfl_xor(sc3, 1);
    sc0 += __shfl_xor(sc0, 2); sc1 += __shfl_xor(sc1, 2); sc2 += __shfl_xor(sc2, 2); sc3 += __shfl_xor(sc3, 2);
    sc0 += __shfl_xor(sc0, 4); sc1 += __shfl_xor(sc1, 4); sc2 += __shfl_xor(sc2, 4); sc3 += __shfl_xor(sc3, 4);
    sc0 += __shfl_xor(sc0, 8); sc1 += __shfl_xor(sc1, 8); sc2 += __shfl_xor(sc2, 8); sc3 += __shfl_xor(sc3, 8);
    float p0 = __expf(sc0);
    float p1 = (mm > 1) ? __expf(sc1) : 0.f;
    float p2 = (mm > 2) ? __expf(sc2) : 0.f;
    float p3 = (mm > 3) ? __expf(sc3) : 0.f;
    accv += p0*vl0 + p1*vl1 + p2*vl2 + p3*vl3;
    den  += p0 + p1 + p2 + p3;
  }
  float inv = 1.0f / (den + 1e-16f);
  xr_aggr[(size_t)node*64 + lane] = packbf(accv.x*inv, accv.y*inv);
}

// ---------------- BN stats (bf16 aggr input) ----------------
__global__ __launch_bounds__(256) void k_bn_stats(const unsigned* __restrict__ aggr_b,
                                                  float* __restrict__ stats){
  __shared__ float redS[4][128], redQ[4][128];
  const int t = threadIdx.x;
  const int p = t & 63, rg = t >> 6;
  const int c0 = p*2;
  float s0=0.f, s1=0.f, q0=0.f, q1=0.f;
  for (int r = blockIdx.x*4 + rg; r < N_NODES; r += gridDim.x*4){
    float2 v = bp2f(aggr_b[(size_t)r*64 + p]);
    s0 += v.x; s1 += v.y; q0 += v.x*v.x; q1 += v.y*v.y;
  }
  redS[rg][c0] = s0; redS[rg][c0+1] = s1;
  redQ[rg][c0] = q0; redQ[rg][c0+1] = q1;
  __syncthreads();
  if (rg == 0){
    #pragma unroll
    for (int g=1; g<4; g++){
      s0 += redS[g][c0]; s1 += redS[g][c0+1];
      q0 += redQ[g][c0]; q1 += redQ[g][c0+1];
    }
    atomicAdd(&stats[c0],     s0);
    atomicAdd(&stats[c0+1],   s1);
    atomicAdd(&stats[128+c0],   q0);
    atomicAdd(&stats[128+c0+1], q1);
  }
}

// ---------------- BN apply + ELU (+ residual), uint4-vectorized ----------------
__global__ __launch_bounds__(256) void k_bn_apply(const unsigned* __restrict__ aggr_b,
                                                  const float* __restrict__ stats,
                                                  const float* __restrict__ gamma,
                                                  const float* __restrict__ beta,
                                                  u16* __restrict__ h, int residual){
  size_t i = (size_t)blockIdx.x*256 + threadIdx.x;   // uint4-group index (8 channels)
  if (i >= (size_t)N_NODES*16) return;
  const int c = (int)((i & 15) * 8);
  const float invn = 1.0f / (float)N_NODES;
  uint4 v4 = ((const uint4*)aggr_b)[i];
  uint4* hp = (uint4*)h + i;
  uint4 hv4 = make_uint4(0,0,0,0);
  if (residual) hv4 = *hp;
  unsigned vin[4]  = {v4.x, v4.y, v4.z, v4.w};
  unsigned hin[4]  = {hv4.x, hv4.y, hv4.z, hv4.w};
  unsigned outw[4];
  #pragma unroll
  for (int j=0;j<4;j++){
    int cc = c + j*2;
    float mu0  = stats[cc]   * invn,  mu1  = stats[cc+1]   * invn;
    float var0 = stats[128+cc]*invn - mu0*mu0;
    float var1 = stats[129+cc]*invn - mu1*mu1;
    float sc0 = rsqrtf(var0 + 1e-5f) * gamma[cc];
    float sc1 = rsqrtf(var1 + 1e-5f) * gamma[cc+1];
    float2 v = bp2f(vin[j]);
    float val0 = (v.x - mu0) * sc0 + beta[cc];
    float val1 = (v.y - mu1) * sc1 + beta[cc+1];
    val0 = val0 > 0.f ? val0 : expm1f(val0);
    val1 = val1 > 0.f ? val1 : expm1f(val1);
    if (residual){
      float2 hv = bp2f(hin[j]);
      val0 += hv.x; val1 += hv.y;
    }
    outw[j] = packbf(val0, val1);
  }
  *hp = make_uint4(outw[0], outw[1], outw[2], outw[3]);
}

// ---------------- Pool: segmented mean ----------------
__global__ __launch_bounds__(256) void k_pool_seg(const unsigned* __restrict__ h2,
                                                  const int* __restrict__ goff,
                                                  float* __restrict__ emb){
  __shared__ float redS[4][128];
  const int g = blockIdx.x, t = threadIdx.x;
  const int p = t & 63, rg = t >> 6;
  const int beg = goff[g], end = goff[g+1];
  float a0 = 0.f, a1 = 0.f;
  for (int r = beg + rg; r < end; r += 4){
    float2 v = bp2f(h2[(size_t)r*64 + p]);
    a0 += v.x; a1 += v.y;
  }
  redS[rg][p*2] = a0; redS[rg][p*2+1] = a1;
  __syncthreads();
  if (rg == 0){
    #pragma unroll
    for (int k=1;k<4;k++){ a0 += redS[k][p*2]; a1 += redS[k][p*2+1]; }
    float n = fmaxf((float)(end - beg), 1.f);
    emb[(size_t)g*HID_ + p*2]     = a0 / n;
    emb[(size_t)g*HID_ + p*2 + 1] = a1 / n;
  }
}

// ---------------- Per-task heads: 8 graphs per block ----------------
#define HG 8
__global__ __launch_bounds__(128) void k_heads(const float* __restrict__ emb,
                                               const float* __restrict__ mf,
                                               const int* __restrict__ fpi,
                                               const float* __restrict__ tw1,
                                               const float* __restrict__ tb1,
                                               const float* __restrict__ tw2,
                                               const float* __restrict__ tb2,
                                               float* __restrict__ out){
  const int task = blockIdx.y, g0 = blockIdx.x*HG;
  const int j = threadIdx.x;
  __shared__ float fused[HG][160];
  __shared__ float red[HG][128];
  for (int idx = j; idx < HG*160; idx += 128){
    int g = idx / 160, i = idx % 160;
    float v;
    if (i < 128) v = emb[(size_t)(g0+g)*HID_ + i];
    else         v = mf[(size_t)(g0+g)*2048 + fpi[task*32 + (i-128)]];
    fused[g][i] = v;
  }
  __syncthreads();
  const float* w1 = tw1 + (size_t)task*160*128;
  float acc[HG];
  float b1 = tb1[task*128 + j];
  #pragma unroll
  for (int g=0; g<HG; g++) acc[g] = b1;
  for (int i=0; i<160; i++){
    float wv = w1[(size_t)i*128 + j];
    #pragma unroll
    for (int g=0; g<HG; g++) acc[g] += fused[g][i] * wv;
  }
  float t2 = tw2[task*128 + j];
  #pragma unroll
  for (int g=0; g<HG; g++){
    float v = acc[g] > 0.f ? acc[g] : 0.f;
    red[g][j] = v * t2;
  }
  __syncthreads();
  int g = j >> 4, l16 = j & 15;
  float s = 0.f;
  #pragma unroll
  for (int k=0;k<8;k++) s += red[g][l16 + k*16];
  s += __shfl_xor(s, 1, 16);
  s += __shfl_xor(s, 2, 16);
  s += __shfl_xor(s, 4, 16);
  s += __shfl_xor(s, 8, 16);
  if (l16 == 0) out[(size_t)(g0+g)*N_TASK + task] = s + tb2[task];
}

extern "C" void kernel_launch(void* const* d_in, const int* in_sizes, int n_in,
                              void* d_out, int out_size, void* d_ws, size_t ws_size,
                              hipStream_t stream){
  const float* x    = (const float*)d_in[0];
  const int*   ei   = (const int*)  d_in[1];
  const float* ea   = (const float*)d_in[2];
  const int*   batch= (const int*)  d_in[3];
  const float* mf   = (const float*)d_in[4];
  const int*   fpi  = (const int*)  d_in[5];
  const float* Wl0  = (const float*)d_in[6];
  const float* bl0  = (const float*)d_in[7];
  const float* Wr0  = (const float*)d_in[8];
  const float* br0  = (const float*)d_in[9];
  const float* We0  = (const float*)d_in[10];
  const float* att0 = (const float*)d_in[11];
  const float* g0   = (const float*)d_in[13];
  const float* b0   = (const float*)d_in[14];
  const float* Wl   = (const float*)d_in[15];
  const float* bl   = (const float*)d_in[16];
  const float* Wr   = (const float*)d_in[17];
  const float* br   = (const float*)d_in[18];
  const float* We   = (const float*)d_in[19];
  const float* att  = (const float*)d_in[20];
  const float* gg   = (const float*)d_in[22];
  const float* bb   = (const float*)d_in[23];
  const float* tw1  = (const float*)d_in[24];
  const float* tb1  = (const float*)d_in[25];
  const float* tw2  = (const float*)d_in[26];
  const float* tb2  = (const float*)d_in[27];
  float* out = (float*)d_out;

  char* w = (char*)d_ws;
  auto alloc = [&](size_t bytes)->char*{ char* r = w; w += (bytes + 255) & ~(size_t)255; return r; };
  u16*   xl     = (u16*)  alloc((size_t)N_NODES*HID_*2);
  unsigned* xr_aggr = (unsigned*)alloc((size_t)N_NODES*64*4);
  u16*   h      = (u16*)  alloc((size_t)N_NODES*HID_*2);
  u16*   ea16   = (u16*)  alloc((size_t)N_EDGES*16*2);
  int*   counts = (int*)  alloc((size_t)N_NODES*4);
  float* stats4 = (float*)alloc(4*256*4);
  int*   offsets= (int*)  alloc((size_t)(N_NODES+1)*4);
  int*   cursor = (int*)  alloc((size_t)N_NODES*4);
  int*   incl   = (int*)  alloc((size_t)N_NODES*4);
  int*   bsum   = (int*)  alloc(256*4);
  int*   ssrc   = (int*)  alloc((size_t)N_EDGES*4);
  int*   goff   = (int*)  alloc((size_t)(N_GRAPH+1)*4);
  float* emb    = (float*)alloc((size_t)N_GRAPH*HID_*4);
  u16*   Wzl0   = (u16*)  alloc((size_t)F_NODE_*128*2);
  u16*   Wzr0   = (u16*)  alloc((size_t)F_NODE_*128*2);
  u16*   Wzl123 = (u16*)  alloc((size_t)3*HID_*128*2);
  u16*   Wzr123 = (u16*)  alloc((size_t)3*HID_*128*2);
  u16*   Wez4   = (u16*)  alloc((size_t)4*32*128*2);
  u16*   xbf    = (u16*)  alloc((size_t)N_NODES*F_NODE_*2);

  const size_t zlen = (size_t)((char*)(stats4 + 4*256) - (char*)counts);
  const int nscan = (N_NODES + 511)/512;

  // prelude
  {
    WZ12 p;
    p.src[0] = Wl0; p.dst[0] = Wzl0; p.Ks[0] = F_NODE_; p.Kd[0] = F_NODE_;
    p.src[1] = Wr0; p.dst[1] = Wzr0; p.Ks[1] = F_NODE_; p.Kd[1] = F_NODE_;
    for (int i=0;i<3;i++){
      p.src[2+i] = Wl + (size_t)i*HID_*HID_; p.dst[2+i] = Wzl123 + (size_t)i*HID_*128; p.Ks[2+i] = HID_; p.Kd[2+i] = HID_;
      p.src[5+i] = Wr + (size_t)i*HID_*HID_; p.dst[5+i] = Wzr123 + (size_t)i*HID_*128; p.Ks[5+i] = HID_; p.Kd[5+i] = HID_;
    }
    p.src[8] = We0; p.dst[8] = Wez4; p.Ks[8] = F_EDGE_; p.Kd[8] = 32;
    for (int i=0;i<3;i++){
      p.src[9+i] = We + (size_t)i*F_EDGE_*HID_; p.dst[9+i] = Wez4 + (size_t)(i+1)*32*128; p.Ks[9+i] = F_EDGE_; p.Kd[9+i] = 32;
    }
    hipLaunchKernelGGL(k_wswz_all, dim3((HID_*128 + 255)/256, 12), dim3(256), 0, stream, p);
  }
  hipMemsetAsync(counts, 0, zlen, stream);
  hipLaunchKernelGGL(k_cast_hist, dim3(CAST_BLKS + EG256 + GOFF_BLKS), dim3(256), 0, stream,
                     x, xbf, ei, counts, batch, goff);
  hipLaunchKernelGGL(k_scan1,  dim3(nscan), dim3(512), 0, stream, counts, incl, bsum);
  hipLaunchKernelGGL(k_scan2,  dim3(1),     dim3(256), 0, stream, bsum, nscan);
  hipLaunchKernelGGL(k_scan3,  dim3(nscan), dim3(512), 0, stream, counts, incl, bsum, offsets, cursor);
  hipLaunchKernelGGL(k_scatter,dim3(EG256), dim3(256), 0, stream, ei, cursor, ssrc, ea, ea16);

  for (int layer = 0; layer < 4; layer++){
    const float *bl_, *br_, *att_, *g_, *b_, *We_;
    const u16 *Wzl_, *Wzr_, *Ain;
    int K;
    if (layer == 0){
      bl_=bl0; br_=br0; att_=att0; g_=g0; b_=b0; We_ = We0;
      Wzl_ = Wzl0; Wzr_ = Wzr0; Ain = xbf; K = F_NODE_;
    } else {
      int i = layer - 1;
      bl_ = bl + (size_t)i*HID_;  br_ = br + (size_t)i*HID_;
      att_= att + (size_t)i*HID_;
      g_  = gg + (size_t)i*HID_;  b_  = bb + (size_t)i*HID_;
      We_ = We + (size_t)i*F_EDGE_*HID_;
      Wzl_ = Wzl123 + (size_t)i*HID_*128;
      Wzr_ = Wzr123 + (size_t)i*HID_*128;
      Ain = h; K = HID_;
    }
    float* stats = stats4 + layer*256;
    hipLaunchKernelGGL(k_gemm2, dim3(2*GEMM_GRID), dim3(256), 0, stream,
                       Ain, Wzl_, Wzr_, bl_, br_, xl, (u16*)xr_aggr, N_NODES, K);
    hipLaunchKernelGGL(k_gat_ep, dim3(GAT_GRID), dim3(256), 0, stream,
                       xl, xr_aggr, ea16, Wez4 + (size_t)layer*32*128, We_, att_, offsets, ssrc);
    hipLaunchKernelGGL(k_bn_stats, dim3(512), dim3(256), 0, stream, xr_aggr, stats);
    hipLaunchKernelGGL(k_bn_apply, dim3((N_NODES*16 + 255)/256), dim3(256), 0, stream,
                       xr_aggr, stats, g_, b_, h, layer > 0 ? 1 : 0);
  }
  hipLaunchKernelGGL(k_pool_seg, dim3(N_GRAPH), dim3(256), 0, stream, (const unsigned*)h, goff, emb);
  hipLaunchKernelGGL(k_heads, dim3(N_GRAPH/HG, N_TASK), dim3(128), 0, stream, emb, mf, fpi, tw1, tb1, tw2, tb2, out);
}

// Round 4
// 833.774 us; speedup vs baseline: 1.9098x; 1.3465x over previous
//
#include <hip/hip_runtime.h>
#include <hip/hip_bf16.h>

#define N_NODES 100000
#define N_EDGES 400000
#define F_NODE_ 64
#define F_EDGE_ 16
#define HID_ 128
#define N_GRAPH 1024
#define N_TASK 5

typedef unsigned short u16;
typedef __attribute__((ext_vector_type(8))) short frag8;   // 8 bf16 = 4 VGPRs
typedef __attribute__((ext_vector_type(4))) float f32x4;   // MFMA C/D
typedef __attribute__((ext_vector_type(2))) float f32x2;

__device__ __forceinline__ float bu2f(u16 v){ return __uint_as_float(((unsigned)v) << 16); }
__device__ __forceinline__ float2 bp2f(unsigned u){
  return make_float2(__uint_as_float(u << 16), __uint_as_float(u & 0xFFFF0000u));
}
__device__ __forceinline__ f32x2 bp2v(unsigned u){
  f32x2 r; r.x = __uint_as_float(u << 16); r.y = __uint_as_float(u & 0xFFFF0000u); return r;
}
__device__ __forceinline__ u16 f2bu(float f){
  __hip_bfloat16 h = __float2bfloat16(f);
  return *(u16*)&h;
}
__device__ __forceinline__ unsigned packbf(float a, float b){
  return (unsigned)f2bu(a) | ((unsigned)f2bu(b) << 16);
}

// ---------------- cast f32 -> bf16 fused with edge histogram + graph offsets ----------------
#define CAST_BLKS ((N_NODES*F_NODE_ + 255)/256)
#define EG256 ((N_EDGES + 255)/256)
#define GOFF_BLKS ((N_GRAPH + 1 + 255)/256)
__global__ __launch_bounds__(256) void k_cast_hist(const float* __restrict__ s, u16* __restrict__ d,
                                                   const int* __restrict__ ei, int* __restrict__ counts,
                                                   const int* __restrict__ batch, int* __restrict__ goff){
  int b = blockIdx.x;
  if (b < CAST_BLKS){
    int i = b*256 + threadIdx.x;
    if (i < N_NODES*F_NODE_) d[i] = f2bu(s[i]);
  } else if (b < CAST_BLKS + EG256){
    int e = (b - CAST_BLKS)*256 + threadIdx.x;
    if (e < N_EDGES) atomicAdd(&counts[ei[N_EDGES + e]], 1);
  } else {
    int g = (b - CAST_BLKS - EG256)*256 + threadIdx.x;
    if (g <= N_GRAPH){
      int lo = 0, hi = N_NODES;
      while (lo < hi){
        int mid = (lo + hi) >> 1;
        if (batch[mid] < g) lo = mid + 1; else hi = mid;
      }
      goff[g] = lo;
    }
  }
}

// ---------------- batched pre-swizzle: 8 W (K=64/128) + 4 We (K=16 zero-padded to 32) ----------------
struct WZ12 { const float* src[12]; u16* dst[12]; int Ks[12]; int Kd[12]; };
__global__ __launch_bounds__(256) void k_wswz_all(WZ12 p){
  const int s = blockIdx.y;
  const int Kd = p.Kd[s], Ks = p.Ks[s];
  int i = blockIdx.x*256 + threadIdx.x;
  if (i >= Kd*128) return;
  int k = i >> 7, n = i & 127;
  float v = (k < Ks) ? p.src[s][k*128 + n] : 0.f;
  int kk = k & 31, c = k >> 5;
  int quad = kk >> 3, j = kk & 7;
  int nt = n >> 4;
  int lane = quad*16 + (n & 15);
  p.dst[s][(((c*8 + nt)*64) + lane)*8 + j] = f2bu(v);
}

// ---------------- fused: paired MFMA GEMMs + eproj MFMA GEMM (flat grid) ----------------
#define GEMM_GRID ((N_NODES + 127)/128)   // 782
#define EPROJ_GRID ((N_EDGES + 127)/128)  // 3125
__global__ __launch_bounds__(256) void k_gemm_eproj(const u16* __restrict__ A,
                                                    const u16* __restrict__ Wzl,
                                                    const u16* __restrict__ Wzr,
                                                    const float* __restrict__ bl,
                                                    const float* __restrict__ br,
                                                    u16* __restrict__ Cl,
                                                    u16* Cr,
                                                    int M, int K,
                                                    const u16* __restrict__ ea16,
                                                    const u16* __restrict__ Wez,
                                                    u16* __restrict__ eproj){
  __shared__ u16 WS[128*128];
  const int t = threadIdx.x;
  const int b = blockIdx.x;
  if (b < 2*GEMM_GRID){
    const int which = (b >= GEMM_GRID);
    const int bx = which ? b - GEMM_GRID : b;
    const u16*   Wz   = which ? Wzr : Wzl;
    const float* bias = which ? br  : bl;
    u16*         C    = which ? Cr  : Cl;
    {
      const uint4* src = (const uint4*)Wz;
      uint4* dst = (uint4*)WS;
      const int n = (K*128) >> 3;
      for (int i = t; i < n; i += 256) dst[i] = src[i];
    }
    __syncthreads();
    const int w = t >> 6, l = t & 63;
    const int m = l & 15, quad = l >> 4;
    const int rowA0 = bx*128 + w*32 + m;
    const int rowA1 = rowA0 + 16;
    f32x4 acc[2][8];
    #pragma unroll
    for (int i=0;i<2;i++)
      #pragma unroll
      for (int j=0;j<8;j++) acc[i][j] = (f32x4){0.f,0.f,0.f,0.f};
    const int KC = K >> 5;
    for (int c = 0; c < KC; c++){
      frag8 a0 = {}, a1 = {};
      if (rowA0 < M) a0 = *(const frag8*)(A + (size_t)rowA0*K + c*32 + quad*8);
      if (rowA1 < M) a1 = *(const frag8*)(A + (size_t)rowA1*K + c*32 + quad*8);
      #pragma unroll
      for (int nt = 0; nt < 8; nt++){
        frag8 bfr = *(const frag8*)&WS[(((c*8 + nt)*64) + l)*8];
        acc[0][nt] = __builtin_amdgcn_mfma_f32_16x16x32_bf16(a0, bfr, acc[0][nt], 0,0,0);
        acc[1][nt] = __builtin_amdgcn_mfma_f32_16x16x32_bf16(a1, bfr, acc[1][nt], 0,0,0);
      }
    }
    #pragma unroll
    for (int rt = 0; rt < 2; rt++){
      int rbase = bx*128 + w*32 + rt*16 + quad*4;
      #pragma unroll
      for (int nt = 0; nt < 8; nt++){
        int col = nt*16 + m;
        float bc = bias[col];
        #pragma unroll
        for (int r = 0; r < 4; r++){
          int row = rbase + r;
          if (row < M) C[(size_t)row*128 + col] = f2bu(acc[rt][nt][r] + bc);
        }
      }
    }
  } else {
    // eproj GEMM: 128 edges/block, K=32 via fragment zero-padding (ea16 stride 16; quad>=2 lanes stay zero)
    const int bx = b - 2*GEMM_GRID;
    {
      const uint4* s4 = (const uint4*)Wez;
      uint4* d4 = (uint4*)WS;
      for (int i = t; i < 512; i += 256) d4[i] = s4[i];
    }
    __syncthreads();
    const int w = t >> 6, l = t & 63, m = l & 15, quad = l >> 4;
    const int row0 = bx*128 + w*32 + m;
    const int row1 = row0 + 16;
    f32x4 acc[2][8];
    #pragma unroll
    for (int i=0;i<2;i++)
      #pragma unroll
      for (int j=0;j<8;j++) acc[i][j] = (f32x4){0.f,0.f,0.f,0.f};
    frag8 a0 = {}, a1 = {};
    if (quad < 2){
      if (row0 < N_EDGES) a0 = *(const frag8*)(ea16 + (size_t)row0*16 + quad*8);
      if (row1 < N_EDGES) a1 = *(const frag8*)(ea16 + (size_t)row1*16 + quad*8);
    }
    #pragma unroll
    for (int nt = 0; nt < 8; nt++){
      frag8 bfr = *(const frag8*)&WS[(nt*64 + l)*8];
      acc[0][nt] = __builtin_amdgcn_mfma_f32_16x16x32_bf16(a0, bfr, acc[0][nt], 0,0,0);
      acc[1][nt] = __builtin_amdgcn_mfma_f32_16x16x32_bf16(a1, bfr, acc[1][nt], 0,0,0);
    }
    #pragma unroll
    for (int rt = 0; rt < 2; rt++){
      const int rbase = bx*128 + w*32 + rt*16 + quad*4;
      #pragma unroll
      for (int nt = 0; nt < 8; nt++){
        int col = nt*16 + m;
        #pragma unroll
        for (int r = 0; r < 4; r++){
          int row = rbase + r;
          if (row < N_EDGES) eproj[(size_t)row*128 + col] = f2bu(acc[rt][nt][r]);
        }
      }
    }
  }
}

__global__ __launch_bounds__(512) void k_scan1(const int* __restrict__ counts,
                                               int* __restrict__ incl,
                                               int* __restrict__ bsum){
  __shared__ int s[512];
  const int t = threadIdx.x;
  int i = blockIdx.x*512 + t;
  int v = (i < N_NODES) ? counts[i] : 0;
  s[t] = v;
  __syncthreads();
  for (int off = 1; off < 512; off <<= 1){
    int x = (t >= off) ? s[t - off] : 0;
    __syncthreads();
    s[t] += x;
    __syncthreads();
  }
  if (i < N_NODES) incl[i] = s[t];
  if (t == 511) bsum[blockIdx.x] = s[511];
}

__global__ __launch_bounds__(256) void k_scan2(int* __restrict__ bsum, int nb){
  __shared__ int s[256];
  const int t = threadIdx.x;
  int v = (t < nb) ? bsum[t] : 0;
  s[t] = v;
  __syncthreads();
  for (int off = 1; off < 256; off <<= 1){
    int x = (t >= off) ? s[t - off] : 0;
    __syncthreads();
    s[t] += x;
    __syncthreads();
  }
  if (t < nb) bsum[t] = s[t] - v;
}

__global__ __launch_bounds__(512) void k_scan3(const int* __restrict__ counts,
                                               const int* __restrict__ incl,
                                               const int* __restrict__ bsum,
                                               int* __restrict__ offsets,
                                               int* __restrict__ cursor){
  int i = blockIdx.x*512 + threadIdx.x;
  if (i >= N_NODES) return;
  int o = bsum[blockIdx.x] + incl[i];
  offsets[i + 1] = o;
  cursor[i]      = o - counts[i];
  if (i == 0) offsets[0] = 0;
}

// scatter: src index + bf16 edge features into CSR order ([E][16] bf16)
__global__ __launch_bounds__(256) void k_scatter(const int* __restrict__ ei,
                                                 int* __restrict__ cursor,
                                                 int* __restrict__ ssrc,
                                                 const float* __restrict__ ea,
                                                 u16* __restrict__ ea16){
  int e = blockIdx.x*256 + threadIdx.x;
  if (e >= N_EDGES) return;
  int dst = ei[N_EDGES + e];
  int pos = atomicAdd(&cursor[dst], 1);
  ssrc[pos] = ei[e];
  const float* s = ea + (size_t)e*F_EDGE_;
  unsigned p[8];
  #pragma unroll
  for (int k=0;k<8;k++) p[k] = packbf(s[2*k], s[2*k+1]);
  uint4* d4 = (uint4*)(ea16 + (size_t)pos*16);
  d4[0] = make_uint4(p[0],p[1],p[2],p[3]);
  d4[1] = make_uint4(p[4],p[5],p[6],p[7]);
}

// ---------------- Fused GAT (streaming-eproj body, 16 nodes/block) ----------------
#define GAT_GRID (N_NODES/16)   // 6250, exact
__global__ __launch_bounds__(256) void k_gat_ep(const u16* __restrict__ xl,
                                                unsigned* xr_aggr,
                                                const u16* __restrict__ eproj,
                                                const float* __restrict__ att,
                                                const int* __restrict__ offsets,
                                                const int* __restrict__ ssrc){
  const int t = threadIdx.x;
  const int wave = t >> 6, lane = t & 63;
  const int c0 = lane*2;
  const float a0 = att[c0], a1 = att[c0+1];

  for (int k = 0; k < 4; k++){
    const int node = blockIdx.x*16 + wave*4 + k;   // always < N_NODES (grid exact)
    const f32x2 xrv = bp2v(xr_aggr[(size_t)node*64 + lane]);
    f32x2 accv = {0.f, 0.f};
    float den = 0.f;
    const int beg = offsets[node], end = offsets[node+1];
    for (int i = beg; i < end; i += 4){
      const int mm = end - i;
      const int i1 = (mm > 1) ? i+1 : i;
      const int i2 = (mm > 2) ? i+2 : i;
      const int i3 = (mm > 3) ? i+3 : i;
      int s0 = ssrc[i], s1 = ssrc[i1], s2 = ssrc[i2], s3 = ssrc[i3];
      unsigned ep0 = *(const unsigned*)(eproj + (size_t)i *128 + c0);
      unsigned ep1 = *(const unsigned*)(eproj + (size_t)i1*128 + c0);
      unsigned ep2 = *(const unsigned*)(eproj + (size_t)i2*128 + c0);
      unsigned ep3 = *(const unsigned*)(eproj + (size_t)i3*128 + c0);
      f32x2 vl0 = bp2v(*(const unsigned*)(xl + (size_t)s0*HID_ + c0));
      f32x2 vl1 = bp2v(*(const unsigned*)(xl + (size_t)s1*HID_ + c0));
      f32x2 vl2 = bp2v(*(const unsigned*)(xl + (size_t)s2*HID_ + c0));
      f32x2 vl3 = bp2v(*(const unsigned*)(xl + (size_t)s3*HID_ + c0));
      f32x2 v0 = vl0 + xrv + bp2v(ep0);
      f32x2 v1 = vl1 + xrv + bp2v(ep1);
      f32x2 v2 = vl2 + xrv + bp2v(ep2);
      f32x2 v3 = vl3 + xrv + bp2v(ep3);
      f32x2 w0 = v0*0.2f, w1 = v1*0.2f, w2 = v2*0.2f, w3 = v3*0.2f;
      v0.x = fmaxf(v0.x,w0.x); v0.y = fmaxf(v0.y,w0.y);
      v1.x = fmaxf(v1.x,w1.x); v1.y = fmaxf(v1.y,w1.y);
      v2.x = fmaxf(v2.x,w2.x); v2.y = fmaxf(v2.y,w2.y);
      v3.x = fmaxf(v3.x,w3.x); v3.y = fmaxf(v3.y,w3.y);
      float sc0 = v0.x*a0 + v0.y*a1;
      float sc1 = v1.x*a0 + v1.y*a1;
      float sc2 = v2.x*a0 + v2.y*a1;
      float sc3 = v3.x*a0 + v3.y*a1;
      sc0 += __shfl_xor(sc0, 1); sc1 += __shfl_xor(sc1, 1); sc2 += __shfl_xor(sc2, 1); sc3 += __shfl_xor(sc3, 1);
      sc0 += __shfl_xor(sc0, 2); sc1 += __shfl_xor(sc1, 2); sc2 += __shfl_xor(sc2, 2); sc3 += __shfl_xor(sc3, 2);
      sc0 += __shfl_xor(sc0, 4); sc1 += __shfl_xor(sc1, 4); sc2 += __shfl_xor(sc2, 4); sc3 += __shfl_xor(sc3, 4);
      sc0 += __shfl_xor(sc0, 8); sc1 += __shfl_xor(sc1, 8); sc2 += __shfl_xor(sc2, 8); sc3 += __shfl_xor(sc3, 8);
      float p0 = __expf(sc0);
      float p1 = (mm > 1) ? __expf(sc1) : 0.f;
      float p2 = (mm > 2) ? __expf(sc2) : 0.f;
      float p3 = (mm > 3) ? __expf(sc3) : 0.f;
      accv += p0*vl0 + p1*vl1 + p2*vl2 + p3*vl3;
      den  += p0 + p1 + p2 + p3;
    }
    float inv = 1.0f / (den + 1e-16f);
    xr_aggr[(size_t)node*64 + lane] = packbf(accv.x*inv, accv.y*inv);
  }
}

// ---------------- BN stats (bf16 aggr input) ----------------
__global__ __launch_bounds__(256) void k_bn_stats(const unsigned* __restrict__ aggr_b,
                                                  float* __restrict__ stats){
  __shared__ float redS[4][128], redQ[4][128];
  const int t = threadIdx.x;
  const int p = t & 63, rg = t >> 6;
  const int c0 = p*2;
  float s0=0.f, s1=0.f, q0=0.f, q1=0.f;
  for (int r = blockIdx.x*4 + rg; r < N_NODES; r += gridDim.x*4){
    float2 v = bp2f(aggr_b[(size_t)r*64 + p]);
    s0 += v.x; s1 += v.y; q0 += v.x*v.x; q1 += v.y*v.y;
  }
  redS[rg][c0] = s0; redS[rg][c0+1] = s1;
  redQ[rg][c0] = q0; redQ[rg][c0+1] = q1;
  __syncthreads();
  if (rg == 0){
    #pragma unroll
    for (int g=1; g<4; g++){
      s0 += redS[g][c0]; s1 += redS[g][c0+1];
      q0 += redQ[g][c0]; q1 += redQ[g][c0+1];
    }
    atomicAdd(&stats[c0],     s0);
    atomicAdd(&stats[c0+1],   s1);
    atomicAdd(&stats[128+c0],   q0);
    atomicAdd(&stats[128+c0+1], q1);
  }
}

// ---------------- BN apply + ELU (+ residual), uint4-vectorized ----------------
__global__ __launch_bounds__(256) void k_bn_apply(const unsigned* __restrict__ aggr_b,
                                                  const float* __restrict__ stats,
                                                  const float* __restrict__ gamma,
                                                  const float* __restrict__ beta,
                                                  u16* __restrict__ h, int residual){
  size_t i = (size_t)blockIdx.x*256 + threadIdx.x;   // uint4-group index (8 channels)
  if (i >= (size_t)N_NODES*16) return;
  const int c = (int)((i & 15) * 8);
  const float invn = 1.0f / (float)N_NODES;
  uint4 v4 = ((const uint4*)aggr_b)[i];
  uint4* hp = (uint4*)h + i;
  uint4 hv4 = make_uint4(0,0,0,0);
  if (residual) hv4 = *hp;
  unsigned vin[4]  = {v4.x, v4.y, v4.z, v4.w};
  unsigned hin[4]  = {hv4.x, hv4.y, hv4.z, hv4.w};
  unsigned outw[4];
  #pragma unroll
  for (int j=0;j<4;j++){
    int cc = c + j*2;
    float mu0  = stats[cc]   * invn,  mu1  = stats[cc+1]   * invn;
    float var0 = stats[128+cc]*invn - mu0*mu0;
    float var1 = stats[129+cc]*invn - mu1*mu1;
    float sc0 = rsqrtf(var0 + 1e-5f) * gamma[cc];
    float sc1 = rsqrtf(var1 + 1e-5f) * gamma[cc+1];
    float2 v = bp2f(vin[j]);
    float val0 = (v.x - mu0) * sc0 + beta[cc];
    float val1 = (v.y - mu1) * sc1 + beta[cc+1];
    val0 = val0 > 0.f ? val0 : expm1f(val0);
    val1 = val1 > 0.f ? val1 : expm1f(val1);
    if (residual){
      float2 hv = bp2f(hin[j]);
      val0 += hv.x; val1 += hv.y;
    }
    outw[j] = packbf(val0, val1);
  }
  *hp = make_uint4(outw[0], outw[1], outw[2], outw[3]);
}

// ---------------- Pool: segmented mean ----------------
__global__ __launch_bounds__(256) void k_pool_seg(const unsigned* __restrict__ h2,
                                                  const int* __restrict__ goff,
                                                  float* __restrict__ emb){
  __shared__ float redS[4][128];
  const int g = blockIdx.x, t = threadIdx.x;
  const int p = t & 63, rg = t >> 6;
  const int beg = goff[g], end = goff[g+1];
  float a0 = 0.f, a1 = 0.f;
  for (int r = beg + rg; r < end; r += 4){
    float2 v = bp2f(h2[(size_t)r*64 + p]);
    a0 += v.x; a1 += v.y;
  }
  redS[rg][p*2] = a0; redS[rg][p*2+1] = a1;
  __syncthreads();
  if (rg == 0){
    #pragma unroll
    for (int k=1;k<4;k++){ a0 += redS[k][p*2]; a1 += redS[k][p*2+1]; }
    float n = fmaxf((float)(end - beg), 1.f);
    emb[(size_t)g*HID_ + p*2]     = a0 / n;
    emb[(size_t)g*HID_ + p*2 + 1] = a1 / n;
  }
}

// ---------------- Per-task heads: 8 graphs per block ----------------
#define HG 8
__global__ __launch_bounds__(128) void k_heads(const float* __restrict__ emb,
                                               const float* __restrict__ mf,
                                               const int* __restrict__ fpi,
                                               const float* __restrict__ tw1,
                                               const float* __restrict__ tb1,
                                               const float* __restrict__ tw2,
                                               const float* __restrict__ tb2,
                                               float* __restrict__ out){
  const int task = blockIdx.y, g0 = blockIdx.x*HG;
  const int j = threadIdx.x;
  __shared__ float fused[HG][160];
  __shared__ float red[HG][128];
  for (int idx = j; idx < HG*160; idx += 128){
    int g = idx / 160, i = idx % 160;
    float v;
    if (i < 128) v = emb[(size_t)(g0+g)*HID_ + i];
    else         v = mf[(size_t)(g0+g)*2048 + fpi[task*32 + (i-128)]];
    fused[g][i] = v;
  }
  __syncthreads();
  const float* w1 = tw1 + (size_t)task*160*128;
  float acc[HG];
  float b1 = tb1[task*128 + j];
  #pragma unroll
  for (int g=0; g<HG; g++) acc[g] = b1;
  for (int i=0; i<160; i++){
    float wv = w1[(size_t)i*128 + j];
    #pragma unroll
    for (int g=0; g<HG; g++) acc[g] += fused[g][i] * wv;
  }
  float t2 = tw2[task*128 + j];
  #pragma unroll
  for (int g=0; g<HG; g++){
    float v = acc[g] > 0.f ? acc[g] : 0.f;
    red[g][j] = v * t2;
  }
  __syncthreads();
  int g = j >> 4, l16 = j & 15;
  float s = 0.f;
  #pragma unroll
  for (int k=0;k<8;k++) s += red[g][l16 + k*16];
  s += __shfl_xor(s, 1, 16);
  s += __shfl_xor(s, 2, 16);
  s += __shfl_xor(s, 4, 16);
  s += __shfl_xor(s, 8, 16);
  if (l16 == 0) out[(size_t)(g0+g)*N_TASK + task] = s + tb2[task];
}

extern "C" void kernel_launch(void* const* d_in, const int* in_sizes, int n_in,
                              void* d_out, int out_size, void* d_ws, size_t ws_size,
                              hipStream_t stream){
  const float* x    = (const float*)d_in[0];
  const int*   ei   = (const int*)  d_in[1];
  const float* ea   = (const float*)d_in[2];
  const int*   batch= (const int*)  d_in[3];
  const float* mf   = (const float*)d_in[4];
  const int*   fpi  = (const int*)  d_in[5];
  const float* Wl0  = (const float*)d_in[6];
  const float* bl0  = (const float*)d_in[7];
  const float* Wr0  = (const float*)d_in[8];
  const float* br0  = (const float*)d_in[9];
  const float* We0  = (const float*)d_in[10];
  const float* att0 = (const float*)d_in[11];
  const float* g0   = (const float*)d_in[13];
  const float* b0   = (const float*)d_in[14];
  const float* Wl   = (const float*)d_in[15];
  const float* bl   = (const float*)d_in[16];
  const float* Wr   = (const float*)d_in[17];
  const float* br   = (const float*)d_in[18];
  const float* We   = (const float*)d_in[19];
  const float* att  = (const float*)d_in[20];
  const float* gg   = (const float*)d_in[22];
  const float* bb   = (const float*)d_in[23];
  const float* tw1  = (const float*)d_in[24];
  const float* tb1  = (const float*)d_in[25];
  const float* tw2  = (const float*)d_in[26];
  const float* tb2  = (const float*)d_in[27];
  float* out = (float*)d_out;

  char* w = (char*)d_ws;
  auto alloc = [&](size_t bytes)->char*{ char* r = w; w += (bytes + 255) & ~(size_t)255; return r; };
  u16*   xl     = (u16*)  alloc((size_t)N_NODES*HID_*2);
  unsigned* xr_aggr = (unsigned*)alloc((size_t)N_NODES*64*4);
  u16*   h      = (u16*)  alloc((size_t)N_NODES*HID_*2);
  u16*   ea16   = (u16*)  alloc((size_t)N_EDGES*16*2);
  int*   counts = (int*)  alloc((size_t)N_NODES*4);
  float* stats4 = (float*)alloc(4*256*4);
  int*   offsets= (int*)  alloc((size_t)(N_NODES+1)*4);
  int*   cursor = (int*)  alloc((size_t)N_NODES*4);
  int*   incl   = (int*)  alloc((size_t)N_NODES*4);
  int*   bsum   = (int*)  alloc(256*4);
  int*   ssrc   = (int*)  alloc((size_t)N_EDGES*4);
  int*   goff   = (int*)  alloc((size_t)(N_GRAPH+1)*4);
  float* emb    = (float*)alloc((size_t)N_GRAPH*HID_*4);
  u16*   Wzl0   = (u16*)  alloc((size_t)F_NODE_*128*2);
  u16*   Wzr0   = (u16*)  alloc((size_t)F_NODE_*128*2);
  u16*   Wzl123 = (u16*)  alloc((size_t)3*HID_*128*2);
  u16*   Wzr123 = (u16*)  alloc((size_t)3*HID_*128*2);
  u16*   Wez4   = (u16*)  alloc((size_t)4*32*128*2);
  u16*   eproj  = (u16*)  alloc((size_t)N_EDGES*HID_*2);
  u16*   xbf    = (u16*)  alloc((size_t)N_NODES*F_NODE_*2);  // separate from eproj (no race); ea16 shrink pays for it

  const size_t zlen = (size_t)((char*)(stats4 + 4*256) - (char*)counts);
  const int nscan = (N_NODES + 511)/512;

  // prelude
  {
    WZ12 p;
    p.src[0] = Wl0; p.dst[0] = Wzl0; p.Ks[0] = F_NODE_; p.Kd[0] = F_NODE_;
    p.src[1] = Wr0; p.dst[1] = Wzr0; p.Ks[1] = F_NODE_; p.Kd[1] = F_NODE_;
    for (int i=0;i<3;i++){
      p.src[2+i] = Wl + (size_t)i*HID_*HID_; p.dst[2+i] = Wzl123 + (size_t)i*HID_*128; p.Ks[2+i] = HID_; p.Kd[2+i] = HID_;
      p.src[5+i] = Wr + (size_t)i*HID_*HID_; p.dst[5+i] = Wzr123 + (size_t)i*HID_*128; p.Ks[5+i] = HID_; p.Kd[5+i] = HID_;
    }
    p.src[8] = We0; p.dst[8] = Wez4; p.Ks[8] = F_EDGE_; p.Kd[8] = 32;
    for (int i=0;i<3;i++){
      p.src[9+i] = We + (size_t)i*F_EDGE_*HID_; p.dst[9+i] = Wez4 + (size_t)(i+1)*32*128; p.Ks[9+i] = F_EDGE_; p.Kd[9+i] = 32;
    }
    hipLaunchKernelGGL(k_wswz_all, dim3((HID_*128 + 255)/256, 12), dim3(256), 0, stream, p);
  }
  hipMemsetAsync(counts, 0, zlen, stream);
  hipLaunchKernelGGL(k_cast_hist, dim3(CAST_BLKS + EG256 + GOFF_BLKS), dim3(256), 0, stream,
                     x, xbf, ei, counts, batch, goff);
  hipLaunchKernelGGL(k_scan1,  dim3(nscan), dim3(512), 0, stream, counts, incl, bsum);
  hipLaunchKernelGGL(k_scan2,  dim3(1),     dim3(256), 0, stream, bsum, nscan);
  hipLaunchKernelGGL(k_scan3,  dim3(nscan), dim3(512), 0, stream, counts, incl, bsum, offsets, cursor);
  hipLaunchKernelGGL(k_scatter,dim3(EG256), dim3(256), 0, stream, ei, cursor, ssrc, ea, ea16);

  for (int layer = 0; layer < 4; layer++){
    const float *bl_, *br_, *att_, *g_, *b_;
    const u16 *Wzl_, *Wzr_, *Ain;
    int K;
    if (layer == 0){
      bl_=bl0; br_=br0; att_=att0; g_=g0; b_=b0;
      Wzl_ = Wzl0; Wzr_ = Wzr0; Ain = xbf; K = F_NODE_;
    } else {
      int i = layer - 1;
      bl_ = bl + (size_t)i*HID_;  br_ = br + (size_t)i*HID_;
      att_= att + (size_t)i*HID_;
      g_  = gg + (size_t)i*HID_;  b_  = bb + (size_t)i*HID_;
      Wzl_ = Wzl123 + (size_t)i*HID_*128;
      Wzr_ = Wzr123 + (size_t)i*HID_*128;
      Ain = h; K = HID_;
    }
    float* stats = stats4 + layer*256;
    hipLaunchKernelGGL(k_gemm_eproj, dim3(2*GEMM_GRID + EPROJ_GRID), dim3(256), 0, stream,
                       Ain, Wzl_, Wzr_, bl_, br_, xl, (u16*)xr_aggr, N_NODES, K,
                       ea16, Wez4 + (size_t)layer*32*128, eproj);
    hipLaunchKernelGGL(k_gat_ep, dim3(GAT_GRID), dim3(256), 0, stream,
                       xl, xr_aggr, eproj, att_, offsets, ssrc);
    hipLaunchKernelGGL(k_bn_stats, dim3(512), dim3(256), 0, stream, xr_aggr, stats);
    hipLaunchKernelGGL(k_bn_apply, dim3((N_NODES*16 + 255)/256), dim3(256), 0, stream,
                       xr_aggr, stats, g_, b_, h, layer > 0 ? 1 : 0);
  }
  hipLaunchKernelGGL(k_pool_seg, dim3(N_GRAPH), dim3(256), 0, stream, (const unsigned*)h, goff, emb);
  hipLaunchKernelGGL(k_heads, dim3(N_GRAPH/HG, N_TASK), dim3(128), 0, stream, emb, mf, fpi, tw1, tb1, tw2, tb2, out);
}

// Round 5
// 795.224 us; speedup vs baseline: 2.0023x; 1.0485x over previous
//
#include <hip/hip_runtime.h>
#include <hip/hip_bf16.h>

#define N_NODES 100000
#define N_EDGES 400000
#define F_NODE_ 64
#define F_EDGE_ 16
#define HID_ 128
#define N_GRAPH 1024
#define N_TASK 5

typedef unsigned short u16;
typedef __attribute__((ext_vector_type(8))) short frag8;   // 8 bf16 = 4 VGPRs
typedef __attribute__((ext_vector_type(4))) float f32x4;   // MFMA C/D
typedef __attribute__((ext_vector_type(2))) float f32x2;

__device__ __forceinline__ float bu2f(u16 v){ return __uint_as_float(((unsigned)v) << 16); }
__device__ __forceinline__ float2 bp2f(unsigned u){
  return make_float2(__uint_as_float(u << 16), __uint_as_float(u & 0xFFFF0000u));
}
__device__ __forceinline__ f32x2 bp2v(unsigned u){
  f32x2 r; r.x = __uint_as_float(u << 16); r.y = __uint_as_float(u & 0xFFFF0000u); return r;
}
__device__ __forceinline__ u16 f2bu(float f){
  __hip_bfloat16 h = __float2bfloat16(f);
  return *(u16*)&h;
}
__device__ __forceinline__ unsigned packbf(float a, float b){
  return (unsigned)f2bu(a) | ((unsigned)f2bu(b) << 16);
}

// ---------------- cast f32 -> bf16 fused with edge histogram + graph offsets ----------------
#define CAST_BLKS ((N_NODES*F_NODE_ + 255)/256)
#define EG256 ((N_EDGES + 255)/256)
#define GOFF_BLKS ((N_GRAPH + 1 + 255)/256)
__global__ __launch_bounds__(256) void k_cast_hist(const float* __restrict__ s, u16* __restrict__ d,
                                                   const int* __restrict__ ei, int* __restrict__ counts,
                                                   const int* __restrict__ batch, int* __restrict__ goff){
  int b = blockIdx.x;
  if (b < CAST_BLKS){
    int i = b*256 + threadIdx.x;
    if (i < N_NODES*F_NODE_) d[i] = f2bu(s[i]);
  } else if (b < CAST_BLKS + EG256){
    int e = (b - CAST_BLKS)*256 + threadIdx.x;
    if (e < N_EDGES) atomicAdd(&counts[ei[N_EDGES + e]], 1);
  } else {
    int g = (b - CAST_BLKS - EG256)*256 + threadIdx.x;
    if (g <= N_GRAPH){
      int lo = 0, hi = N_NODES;
      while (lo < hi){
        int mid = (lo + hi) >> 1;
        if (batch[mid] < g) lo = mid + 1; else hi = mid;
      }
      goff[g] = lo;
    }
  }
}

// ---------------- batched pre-swizzle: 8 W (K=64/128) + 4 We (K=16 zero-padded to 32) ----------------
struct WZ12 { const float* src[12]; u16* dst[12]; int Ks[12]; int Kd[12]; };
__global__ __launch_bounds__(256) void k_wswz_all(WZ12 p){
  const int s = blockIdx.y;
  const int Kd = p.Kd[s], Ks = p.Ks[s];
  int i = blockIdx.x*256 + threadIdx.x;
  if (i >= Kd*128) return;
  int k = i >> 7, n = i & 127;
  float v = (k < Ks) ? p.src[s][k*128 + n] : 0.f;
  int kk = k & 31, c = k >> 5;
  int quad = kk >> 3, j = kk & 7;
  int nt = n >> 4;
  int lane = quad*16 + (n & 15);
  p.dst[s][(((c*8 + nt)*64) + lane)*8 + j] = f2bu(v);
}

// ---------------- fused: paired MFMA GEMMs + eproj MFMA GEMM (flat grid) ----------------
// C-write: stage tile in LDS (quad-XOR swizzle, conflict-free) then coalesced uint4 stores.
#define GEMM_GRID ((N_NODES + 127)/128)   // 782
#define EPROJ_GRID ((N_EDGES + 127)/128)  // 3125
__global__ __launch_bounds__(256) void k_gemm_eproj(const u16* __restrict__ A,
                                                    const u16* __restrict__ Wzl,
                                                    const u16* __restrict__ Wzr,
                                                    const float* __restrict__ bl,
                                                    const float* __restrict__ br,
                                                    u16* __restrict__ Cl,
                                                    u16* Cr,
                                                    int M, int K,
                                                    const u16* __restrict__ ea16,
                                                    const u16* __restrict__ Wez,
                                                    u16* __restrict__ eproj){
  __shared__ u16 WS[128*128];
  const int t = threadIdx.x;
  const int b = blockIdx.x;
  if (b < 2*GEMM_GRID){
    const int which = (b >= GEMM_GRID);
    const int bx = which ? b - GEMM_GRID : b;
    const u16*   Wz   = which ? Wzr : Wzl;
    const float* bias = which ? br  : bl;
    u16*         C    = which ? Cr  : Cl;
    {
      const uint4* src = (const uint4*)Wz;
      uint4* dst = (uint4*)WS;
      const int n = (K*128) >> 3;
      for (int i = t; i < n; i += 256) dst[i] = src[i];
    }
    __syncthreads();
    const int w = t >> 6, l = t & 63;
    const int m = l & 15, quad = l >> 4;
    const int rowA0 = bx*128 + w*32 + m;
    const int rowA1 = rowA0 + 16;
    f32x4 acc[2][8];
    #pragma unroll
    for (int i=0;i<2;i++)
      #pragma unroll
      for (int j=0;j<8;j++) acc[i][j] = (f32x4){0.f,0.f,0.f,0.f};
    const int KC = K >> 5;
    for (int c = 0; c < KC; c++){
      frag8 a0 = {}, a1 = {};
      if (rowA0 < M) a0 = *(const frag8*)(A + (size_t)rowA0*K + c*32 + quad*8);
      if (rowA1 < M) a1 = *(const frag8*)(A + (size_t)rowA1*K + c*32 + quad*8);
      #pragma unroll
      for (int nt = 0; nt < 8; nt++){
        frag8 bfr = *(const frag8*)&WS[(((c*8 + nt)*64) + l)*8];
        acc[0][nt] = __builtin_amdgcn_mfma_f32_16x16x32_bf16(a0, bfr, acc[0][nt], 0,0,0);
        acc[1][nt] = __builtin_amdgcn_mfma_f32_16x16x32_bf16(a1, bfr, acc[1][nt], 0,0,0);
      }
    }
    // bias per nt (col = nt*16 + m)
    float bcv[8];
    #pragma unroll
    for (int nt=0; nt<8; nt++) bcv[nt] = bias[nt*16 + m];
    __syncthreads();          // all WS reads (MFMA) done
    const int sXor = quad << 4;   // ((row>>2)&3)<<4 == quad<<4 : quads -> disjoint bank groups
    #pragma unroll
    for (int rt = 0; rt < 2; rt++){
      #pragma unroll
      for (int r = 0; r < 4; r++){
        const int row = w*32 + rt*16 + quad*4 + r;
        #pragma unroll
        for (int nt = 0; nt < 8; nt++){
          const int col = nt*16 + m;
          WS[row*128 + (col ^ sXor)] = f2bu(acc[rt][nt][r] + bcv[nt]);
        }
      }
    }
    __syncthreads();
    #pragma unroll
    for (int i = 0; i < 8; i++){
      const int idx = i*256 + t;
      const int row = idx >> 4, k16 = idx & 15;
      const int grp = (k16*8) ^ (((row>>2)&3)<<4);
      const int grow = bx*128 + row;
      if (grow < M)
        *(uint4*)(C + (size_t)grow*128 + k16*8) = *(const uint4*)&WS[row*128 + grp];
    }
  } else {
    // eproj GEMM: 128 edges/block, K=32 via fragment zero-padding (ea16 stride 16; quad>=2 lanes stay zero)
    const int bx = b - 2*GEMM_GRID;
    {
      const uint4* s4 = (const uint4*)Wez;
      uint4* d4 = (uint4*)WS;
      for (int i = t; i < 512; i += 256) d4[i] = s4[i];
    }
    __syncthreads();
    const int w = t >> 6, l = t & 63, m = l & 15, quad = l >> 4;
    const int row0 = bx*128 + w*32 + m;
    const int row1 = row0 + 16;
    f32x4 acc[2][8];
    #pragma unroll
    for (int i=0;i<2;i++)
      #pragma unroll
      for (int j=0;j<8;j++) acc[i][j] = (f32x4){0.f,0.f,0.f,0.f};
    frag8 a0 = {}, a1 = {};
    if (quad < 2){
      a0 = *(const frag8*)(ea16 + (size_t)row0*16 + quad*8);   // grid exact: rows < N_EDGES
      a1 = *(const frag8*)(ea16 + (size_t)row1*16 + quad*8);
    }
    #pragma unroll
    for (int nt = 0; nt < 8; nt++){
      frag8 bfr = *(const frag8*)&WS[(nt*64 + l)*8];
      acc[0][nt] = __builtin_amdgcn_mfma_f32_16x16x32_bf16(a0, bfr, acc[0][nt], 0,0,0);
      acc[1][nt] = __builtin_amdgcn_mfma_f32_16x16x32_bf16(a1, bfr, acc[1][nt], 0,0,0);
    }
    __syncthreads();          // all WS reads (MFMA) done
    const int sXor = quad << 4;
    #pragma unroll
    for (int rt = 0; rt < 2; rt++){
      #pragma unroll
      for (int r = 0; r < 4; r++){
        const int row = w*32 + rt*16 + quad*4 + r;
        #pragma unroll
        for (int nt = 0; nt < 8; nt++){
          const int col = nt*16 + m;
          WS[row*128 + (col ^ sXor)] = f2bu(acc[rt][nt][r]);
        }
      }
    }
    __syncthreads();
    #pragma unroll
    for (int i = 0; i < 8; i++){
      const int idx = i*256 + t;
      const int row = idx >> 4, k16 = idx & 15;
      const int grp = (k16*8) ^ (((row>>2)&3)<<4);
      *(uint4*)(eproj + ((size_t)(bx*128 + row))*128 + k16*8) = *(const uint4*)&WS[row*128 + grp];
    }
  }
}

__global__ __launch_bounds__(512) void k_scan1(const int* __restrict__ counts,
                                               int* __restrict__ incl,
                                               int* __restrict__ bsum){
  __shared__ int s[512];
  const int t = threadIdx.x;
  int i = blockIdx.x*512 + t;
  int v = (i < N_NODES) ? counts[i] : 0;
  s[t] = v;
  __syncthreads();
  for (int off = 1; off < 512; off <<= 1){
    int x = (t >= off) ? s[t - off] : 0;
    __syncthreads();
    s[t] += x;
    __syncthreads();
  }
  if (i < N_NODES) incl[i] = s[t];
  if (t == 511) bsum[blockIdx.x] = s[511];
}

__global__ __launch_bounds__(256) void k_scan2(int* __restrict__ bsum, int nb){
  __shared__ int s[256];
  const int t = threadIdx.x;
  int v = (t < nb) ? bsum[t] : 0;
  s[t] = v;
  __syncthreads();
  for (int off = 1; off < 256; off <<= 1){
    int x = (t >= off) ? s[t - off] : 0;
    __syncthreads();
    s[t] += x;
    __syncthreads();
  }
  if (t < nb) bsum[t] = s[t] - v;
}

__global__ __launch_bounds__(512) void k_scan3(const int* __restrict__ counts,
                                               const int* __restrict__ incl,
                                               const int* __restrict__ bsum,
                                               int* __restrict__ offsets,
                                               int* __restrict__ cursor){
  int i = blockIdx.x*512 + threadIdx.x;
  if (i >= N_NODES) return;
  int o = bsum[blockIdx.x] + incl[i];
  offsets[i + 1] = o;
  cursor[i]      = o - counts[i];
  if (i == 0) offsets[0] = 0;
}

// scatter: src index + bf16 edge features into CSR order ([E][16] bf16)
__global__ __launch_bounds__(256) void k_scatter(const int* __restrict__ ei,
                                                 int* __restrict__ cursor,
                                                 int* __restrict__ ssrc,
                                                 const float* __restrict__ ea,
                                                 u16* __restrict__ ea16){
  int e = blockIdx.x*256 + threadIdx.x;
  if (e >= N_EDGES) return;
  int dst = ei[N_EDGES + e];
  int pos = atomicAdd(&cursor[dst], 1);
  ssrc[pos] = ei[e];
  const float* s = ea + (size_t)e*F_EDGE_;
  unsigned p[8];
  #pragma unroll
  for (int k=0;k<8;k++) p[k] = packbf(s[2*k], s[2*k+1]);
  uint4* d4 = (uint4*)(ea16 + (size_t)pos*16);
  d4[0] = make_uint4(p[0],p[1],p[2],p[3]);
  d4[1] = make_uint4(p[4],p[5],p[6],p[7]);
}

// ---------------- Fused GAT (streaming-eproj body, 16 nodes/block) ----------------
#define GAT_GRID (N_NODES/16)   // 6250, exact
__global__ __launch_bounds__(256) void k_gat_ep(const u16* __restrict__ xl,
                                                unsigned* xr_aggr,
                                                const u16* __restrict__ eproj,
                                                const float* __restrict__ att,
                                                const int* __restrict__ offsets,
                                                const int* __restrict__ ssrc){
  const int t = threadIdx.x;
  const int wave = t >> 6, lane = t & 63;
  const int c0 = lane*2;
  const float a0 = att[c0], a1 = att[c0+1];

  for (int k = 0; k < 4; k++){
    const int node = blockIdx.x*16 + wave*4 + k;   // always < N_NODES (grid exact)
    const f32x2 xrv = bp2v(xr_aggr[(size_t)node*64 + lane]);
    f32x2 accv = {0.f, 0.f};
    float den = 0.f;
    const int beg = offsets[node], end = offsets[node+1];
    for (int i = beg; i < end; i += 4){
      const int mm = end - i;
      const int i1 = (mm > 1) ? i+1 : i;
      const int i2 = (mm > 2) ? i+2 : i;
      const int i3 = (mm > 3) ? i+3 : i;
      int s0 = ssrc[i], s1 = ssrc[i1], s2 = ssrc[i2], s3 = ssrc[i3];
      unsigned ep0 = *(const unsigned*)(eproj + (size_t)i *128 + c0);
      unsigned ep1 = *(const unsigned*)(eproj + (size_t)i1*128 + c0);
      unsigned ep2 = *(const unsigned*)(eproj + (size_t)i2*128 + c0);
      unsigned ep3 = *(const unsigned*)(eproj + (size_t)i3*128 + c0);
      f32x2 vl0 = bp2v(*(const unsigned*)(xl + (size_t)s0*HID_ + c0));
      f32x2 vl1 = bp2v(*(const unsigned*)(xl + (size_t)s1*HID_ + c0));
      f32x2 vl2 = bp2v(*(const unsigned*)(xl + (size_t)s2*HID_ + c0));
      f32x2 vl3 = bp2v(*(const unsigned*)(xl + (size_t)s3*HID_ + c0));
      f32x2 v0 = vl0 + xrv + bp2v(ep0);
      f32x2 v1 = vl1 + xrv + bp2v(ep1);
      f32x2 v2 = vl2 + xrv + bp2v(ep2);
      f32x2 v3 = vl3 + xrv + bp2v(ep3);
      f32x2 w0 = v0*0.2f, w1 = v1*0.2f, w2 = v2*0.2f, w3 = v3*0.2f;
      v0.x = fmaxf(v0.x,w0.x); v0.y = fmaxf(v0.y,w0.y);
      v1.x = fmaxf(v1.x,w1.x); v1.y = fmaxf(v1.y,w1.y);
      v2.x = fmaxf(v2.x,w2.x); v2.y = fmaxf(v2.y,w2.y);
      v3.x = fmaxf(v3.x,w3.x); v3.y = fmaxf(v3.y,w3.y);
      float sc0 = v0.x*a0 + v0.y*a1;
      float sc1 = v1.x*a0 + v1.y*a1;
      float sc2 = v2.x*a0 + v2.y*a1;
      float sc3 = v3.x*a0 + v3.y*a1;
      sc0 += __shfl_xor(sc0, 1); sc1 += __shfl_xor(sc1, 1); sc2 += __shfl_xor(sc2, 1); sc3 += __shfl_xor(sc3, 1);
      sc0 += __shfl_xor(sc0, 2); sc1 += __shfl_xor(sc1, 2); sc2 += __shfl_xor(sc2, 2); sc3 += __shfl_xor(sc3, 2);
      sc0 += __shfl_xor(sc0, 4); sc1 += __shfl_xor(sc1, 4); sc2 += __shfl_xor(sc2, 4); sc3 += __shfl_xor(sc3, 4);
      sc0 += __shfl_xor(sc0, 8); sc1 += __shfl_xor(sc1, 8); sc2 += __shfl_xor(sc2, 8); sc3 += __shfl_xor(sc3, 8);
      float p0 = __expf(sc0);
      float p1 = (mm > 1) ? __expf(sc1) : 0.f;
      float p2 = (mm > 2) ? __expf(sc2) : 0.f;
      float p3 = (mm > 3) ? __expf(sc3) : 0.f;
      accv += p0*vl0 + p1*vl1 + p2*vl2 + p3*vl3;
      den  += p0 + p1 + p2 + p3;
    }
    float inv = 1.0f / (den + 1e-16f);
    xr_aggr[(size_t)node*64 + lane] = packbf(accv.x*inv, accv.y*inv);
  }
}

// ---------------- BN stats (bf16 aggr input) ----------------
__global__ __launch_bounds__(256) void k_bn_stats(const unsigned* __restrict__ aggr_b,
                                                  float* __restrict__ stats){
  __shared__ float redS[4][128], redQ[4][128];
  const int t = threadIdx.x;
  const int p = t & 63, rg = t >> 6;
  const int c0 = p*2;
  float s0=0.f, s1=0.f, q0=0.f, q1=0.f;
  for (int r = blockIdx.x*4 + rg; r < N_NODES; r += gridDim.x*4){
    float2 v = bp2f(aggr_b[(size_t)r*64 + p]);
    s0 += v.x; s1 += v.y; q0 += v.x*v.x; q1 += v.y*v.y;
  }
  redS[rg][c0] = s0; redS[rg][c0+1] = s1;
  redQ[rg][c0] = q0; redQ[rg][c0+1] = q1;
  __syncthreads();
  if (rg == 0){
    #pragma unroll
    for (int g=1; g<4; g++){
      s0 += redS[g][c0]; s1 += redS[g][c0+1];
      q0 += redQ[g][c0]; q1 += redQ[g][c0+1];
    }
    atomicAdd(&stats[c0],     s0);
    atomicAdd(&stats[c0+1],   s1);
    atomicAdd(&stats[128+c0],   q0);
    atomicAdd(&stats[128+c0+1], q1);
  }
}

// ---------------- BN apply + ELU (+ residual), uint4-vectorized ----------------
__global__ __launch_bounds__(256) void k_bn_apply(const unsigned* __restrict__ aggr_b,
                                                  const float* __restrict__ stats,
                                                  const float* __restrict__ gamma,
                                                  const float* __restrict__ beta,
                                                  u16* __restrict__ h, int residual){
  size_t i = (size_t)blockIdx.x*256 + threadIdx.x;   // uint4-group index (8 channels)
  if (i >= (size_t)N_NODES*16) return;
  const int c = (int)((i & 15) * 8);
  const float invn = 1.0f / (float)N_NODES;
  uint4 v4 = ((const uint4*)aggr_b)[i];
  uint4* hp = (uint4*)h + i;
  uint4 hv4 = make_uint4(0,0,0,0);
  if (residual) hv4 = *hp;
  unsigned vin[4]  = {v4.x, v4.y, v4.z, v4.w};
  unsigned hin[4]  = {hv4.x, hv4.y, hv4.z, hv4.w};
  unsigned outw[4];
  #pragma unroll
  for (int j=0;j<4;j++){
    int cc = c + j*2;
    float mu0  = stats[cc]   * invn,  mu1  = stats[cc+1]   * invn;
    float var0 = stats[128+cc]*invn - mu0*mu0;
    float var1 = stats[129+cc]*invn - mu1*mu1;
    float sc0 = rsqrtf(var0 + 1e-5f) * gamma[cc];
    float sc1 = rsqrtf(var1 + 1e-5f) * gamma[cc+1];
    float2 v = bp2f(vin[j]);
    float val0 = (v.x - mu0) * sc0 + beta[cc];
    float val1 = (v.y - mu1) * sc1 + beta[cc+1];
    val0 = val0 > 0.f ? val0 : expm1f(val0);
    val1 = val1 > 0.f ? val1 : expm1f(val1);
    if (residual){
      float2 hv = bp2f(hin[j]);
      val0 += hv.x; val1 += hv.y;
    }
    outw[j] = packbf(val0, val1);
  }
  *hp = make_uint4(outw[0], outw[1], outw[2], outw[3]);
}

// ---------------- Pool: segmented mean ----------------
__global__ __launch_bounds__(256) void k_pool_seg(const unsigned* __restrict__ h2,
                                                  const int* __restrict__ goff,
                                                  float* __restrict__ emb){
  __shared__ float redS[4][128];
  const int g = blockIdx.x, t = threadIdx.x;
  const int p = t & 63, rg = t >> 6;
  const int beg = goff[g], end = goff[g+1];
  float a0 = 0.f, a1 = 0.f;
  for (int r = beg + rg; r < end; r += 4){
    float2 v = bp2f(h2[(size_t)r*64 + p]);
    a0 += v.x; a1 += v.y;
  }
  redS[rg][p*2] = a0; redS[rg][p*2+1] = a1;
  __syncthreads();
  if (rg == 0){
    #pragma unroll
    for (int k=1;k<4;k++){ a0 += redS[k][p*2]; a1 += redS[k][p*2+1]; }
    float n = fmaxf((float)(end - beg), 1.f);
    emb[(size_t)g*HID_ + p*2]     = a0 / n;
    emb[(size_t)g*HID_ + p*2 + 1] = a1 / n;
  }
}

// ---------------- Per-task heads: 8 graphs per block ----------------
#define HG 8
__global__ __launch_bounds__(128) void k_heads(const float* __restrict__ emb,
                                               const float* __restrict__ mf,
                                               const int* __restrict__ fpi,
                                               const float* __restrict__ tw1,
                                               const float* __restrict__ tb1,
                                               const float* __restrict__ tw2,
                                               const float* __restrict__ tb2,
                                               float* __restrict__ out){
  const int task = blockIdx.y, g0 = blockIdx.x*HG;
  const int j = threadIdx.x;
  __shared__ float fused[HG][160];
  __shared__ float red[HG][128];
  for (int idx = j; idx < HG*160; idx += 128){
    int g = idx / 160, i = idx % 160;
    float v;
    if (i < 128) v = emb[(size_t)(g0+g)*HID_ + i];
    else         v = mf[(size_t)(g0+g)*2048 + fpi[task*32 + (i-128)]];
    fused[g][i] = v;
  }
  __syncthreads();
  const float* w1 = tw1 + (size_t)task*160*128;
  float acc[HG];
  float b1 = tb1[task*128 + j];
  #pragma unroll
  for (int g=0; g<HG; g++) acc[g] = b1;
  for (int i=0; i<160; i++){
    float wv = w1[(size_t)i*128 + j];
    #pragma unroll
    for (int g=0; g<HG; g++) acc[g] += fused[g][i] * wv;
  }
  float t2 = tw2[task*128 + j];
  #pragma unroll
  for (int g=0; g<HG; g++){
    float v = acc[g] > 0.f ? acc[g] : 0.f;
    red[g][j] = v * t2;
  }
  __syncthreads();
  int g = j >> 4, l16 = j & 15;
  float s = 0.f;
  #pragma unroll
  for (int k=0;k<8;k++) s += red[g][l16 + k*16];
  s += __shfl_xor(s, 1, 16);
  s += __shfl_xor(s, 2, 16);
  s += __shfl_xor(s, 4, 16);
  s += __shfl_xor(s, 8, 16);
  if (l16 == 0) out[(size_t)(g0+g)*N_TASK + task] = s + tb2[task];
}

extern "C" void kernel_launch(void* const* d_in, const int* in_sizes, int n_in,
                              void* d_out, int out_size, void* d_ws, size_t ws_size,
                              hipStream_t stream){
  const float* x    = (const float*)d_in[0];
  const int*   ei   = (const int*)  d_in[1];
  const float* ea   = (const float*)d_in[2];
  const int*   batch= (const int*)  d_in[3];
  const float* mf   = (const float*)d_in[4];
  const int*   fpi  = (const int*)  d_in[5];
  const float* Wl0  = (const float*)d_in[6];
  const float* bl0  = (const float*)d_in[7];
  const float* Wr0  = (const float*)d_in[8];
  const float* br0  = (const float*)d_in[9];
  const float* We0  = (const float*)d_in[10];
  const float* att0 = (const float*)d_in[11];
  const float* g0   = (const float*)d_in[13];
  const float* b0   = (const float*)d_in[14];
  const float* Wl   = (const float*)d_in[15];
  const float* bl   = (const float*)d_in[16];
  const float* Wr   = (const float*)d_in[17];
  const float* br   = (const float*)d_in[18];
  const float* We   = (const float*)d_in[19];
  const float* att  = (const float*)d_in[20];
  const float* gg   = (const float*)d_in[22];
  const float* bb   = (const float*)d_in[23];
  const float* tw1  = (const float*)d_in[24];
  const float* tb1  = (const float*)d_in[25];
  const float* tw2  = (const float*)d_in[26];
  const float* tb2  = (const float*)d_in[27];
  float* out = (float*)d_out;

  char* w = (char*)d_ws;
  auto alloc = [&](size_t bytes)->char*{ char* r = w; w += (bytes + 255) & ~(size_t)255; return r; };
  u16*   xl     = (u16*)  alloc((size_t)N_NODES*HID_*2);
  unsigned* xr_aggr = (unsigned*)alloc((size_t)N_NODES*64*4);
  u16*   h      = (u16*)  alloc((size_t)N_NODES*HID_*2);
  u16*   ea16   = (u16*)  alloc((size_t)N_EDGES*16*2);
  int*   counts = (int*)  alloc((size_t)N_NODES*4);
  float* stats4 = (float*)alloc(4*256*4);
  int*   offsets= (int*)  alloc((size_t)(N_NODES+1)*4);
  int*   cursor = (int*)  alloc((size_t)N_NODES*4);
  int*   incl   = (int*)  alloc((size_t)N_NODES*4);
  int*   bsum   = (int*)  alloc(256*4);
  int*   ssrc   = (int*)  alloc((size_t)N_EDGES*4);
  int*   goff   = (int*)  alloc((size_t)(N_GRAPH+1)*4);
  float* emb    = (float*)alloc((size_t)N_GRAPH*HID_*4);
  u16*   Wzl0   = (u16*)  alloc((size_t)F_NODE_*128*2);
  u16*   Wzr0   = (u16*)  alloc((size_t)F_NODE_*128*2);
  u16*   Wzl123 = (u16*)  alloc((size_t)3*HID_*128*2);
  u16*   Wzr123 = (u16*)  alloc((size_t)3*HID_*128*2);
  u16*   Wez4   = (u16*)  alloc((size_t)4*32*128*2);
  u16*   eproj  = (u16*)  alloc((size_t)N_EDGES*HID_*2);
  u16*   xbf    = (u16*)  alloc((size_t)N_NODES*F_NODE_*2);  // separate from eproj (no race)

  const size_t zlen = (size_t)((char*)(stats4 + 4*256) - (char*)counts);
  const int nscan = (N_NODES + 511)/512;

  // prelude
  {
    WZ12 p;
    p.src[0] = Wl0; p.dst[0] = Wzl0; p.Ks[0] = F_NODE_; p.Kd[0] = F_NODE_;
    p.src[1] = Wr0; p.dst[1] = Wzr0; p.Ks[1] = F_NODE_; p.Kd[1] = F_NODE_;
    for (int i=0;i<3;i++){
      p.src[2+i] = Wl + (size_t)i*HID_*HID_; p.dst[2+i] = Wzl123 + (size_t)i*HID_*128; p.Ks[2+i] = HID_; p.Kd[2+i] = HID_;
      p.src[5+i] = Wr + (size_t)i*HID_*HID_; p.dst[5+i] = Wzr123 + (size_t)i*HID_*128; p.Ks[5+i] = HID_; p.Kd[5+i] = HID_;
    }
    p.src[8] = We0; p.dst[8] = Wez4; p.Ks[8] = F_EDGE_; p.Kd[8] = 32;
    for (int i=0;i<3;i++){
      p.src[9+i] = We + (size_t)i*F_EDGE_*HID_; p.dst[9+i] = Wez4 + (size_t)(i+1)*32*128; p.Ks[9+i] = F_EDGE_; p.Kd[9+i] = 32;
    }
    hipLaunchKernelGGL(k_wswz_all, dim3((HID_*128 + 255)/256, 12), dim3(256), 0, stream, p);
  }
  hipMemsetAsync(counts, 0, zlen, stream);
  hipLaunchKernelGGL(k_cast_hist, dim3(CAST_BLKS + EG256 + GOFF_BLKS), dim3(256), 0, stream,
                     x, xbf, ei, counts, batch, goff);
  hipLaunchKernelGGL(k_scan1,  dim3(nscan), dim3(512), 0, stream, counts, incl, bsum);
  hipLaunchKernelGGL(k_scan2,  dim3(1),     dim3(256), 0, stream, bsum, nscan);
  hipLaunchKernelGGL(k_scan3,  dim3(nscan), dim3(512), 0, stream, counts, incl, bsum, offsets, cursor);
  hipLaunchKernelGGL(k_scatter,dim3(EG256), dim3(256), 0, stream, ei, cursor, ssrc, ea, ea16);

  for (int layer = 0; layer < 4; layer++){
    const float *bl_, *br_, *att_, *g_, *b_;
    const u16 *Wzl_, *Wzr_, *Ain;
    int K;
    if (layer == 0){
      bl_=bl0; br_=br0; att_=att0; g_=g0; b_=b0;
      Wzl_ = Wzl0; Wzr_ = Wzr0; Ain = xbf; K = F_NODE_;
    } else {
      int i = layer - 1;
      bl_ = bl + (size_t)i*HID_;  br_ = br + (size_t)i*HID_;
      att_= att + (size_t)i*HID_;
      g_  = gg + (size_t)i*HID_;  b_  = bb + (size_t)i*HID_;
      Wzl_ = Wzl123 + (size_t)i*HID_*128;
      Wzr_ = Wzr123 + (size_t)i*HID_*128;
      Ain = h; K = HID_;
    }
    float* stats = stats4 + layer*256;
    hipLaunchKernelGGL(k_gemm_eproj, dim3(2*GEMM_GRID + EPROJ_GRID), dim3(256), 0, stream,
                       Ain, Wzl_, Wzr_, bl_, br_, xl, (u16*)xr_aggr, N_NODES, K,
                       ea16, Wez4 + (size_t)layer*32*128, eproj);
    hipLaunchKernelGGL(k_gat_ep, dim3(GAT_GRID), dim3(256), 0, stream,
                       xl, xr_aggr, eproj, att_, offsets, ssrc);
    hipLaunchKernelGGL(k_bn_stats, dim3(512), dim3(256), 0, stream, xr_aggr, stats);
    hipLaunchKernelGGL(k_bn_apply, dim3((N_NODES*16 + 255)/256), dim3(256), 0, stream,
                       xr_aggr, stats, g_, b_, h, layer > 0 ? 1 : 0);
  }
  hipLaunchKernelGGL(k_pool_seg, dim3(N_GRAPH), dim3(256), 0, stream, (const unsigned*)h, goff, emb);
  hipLaunchKernelGGL(k_heads, dim3(N_GRAPH/HG, N_TASK), dim3(128), 0, stream, emb, mf, fpi, tw1, tb1, tw2, tb2, out);
}

// Round 6
// 781.913 us; speedup vs baseline: 2.0364x; 1.0170x over previous
//
#include <hip/hip_runtime.h>
#include <hip/hip_bf16.h>

#define N_NODES 100000
#define N_EDGES 400000
#define F_NODE_ 64
#define F_EDGE_ 16
#define HID_ 128
#define N_GRAPH 1024
#define N_TASK 5

typedef unsigned short u16;
typedef __attribute__((ext_vector_type(8))) short frag8;   // 8 bf16 = 4 VGPRs
typedef __attribute__((ext_vector_type(4))) float f32x4;   // MFMA C/D
typedef __attribute__((ext_vector_type(2))) float f32x2;

__device__ __forceinline__ float bu2f(u16 v){ return __uint_as_float(((unsigned)v) << 16); }
__device__ __forceinline__ float2 bp2f(unsigned u){
  return make_float2(__uint_as_float(u << 16), __uint_as_float(u & 0xFFFF0000u));
}
__device__ __forceinline__ f32x2 bp2v(unsigned u){
  f32x2 r; r.x = __uint_as_float(u << 16); r.y = __uint_as_float(u & 0xFFFF0000u); return r;
}
__device__ __forceinline__ u16 f2bu(float f){
  __hip_bfloat16 h = __float2bfloat16(f);
  return *(u16*)&h;
}
__device__ __forceinline__ unsigned packbf(float a, float b){
  return (unsigned)f2bu(a) | ((unsigned)f2bu(b) << 16);
}

// ---------------- cast f32 -> bf16 fused with edge histogram + graph offsets ----------------
#define CAST_BLKS ((N_NODES*F_NODE_ + 255)/256)
#define EG256 ((N_EDGES + 255)/256)
#define GOFF_BLKS ((N_GRAPH + 1 + 255)/256)
__global__ __launch_bounds__(256) void k_cast_hist(const float* __restrict__ s, u16* __restrict__ d,
                                                   const int* __restrict__ ei, int* __restrict__ counts,
                                                   const int* __restrict__ batch, int* __restrict__ goff){
  int b = blockIdx.x;
  if (b < CAST_BLKS){
    int i = b*256 + threadIdx.x;
    if (i < N_NODES*F_NODE_) d[i] = f2bu(s[i]);
  } else if (b < CAST_BLKS + EG256){
    int e = (b - CAST_BLKS)*256 + threadIdx.x;
    if (e < N_EDGES) atomicAdd(&counts[ei[N_EDGES + e]], 1);
  } else {
    int g = (b - CAST_BLKS - EG256)*256 + threadIdx.x;
    if (g <= N_GRAPH){
      int lo = 0, hi = N_NODES;
      while (lo < hi){
        int mid = (lo + hi) >> 1;
        if (batch[mid] < g) lo = mid + 1; else hi = mid;
      }
      goff[g] = lo;
    }
  }
}

// ---------------- batched pre-swizzle: 8 W (K=64/128) + 4 We (K=16 zero-padded to 32) ----------------
struct WZ12 { const float* src[12]; u16* dst[12]; int Ks[12]; int Kd[12]; };
__global__ __launch_bounds__(256) void k_wswz_all(WZ12 p){
  const int s = blockIdx.y;
  const int Kd = p.Kd[s], Ks = p.Ks[s];
  int i = blockIdx.x*256 + threadIdx.x;
  if (i >= Kd*128) return;
  int k = i >> 7, n = i & 127;
  float v = (k < Ks) ? p.src[s][k*128 + n] : 0.f;
  int kk = k & 31, c = k >> 5;
  int quad = kk >> 3, j = kk & 7;
  int nt = n >> 4;
  int lane = quad*16 + (n & 15);
  p.dst[s][(((c*8 + nt)*64) + lane)*8 + j] = f2bu(v);
}

// ---------------- fused: paired MFMA GEMMs + eproj MFMA GEMM (flat grid) ----------------
// C-write: stage tile in LDS (quad-XOR swizzle, conflict-free) then coalesced uint4 stores.
#define GEMM_GRID ((N_NODES + 127)/128)   // 782
#define EPROJ_GRID ((N_EDGES + 127)/128)  // 3125
__global__ __launch_bounds__(256) void k_gemm_eproj(const u16* __restrict__ A,
                                                    const u16* __restrict__ Wzl,
                                                    const u16* __restrict__ Wzr,
                                                    const float* __restrict__ bl,
                                                    const float* __restrict__ br,
                                                    u16* __restrict__ Cl,
                                                    u16* Cr,
                                                    int M, int K,
                                                    const u16* __restrict__ ea16,
                                                    const u16* __restrict__ Wez,
                                                    u16* __restrict__ eproj){
  __shared__ u16 WS[128*128];
  const int t = threadIdx.x;
  const int b = blockIdx.x;
  if (b < 2*GEMM_GRID){
    const int which = (b >= GEMM_GRID);
    const int bx = which ? b - GEMM_GRID : b;
    const u16*   Wz   = which ? Wzr : Wzl;
    const float* bias = which ? br  : bl;
    u16*         C    = which ? Cr  : Cl;
    {
      const uint4* src = (const uint4*)Wz;
      uint4* dst = (uint4*)WS;
      const int n = (K*128) >> 3;
      for (int i = t; i < n; i += 256) dst[i] = src[i];
    }
    __syncthreads();
    const int w = t >> 6, l = t & 63;
    const int m = l & 15, quad = l >> 4;
    const int rowA0 = bx*128 + w*32 + m;
    const int rowA1 = rowA0 + 16;
    f32x4 acc[2][8];
    #pragma unroll
    for (int i=0;i<2;i++)
      #pragma unroll
      for (int j=0;j<8;j++) acc[i][j] = (f32x4){0.f,0.f,0.f,0.f};
    const int KC = K >> 5;
    for (int c = 0; c < KC; c++){
      frag8 a0 = {}, a1 = {};
      if (rowA0 < M) a0 = *(const frag8*)(A + (size_t)rowA0*K + c*32 + quad*8);
      if (rowA1 < M) a1 = *(const frag8*)(A + (size_t)rowA1*K + c*32 + quad*8);
      #pragma unroll
      for (int nt = 0; nt < 8; nt++){
        frag8 bfr = *(const frag8*)&WS[(((c*8 + nt)*64) + l)*8];
        acc[0][nt] = __builtin_amdgcn_mfma_f32_16x16x32_bf16(a0, bfr, acc[0][nt], 0,0,0);
        acc[1][nt] = __builtin_amdgcn_mfma_f32_16x16x32_bf16(a1, bfr, acc[1][nt], 0,0,0);
      }
    }
    // bias per nt (col = nt*16 + m)
    float bcv[8];
    #pragma unroll
    for (int nt=0; nt<8; nt++) bcv[nt] = bias[nt*16 + m];
    __syncthreads();          // all WS reads (MFMA) done
    const int sXor = quad << 4;   // quads -> disjoint bank groups
    #pragma unroll
    for (int rt = 0; rt < 2; rt++){
      #pragma unroll
      for (int r = 0; r < 4; r++){
        const int row = w*32 + rt*16 + quad*4 + r;
        #pragma unroll
        for (int nt = 0; nt < 8; nt++){
          const int col = nt*16 + m;
          WS[row*128 + (col ^ sXor)] = f2bu(acc[rt][nt][r] + bcv[nt]);
        }
      }
    }
    __syncthreads();
    #pragma unroll
    for (int i = 0; i < 8; i++){
      const int idx = i*256 + t;
      const int row = idx >> 4, k16 = idx & 15;
      const int grp = (k16*8) ^ (((row>>2)&3)<<4);
      const int grow = bx*128 + row;
      if (grow < M)
        *(uint4*)(C + (size_t)grow*128 + k16*8) = *(const uint4*)&WS[row*128 + grp];
    }
  } else {
    // eproj GEMM: 128 edges/block, K=32 via fragment zero-padding
    const int bx = b - 2*GEMM_GRID;
    {
      const uint4* s4 = (const uint4*)Wez;
      uint4* d4 = (uint4*)WS;
      for (int i = t; i < 512; i += 256) d4[i] = s4[i];
    }
    __syncthreads();
    const int w = t >> 6, l = t & 63, m = l & 15, quad = l >> 4;
    const int row0 = bx*128 + w*32 + m;
    const int row1 = row0 + 16;
    f32x4 acc[2][8];
    #pragma unroll
    for (int i=0;i<2;i++)
      #pragma unroll
      for (int j=0;j<8;j++) acc[i][j] = (f32x4){0.f,0.f,0.f,0.f};
    frag8 a0 = {}, a1 = {};
    if (quad < 2){
      a0 = *(const frag8*)(ea16 + (size_t)row0*16 + quad*8);   // grid exact: rows < N_EDGES
      a1 = *(const frag8*)(ea16 + (size_t)row1*16 + quad*8);
    }
    #pragma unroll
    for (int nt = 0; nt < 8; nt++){
      frag8 bfr = *(const frag8*)&WS[(nt*64 + l)*8];
      acc[0][nt] = __builtin_amdgcn_mfma_f32_16x16x32_bf16(a0, bfr, acc[0][nt], 0,0,0);
      acc[1][nt] = __builtin_amdgcn_mfma_f32_16x16x32_bf16(a1, bfr, acc[1][nt], 0,0,0);
    }
    __syncthreads();          // all WS reads (MFMA) done
    const int sXor = quad << 4;
    #pragma unroll
    for (int rt = 0; rt < 2; rt++){
      #pragma unroll
      for (int r = 0; r < 4; r++){
        const int row = w*32 + rt*16 + quad*4 + r;
        #pragma unroll
        for (int nt = 0; nt < 8; nt++){
          const int col = nt*16 + m;
          WS[row*128 + (col ^ sXor)] = f2bu(acc[rt][nt][r]);
        }
      }
    }
    __syncthreads();
    #pragma unroll
    for (int i = 0; i < 8; i++){
      const int idx = i*256 + t;
      const int row = idx >> 4, k16 = idx & 15;
      const int grp = (k16*8) ^ (((row>>2)&3)<<4);
      *(uint4*)(eproj + ((size_t)(bx*128 + row))*128 + k16*8) = *(const uint4*)&WS[row*128 + grp];
    }
  }
}

__global__ __launch_bounds__(512) void k_scan1(const int* __restrict__ counts,
                                               int* __restrict__ incl,
                                               int* __restrict__ bsum){
  __shared__ int s[512];
  const int t = threadIdx.x;
  int i = blockIdx.x*512 + t;
  int v = (i < N_NODES) ? counts[i] : 0;
  s[t] = v;
  __syncthreads();
  for (int off = 1; off < 512; off <<= 1){
    int x = (t >= off) ? s[t - off] : 0;
    __syncthreads();
    s[t] += x;
    __syncthreads();
  }
  if (i < N_NODES) incl[i] = s[t];
  if (t == 511) bsum[blockIdx.x] = s[511];
}

__global__ __launch_bounds__(256) void k_scan2(int* __restrict__ bsum, int nb){
  __shared__ int s[256];
  const int t = threadIdx.x;
  int v = (t < nb) ? bsum[t] : 0;
  s[t] = v;
  __syncthreads();
  for (int off = 1; off < 256; off <<= 1){
    int x = (t >= off) ? s[t - off] : 0;
    __syncthreads();
    s[t] += x;
    __syncthreads();
  }
  if (t < nb) bsum[t] = s[t] - v;
}

__global__ __launch_bounds__(512) void k_scan3(const int* __restrict__ counts,
                                               const int* __restrict__ incl,
                                               const int* __restrict__ bsum,
                                               int* __restrict__ offsets,
                                               int* __restrict__ cursor){
  int i = blockIdx.x*512 + threadIdx.x;
  if (i >= N_NODES) return;
  int o = bsum[blockIdx.x] + incl[i];
  offsets[i + 1] = o;
  cursor[i]      = o - counts[i];
  if (i == 0) offsets[0] = 0;
}

// scatter: src index + bf16 edge features into CSR order ([E][16] bf16)
__global__ __launch_bounds__(256) void k_scatter(const int* __restrict__ ei,
                                                 int* __restrict__ cursor,
                                                 int* __restrict__ ssrc,
                                                 const float* __restrict__ ea,
                                                 u16* __restrict__ ea16){
  int e = blockIdx.x*256 + threadIdx.x;
  if (e >= N_EDGES) return;
  int dst = ei[N_EDGES + e];
  int pos = atomicAdd(&cursor[dst], 1);
  ssrc[pos] = ei[e];
  const float* s = ea + (size_t)e*F_EDGE_;
  unsigned p[8];
  #pragma unroll
  for (int k=0;k<8;k++) p[k] = packbf(s[2*k], s[2*k+1]);
  uint4* d4 = (uint4*)(ea16 + (size_t)pos*16);
  d4[0] = make_uint4(p[0],p[1],p[2],p[3]);
  d4[1] = make_uint4(p[4],p[5],p[6],p[7]);
}

// ---------------- Fused GAT v14: 2 nodes per wave (lanes 0-31 / 32-63), 4 ch/lane ----------------
// Per edge, each half-wave does the work: 8B loads, 3-shfl head reduce (head = 8 lanes).
#define GAT_GRID (N_NODES/16)   // 6250, exact: 4 waves x 2 halves x 2 k-iters = 16 nodes/block
__global__ __launch_bounds__(256) void k_gat_ep(const u16* __restrict__ xl,
                                                unsigned* xr_aggr,
                                                const u16* __restrict__ eproj,
                                                const float* __restrict__ att,
                                                const int* __restrict__ offsets,
                                                const int* __restrict__ ssrc){
  const int t = threadIdx.x;
  const int wave = t >> 6, lane = t & 63;
  const int half = lane >> 5, l32 = lane & 31;
  const int c0 = l32*4;                         // 4 channels per lane
  const float4 av = *(const float4*)(att + c0);

  for (int k = 0; k < 2; k++){
    const int node = blockIdx.x*16 + wave*4 + k*2 + half;   // < N_NODES (grid exact)
    const uint2 xru = *(const uint2*)(xr_aggr + (size_t)node*64 + l32*2);
    const f32x2 xr0 = bp2v(xru.x), xr1 = bp2v(xru.y);
    f32x2 acc0 = {0.f,0.f}, acc1 = {0.f,0.f};
    float den = 0.f;
    const int beg = offsets[node], end = offsets[node+1];
    int it = (end - beg + 3) >> 2;
    int oit = __shfl_xor(it, 32);
    const int maxit = it > oit ? it : oit;
    int i = beg;
    for (int n = 0; n < maxit; n++, i += 4){
      const int mm = end - i;                   // may be <= 0 for exhausted half
      int ib = (mm > 0) ? i : beg;
      ib = ib < N_EDGES ? ib : N_EDGES - 1;     // zero-degree tail safety
      const int i0 = ib;
      const int i1 = (mm > 1) ? i+1 : ib;
      const int i2 = (mm > 2) ? i+2 : ib;
      const int i3 = (mm > 3) ? i+3 : ib;
      const int s0 = ssrc[i0], s1 = ssrc[i1], s2 = ssrc[i2], s3 = ssrc[i3];
      const uint2 e0 = *(const uint2*)(eproj + (size_t)i0*128 + c0);
      const uint2 e1 = *(const uint2*)(eproj + (size_t)i1*128 + c0);
      const uint2 e2 = *(const uint2*)(eproj + (size_t)i2*128 + c0);
      const uint2 e3 = *(const uint2*)(eproj + (size_t)i3*128 + c0);
      const uint2 x0 = *(const uint2*)(xl + (size_t)s0*HID_ + c0);
      const uint2 x1 = *(const uint2*)(xl + (size_t)s1*HID_ + c0);
      const uint2 x2 = *(const uint2*)(xl + (size_t)s2*HID_ + c0);
      const uint2 x3 = *(const uint2*)(xl + (size_t)s3*HID_ + c0);
      const f32x2 vl00 = bp2v(x0.x), vl01 = bp2v(x0.y);
      const f32x2 vl10 = bp2v(x1.x), vl11 = bp2v(x1.y);
      const f32x2 vl20 = bp2v(x2.x), vl21 = bp2v(x2.y);
      const f32x2 vl30 = bp2v(x3.x), vl31 = bp2v(x3.y);
      f32x2 v00 = vl00 + xr0 + bp2v(e0.x), v01 = vl01 + xr1 + bp2v(e0.y);
      f32x2 v10 = vl10 + xr0 + bp2v(e1.x), v11 = vl11 + xr1 + bp2v(e1.y);
      f32x2 v20 = vl20 + xr0 + bp2v(e2.x), v21 = vl21 + xr1 + bp2v(e2.y);
      f32x2 v30 = vl30 + xr0 + bp2v(e3.x), v31 = vl31 + xr1 + bp2v(e3.y);
      f32x2 w;
      w = v00*0.2f; v00.x = fmaxf(v00.x,w.x); v00.y = fmaxf(v00.y,w.y);
      w = v01*0.2f; v01.x = fmaxf(v01.x,w.x); v01.y = fmaxf(v01.y,w.y);
      w = v10*0.2f; v10.x = fmaxf(v10.x,w.x); v10.y = fmaxf(v10.y,w.y);
      w = v11*0.2f; v11.x = fmaxf(v11.x,w.x); v11.y = fmaxf(v11.y,w.y);
      w = v20*0.2f; v20.x = fmaxf(v20.x,w.x); v20.y = fmaxf(v20.y,w.y);
      w = v21*0.2f; v21.x = fmaxf(v21.x,w.x); v21.y = fmaxf(v21.y,w.y);
      w = v30*0.2f; v30.x = fmaxf(v30.x,w.x); v30.y = fmaxf(v30.y,w.y);
      w = v31*0.2f; v31.x = fmaxf(v31.x,w.x); v31.y = fmaxf(v31.y,w.y);
      float sc0 = v00.x*av.x + v00.y*av.y + v01.x*av.z + v01.y*av.w;
      float sc1 = v10.x*av.x + v10.y*av.y + v11.x*av.z + v11.y*av.w;
      float sc2 = v20.x*av.x + v20.y*av.y + v21.x*av.z + v21.y*av.w;
      float sc3 = v30.x*av.x + v30.y*av.y + v31.x*av.z + v31.y*av.w;
      sc0 += __shfl_xor(sc0, 1); sc1 += __shfl_xor(sc1, 1); sc2 += __shfl_xor(sc2, 1); sc3 += __shfl_xor(sc3, 1);
      sc0 += __shfl_xor(sc0, 2); sc1 += __shfl_xor(sc1, 2); sc2 += __shfl_xor(sc2, 2); sc3 += __shfl_xor(sc3, 2);
      sc0 += __shfl_xor(sc0, 4); sc1 += __shfl_xor(sc1, 4); sc2 += __shfl_xor(sc2, 4); sc3 += __shfl_xor(sc3, 4);
      const float p0 = (mm > 0) ? __expf(sc0) : 0.f;
      const float p1 = (mm > 1) ? __expf(sc1) : 0.f;
      const float p2 = (mm > 2) ? __expf(sc2) : 0.f;
      const float p3 = (mm > 3) ? __expf(sc3) : 0.f;
      acc0 += p0*vl00 + p1*vl10 + p2*vl20 + p3*vl30;
      acc1 += p0*vl01 + p1*vl11 + p2*vl21 + p3*vl31;
      den  += p0 + p1 + p2 + p3;
    }
    const float inv = 1.0f / (den + 1e-16f);
    uint2 outv;
    outv.x = packbf(acc0.x*inv, acc0.y*inv);
    outv.y = packbf(acc1.x*inv, acc1.y*inv);
    *(uint2*)(xr_aggr + (size_t)node*64 + l32*2) = outv;
  }
}

// ---------------- BN stats (bf16 aggr input) ----------------
__global__ __launch_bounds__(256) void k_bn_stats(const unsigned* __restrict__ aggr_b,
                                                  float* __restrict__ stats){
  __shared__ float redS[4][128], redQ[4][128];
  const int t = threadIdx.x;
  const int p = t & 63, rg = t >> 6;
  const int c0 = p*2;
  float s0=0.f, s1=0.f, q0=0.f, q1=0.f;
  for (int r = blockIdx.x*4 + rg; r < N_NODES; r += gridDim.x*4){
    float2 v = bp2f(aggr_b[(size_t)r*64 + p]);
    s0 += v.x; s1 += v.y; q0 += v.x*v.x; q1 += v.y*v.y;
  }
  redS[rg][c0] = s0; redS[rg][c0+1] = s1;
  redQ[rg][c0] = q0; redQ[rg][c0+1] = q1;
  __syncthreads();
  if (rg == 0){
    #pragma unroll
    for (int g=1; g<4; g++){
      s0 += redS[g][c0]; s1 += redS[g][c0+1];
      q0 += redQ[g][c0]; q1 += redQ[g][c0+1];
    }
    atomicAdd(&stats[c0],     s0);
    atomicAdd(&stats[c0+1],   s1);
    atomicAdd(&stats[128+c0],   q0);
    atomicAdd(&stats[128+c0+1], q1);
  }
}

// ---------------- BN apply + ELU (+ residual), uint4-vectorized ----------------
__global__ __launch_bounds__(256) void k_bn_apply(const unsigned* __restrict__ aggr_b,
                                                  const float* __restrict__ stats,
                                                  const float* __restrict__ gamma,
                                                  const float* __restrict__ beta,
                                                  u16* __restrict__ h, int residual){
  size_t i = (size_t)blockIdx.x*256 + threadIdx.x;   // uint4-group index (8 channels)
  if (i >= (size_t)N_NODES*16) return;
  const int c = (int)((i & 15) * 8);
  const float invn = 1.0f / (float)N_NODES;
  uint4 v4 = ((const uint4*)aggr_b)[i];
  uint4* hp = (uint4*)h + i;
  uint4 hv4 = make_uint4(0,0,0,0);
  if (residual) hv4 = *hp;
  unsigned vin[4]  = {v4.x, v4.y, v4.z, v4.w};
  unsigned hin[4]  = {hv4.x, hv4.y, hv4.z, hv4.w};
  unsigned outw[4];
  #pragma unroll
  for (int j=0;j<4;j++){
    int cc = c + j*2;
    float mu0  = stats[cc]   * invn,  mu1  = stats[cc+1]   * invn;
    float var0 = stats[128+cc]*invn - mu0*mu0;
    float var1 = stats[129+cc]*invn - mu1*mu1;
    float sc0 = rsqrtf(var0 + 1e-5f) * gamma[cc];
    float sc1 = rsqrtf(var1 + 1e-5f) * gamma[cc+1];
    float2 v = bp2f(vin[j]);
    float val0 = (v.x - mu0) * sc0 + beta[cc];
    float val1 = (v.y - mu1) * sc1 + beta[cc+1];
    val0 = val0 > 0.f ? val0 : expm1f(val0);
    val1 = val1 > 0.f ? val1 : expm1f(val1);
    if (residual){
      float2 hv = bp2f(hin[j]);
      val0 += hv.x; val1 += hv.y;
    }
    outw[j] = packbf(val0, val1);
  }
  *hp = make_uint4(outw[0], outw[1], outw[2], outw[3]);
}

// ---------------- Pool: segmented mean ----------------
__global__ __launch_bounds__(256) void k_pool_seg(const unsigned* __restrict__ h2,
                                                  const int* __restrict__ goff,
                                                  float* __restrict__ emb){
  __shared__ float redS[4][128];
  const int g = blockIdx.x, t = threadIdx.x;
  const int p = t & 63, rg = t >> 6;
  const int beg = goff[g], end = goff[g+1];
  float a0 = 0.f, a1 = 0.f;
  for (int r = beg + rg; r < end; r += 4){
    float2 v = bp2f(h2[(size_t)r*64 + p]);
    a0 += v.x; a1 += v.y;
  }
  redS[rg][p*2] = a0; redS[rg][p*2+1] = a1;
  __syncthreads();
  if (rg == 0){
    #pragma unroll
    for (int k=1;k<4;k++){ a0 += redS[k][p*2]; a1 += redS[k][p*2+1]; }
    float n = fmaxf((float)(end - beg), 1.f);
    emb[(size_t)g*HID_ + p*2]     = a0 / n;
    emb[(size_t)g*HID_ + p*2 + 1] = a1 / n;
  }
}

// ---------------- Per-task heads: 8 graphs per block ----------------
#define HG 8
__global__ __launch_bounds__(128) void k_heads(const float* __restrict__ emb,
                                               const float* __restrict__ mf,
                                               const int* __restrict__ fpi,
                                               const float* __restrict__ tw1,
                                               const float* __restrict__ tb1,
                                               const float* __restrict__ tw2,
                                               const float* __restrict__ tb2,
                                               float* __restrict__ out){
  const int task = blockIdx.y, g0 = blockIdx.x*HG;
  const int j = threadIdx.x;
  __shared__ float fused[HG][160];
  __shared__ float red[HG][128];
  for (int idx = j; idx < HG*160; idx += 128){
    int g = idx / 160, i = idx % 160;
    float v;
    if (i < 128) v = emb[(size_t)(g0+g)*HID_ + i];
    else         v = mf[(size_t)(g0+g)*2048 + fpi[task*32 + (i-128)]];
    fused[g][i] = v;
  }
  __syncthreads();
  const float* w1 = tw1 + (size_t)task*160*128;
  float acc[HG];
  float b1 = tb1[task*128 + j];
  #pragma unroll
  for (int g=0; g<HG; g++) acc[g] = b1;
  for (int i=0; i<160; i++){
    float wv = w1[(size_t)i*128 + j];
    #pragma unroll
    for (int g=0; g<HG; g++) acc[g] += fused[g][i] * wv;
  }
  float t2 = tw2[task*128 + j];
  #pragma unroll
  for (int g=0; g<HG; g++){
    float v = acc[g] > 0.f ? acc[g] : 0.f;
    red[g][j] = v * t2;
  }
  __syncthreads();
  int g = j >> 4, l16 = j & 15;
  float s = 0.f;
  #pragma unroll
  for (int k=0;k<8;k++) s += red[g][l16 + k*16];
  s += __shfl_xor(s, 1, 16);
  s += __shfl_xor(s, 2, 16);
  s += __shfl_xor(s, 4, 16);
  s += __shfl_xor(s, 8, 16);
  if (l16 == 0) out[(size_t)(g0+g)*N_TASK + task] = s + tb2[task];
}

extern "C" void kernel_launch(void* const* d_in, const int* in_sizes, int n_in,
                              void* d_out, int out_size, void* d_ws, size_t ws_size,
                              hipStream_t stream){
  const float* x    = (const float*)d_in[0];
  const int*   ei   = (const int*)  d_in[1];
  const float* ea   = (const float*)d_in[2];
  const int*   batch= (const int*)  d_in[3];
  const float* mf   = (const float*)d_in[4];
  const int*   fpi  = (const int*)  d_in[5];
  const float* Wl0  = (const float*)d_in[6];
  const float* bl0  = (const float*)d_in[7];
  const float* Wr0  = (const float*)d_in[8];
  const float* br0  = (const float*)d_in[9];
  const float* We0  = (const float*)d_in[10];
  const float* att0 = (const float*)d_in[11];
  const float* g0   = (const float*)d_in[13];
  const float* b0   = (const float*)d_in[14];
  const float* Wl   = (const float*)d_in[15];
  const float* bl   = (const float*)d_in[16];
  const float* Wr   = (const float*)d_in[17];
  const float* br   = (const float*)d_in[18];
  const float* We   = (const float*)d_in[19];
  const float* att  = (const float*)d_in[20];
  const float* gg   = (const float*)d_in[22];
  const float* bb   = (const float*)d_in[23];
  const float* tw1  = (const float*)d_in[24];
  const float* tb1  = (const float*)d_in[25];
  const float* tw2  = (const float*)d_in[26];
  const float* tb2  = (const float*)d_in[27];
  float* out = (float*)d_out;

  char* w = (char*)d_ws;
  auto alloc = [&](size_t bytes)->char*{ char* r = w; w += (bytes + 255) & ~(size_t)255; return r; };
  u16*   xl     = (u16*)  alloc((size_t)N_NODES*HID_*2);
  unsigned* xr_aggr = (unsigned*)alloc((size_t)N_NODES*64*4);
  u16*   h      = (u16*)  alloc((size_t)N_NODES*HID_*2);
  u16*   ea16   = (u16*)  alloc((size_t)N_EDGES*16*2);
  int*   counts = (int*)  alloc((size_t)N_NODES*4);
  float* stats4 = (float*)alloc(4*256*4);
  int*   offsets= (int*)  alloc((size_t)(N_NODES+1)*4);
  int*   cursor = (int*)  alloc((size_t)N_NODES*4);
  int*   incl   = (int*)  alloc((size_t)N_NODES*4);
  int*   bsum   = (int*)  alloc(256*4);
  int*   ssrc   = (int*)  alloc((size_t)N_EDGES*4);
  int*   goff   = (int*)  alloc((size_t)(N_GRAPH+1)*4);
  float* emb    = (float*)alloc((size_t)N_GRAPH*HID_*4);
  u16*   Wzl0   = (u16*)  alloc((size_t)F_NODE_*128*2);
  u16*   Wzr0   = (u16*)  alloc((size_t)F_NODE_*128*2);
  u16*   Wzl123 = (u16*)  alloc((size_t)3*HID_*128*2);
  u16*   Wzr123 = (u16*)  alloc((size_t)3*HID_*128*2);
  u16*   Wez4   = (u16*)  alloc((size_t)4*32*128*2);
  u16*   eproj  = (u16*)  alloc((size_t)N_EDGES*HID_*2);
  u16*   xbf    = (u16*)  alloc((size_t)N_NODES*F_NODE_*2);  // separate from eproj (no race)

  const size_t zlen = (size_t)((char*)(stats4 + 4*256) - (char*)counts);
  const int nscan = (N_NODES + 511)/512;

  // prelude
  {
    WZ12 p;
    p.src[0] = Wl0; p.dst[0] = Wzl0; p.Ks[0] = F_NODE_; p.Kd[0] = F_NODE_;
    p.src[1] = Wr0; p.dst[1] = Wzr0; p.Ks[1] = F_NODE_; p.Kd[1] = F_NODE_;
    for (int i=0;i<3;i++){
      p.src[2+i] = Wl + (size_t)i*HID_*HID_; p.dst[2+i] = Wzl123 + (size_t)i*HID_*128; p.Ks[2+i] = HID_; p.Kd[2+i] = HID_;
      p.src[5+i] = Wr + (size_t)i*HID_*HID_; p.dst[5+i] = Wzr123 + (size_t)i*HID_*128; p.Ks[5+i] = HID_; p.Kd[5+i] = HID_;
    }
    p.src[8] = We0; p.dst[8] = Wez4; p.Ks[8] = F_EDGE_; p.Kd[8] = 32;
    for (int i=0;i<3;i++){
      p.src[9+i] = We + (size_t)i*F_EDGE_*HID_; p.dst[9+i] = Wez4 + (size_t)(i+1)*32*128; p.Ks[9+i] = F_EDGE_; p.Kd[9+i] = 32;
    }
    hipLaunchKernelGGL(k_wswz_all, dim3((HID_*128 + 255)/256, 12), dim3(256), 0, stream, p);
  }
  hipMemsetAsync(counts, 0, zlen, stream);
  hipLaunchKernelGGL(k_cast_hist, dim3(CAST_BLKS + EG256 + GOFF_BLKS), dim3(256), 0, stream,
                     x, xbf, ei, counts, batch, goff);
  hipLaunchKernelGGL(k_scan1,  dim3(nscan), dim3(512), 0, stream, counts, incl, bsum);
  hipLaunchKernelGGL(k_scan2,  dim3(1),     dim3(256), 0, stream, bsum, nscan);
  hipLaunchKernelGGL(k_scan3,  dim3(nscan), dim3(512), 0, stream, counts, incl, bsum, offsets, cursor);
  hipLaunchKernelGGL(k_scatter,dim3(EG256), dim3(256), 0, stream, ei, cursor, ssrc, ea, ea16);

  for (int layer = 0; layer < 4; layer++){
    const float *bl_, *br_, *att_, *g_, *b_;
    const u16 *Wzl_, *Wzr_, *Ain;
    int K;
    if (layer == 0){
      bl_=bl0; br_=br0; att_=att0; g_=g0; b_=b0;
      Wzl_ = Wzl0; Wzr_ = Wzr0; Ain = xbf; K = F_NODE_;
    } else {
      int i = layer - 1;
      bl_ = bl + (size_t)i*HID_;  br_ = br + (size_t)i*HID_;
      att_= att + (size_t)i*HID_;
      g_  = gg + (size_t)i*HID_;  b_  = bb + (size_t)i*HID_;
      Wzl_ = Wzl123 + (size_t)i*HID_*128;
      Wzr_ = Wzr123 + (size_t)i*HID_*128;
      Ain = h; K = HID_;
    }
    float* stats = stats4 + layer*256;
    hipLaunchKernelGGL(k_gemm_eproj, dim3(2*GEMM_GRID + EPROJ_GRID), dim3(256), 0, stream,
                       Ain, Wzl_, Wzr_, bl_, br_, xl, (u16*)xr_aggr, N_NODES, K,
                       ea16, Wez4 + (size_t)layer*32*128, eproj);
    hipLaunchKernelGGL(k_gat_ep, dim3(GAT_GRID), dim3(256), 0, stream,
                       xl, xr_aggr, eproj, att_, offsets, ssrc);
    hipLaunchKernelGGL(k_bn_stats, dim3(512), dim3(256), 0, stream, xr_aggr, stats);
    hipLaunchKernelGGL(k_bn_apply, dim3((N_NODES*16 + 255)/256), dim3(256), 0, stream,
                       xr_aggr, stats, g_, b_, h, layer > 0 ? 1 : 0);
  }
  hipLaunchKernelGGL(k_pool_seg, dim3(N_GRAPH), dim3(256), 0, stream, (const unsigned*)h, goff, emb);
  hipLaunchKernelGGL(k_heads, dim3(N_GRAPH/HG, N_TASK), dim3(128), 0, stream, emb, mf, fpi, tw1, tb1, tw2, tb2, out);
}

// Round 7
// 761.577 us; speedup vs baseline: 2.0908x; 1.0267x over previous
//
#include <hip/hip_runtime.h>
#include <hip/hip_bf16.h>

#define N_NODES 100000
#define N_EDGES 400000
#define F_NODE_ 64
#define F_EDGE_ 16
#define HID_ 128
#define N_GRAPH 1024
#define N_TASK 5

typedef unsigned short u16;
typedef __attribute__((ext_vector_type(8))) short frag8;   // 8 bf16 = 4 VGPRs
typedef __attribute__((ext_vector_type(4))) float f32x4;   // MFMA C/D
typedef __attribute__((ext_vector_type(2))) float f32x2;

__device__ __forceinline__ float bu2f(u16 v){ return __uint_as_float(((unsigned)v) << 16); }
__device__ __forceinline__ float2 bp2f(unsigned u){
  return make_float2(__uint_as_float(u << 16), __uint_as_float(u & 0xFFFF0000u));
}
__device__ __forceinline__ f32x2 bp2v(unsigned u){
  f32x2 r; r.x = __uint_as_float(u << 16); r.y = __uint_as_float(u & 0xFFFF0000u); return r;
}
__device__ __forceinline__ u16 f2bu(float f){
  __hip_bfloat16 h = __float2bfloat16(f);
  return *(u16*)&h;
}
__device__ __forceinline__ unsigned packbf(float a, float b){
  return (unsigned)f2bu(a) | ((unsigned)f2bu(b) << 16);
}

struct WZ12 { const float* src[12]; u16* dst[12]; int Ks[12]; int Kd[12]; };

// ---------------- cast f32->bf16 + edge histogram + graph offsets + W pre-swizzle (flat grid) ----------------
#define CAST_BLKS ((N_NODES*F_NODE_ + 255)/256)
#define EG256 ((N_EDGES + 255)/256)
#define GOFF_BLKS ((N_GRAPH + 1 + 255)/256)
#define WSWZ_BLKS (12*64)
__global__ __launch_bounds__(256) void k_cast_hist(const float* __restrict__ s, u16* __restrict__ d,
                                                   const int* __restrict__ ei, int* __restrict__ counts,
                                                   const int* __restrict__ batch, int* __restrict__ goff,
                                                   WZ12 p){
  int b = blockIdx.x;
  if (b < CAST_BLKS){
    int i = b*256 + threadIdx.x;
    if (i < N_NODES*F_NODE_) d[i] = f2bu(s[i]);
  } else if (b < CAST_BLKS + EG256){
    int e = (b - CAST_BLKS)*256 + threadIdx.x;
    if (e < N_EDGES) atomicAdd(&counts[ei[N_EDGES + e]], 1);
  } else if (b < CAST_BLKS + EG256 + GOFF_BLKS){
    int g = (b - CAST_BLKS - EG256)*256 + threadIdx.x;
    if (g <= N_GRAPH){
      int lo = 0, hi = N_NODES;
      while (lo < hi){
        int mid = (lo + hi) >> 1;
        if (batch[mid] < g) lo = mid + 1; else hi = mid;
      }
      goff[g] = lo;
    }
  } else {
    int bb = b - CAST_BLKS - EG256 - GOFF_BLKS;   // 0..767
    const int sW = bb >> 6;
    const int Kd = p.Kd[sW], Ks = p.Ks[sW];
    int i = (bb & 63)*256 + threadIdx.x;
    if (i >= Kd*128) return;
    int k = i >> 7, n = i & 127;
    float v = (k < Ks) ? p.src[sW][k*128 + n] : 0.f;
    int kk = k & 31, c = k >> 5;
    int quad = kk >> 3, j = kk & 7;
    int nt = n >> 4;
    int lane = quad*16 + (n & 15);
    p.dst[sW][(((c*8 + nt)*64) + lane)*8 + j] = f2bu(v);
  }
}

// ---------------- fused: paired MFMA GEMMs + eproj MFMA GEMM (flat grid) ----------------
// C-write: stage tile in LDS (quad-XOR swizzle, conflict-free) then coalesced uint4 stores.
#define GEMM_GRID ((N_NODES + 127)/128)   // 782
#define EPROJ_GRID ((N_EDGES + 127)/128)  // 3125
__global__ __launch_bounds__(256) void k_gemm_eproj(const u16* __restrict__ A,
                                                    const u16* __restrict__ Wzl,
                                                    const u16* __restrict__ Wzr,
                                                    const float* __restrict__ bl,
                                                    const float* __restrict__ br,
                                                    u16* __restrict__ Cl,
                                                    u16* Cr,
                                                    int M, int K,
                                                    const u16* __restrict__ ea16,
                                                    const u16* __restrict__ Wez,
                                                    u16* __restrict__ eproj){
  __shared__ u16 WS[128*128];
  const int t = threadIdx.x;
  const int b = blockIdx.x;
  if (b < 2*GEMM_GRID){
    const int which = (b >= GEMM_GRID);
    const int bx = which ? b - GEMM_GRID : b;
    const u16*   Wz   = which ? Wzr : Wzl;
    const float* bias = which ? br  : bl;
    u16*         C    = which ? Cr  : Cl;
    {
      const uint4* src = (const uint4*)Wz;
      uint4* dst = (uint4*)WS;
      const int n = (K*128) >> 3;
      for (int i = t; i < n; i += 256) dst[i] = src[i];
    }
    __syncthreads();
    const int w = t >> 6, l = t & 63;
    const int m = l & 15, quad = l >> 4;
    const int rowA0 = bx*128 + w*32 + m;
    const int rowA1 = rowA0 + 16;
    f32x4 acc[2][8];
    #pragma unroll
    for (int i=0;i<2;i++)
      #pragma unroll
      for (int j=0;j<8;j++) acc[i][j] = (f32x4){0.f,0.f,0.f,0.f};
    const int KC = K >> 5;
    for (int c = 0; c < KC; c++){
      frag8 a0 = {}, a1 = {};
      if (rowA0 < M) a0 = *(const frag8*)(A + (size_t)rowA0*K + c*32 + quad*8);
      if (rowA1 < M) a1 = *(const frag8*)(A + (size_t)rowA1*K + c*32 + quad*8);
      #pragma unroll
      for (int nt = 0; nt < 8; nt++){
        frag8 bfr = *(const frag8*)&WS[(((c*8 + nt)*64) + l)*8];
        acc[0][nt] = __builtin_amdgcn_mfma_f32_16x16x32_bf16(a0, bfr, acc[0][nt], 0,0,0);
        acc[1][nt] = __builtin_amdgcn_mfma_f32_16x16x32_bf16(a1, bfr, acc[1][nt], 0,0,0);
      }
    }
    float bcv[8];
    #pragma unroll
    for (int nt=0; nt<8; nt++) bcv[nt] = bias[nt*16 + m];
    __syncthreads();          // all WS reads (MFMA) done
    const int sXor = quad << 4;   // quads -> disjoint bank groups
    #pragma unroll
    for (int rt = 0; rt < 2; rt++){
      #pragma unroll
      for (int r = 0; r < 4; r++){
        const int row = w*32 + rt*16 + quad*4 + r;
        #pragma unroll
        for (int nt = 0; nt < 8; nt++){
          const int col = nt*16 + m;
          WS[row*128 + (col ^ sXor)] = f2bu(acc[rt][nt][r] + bcv[nt]);
        }
      }
    }
    __syncthreads();
    #pragma unroll
    for (int i = 0; i < 8; i++){
      const int idx = i*256 + t;
      const int row = idx >> 4, k16 = idx & 15;
      const int grp = (k16*8) ^ (((row>>2)&3)<<4);
      const int grow = bx*128 + row;
      if (grow < M)
        *(uint4*)(C + (size_t)grow*128 + k16*8) = *(const uint4*)&WS[row*128 + grp];
    }
  } else {
    // eproj GEMM: 128 edges/block, K=32 via fragment zero-padding
    const int bx = b - 2*GEMM_GRID;
    {
      const uint4* s4 = (const uint4*)Wez;
      uint4* d4 = (uint4*)WS;
      for (int i = t; i < 512; i += 256) d4[i] = s4[i];
    }
    __syncthreads();
    const int w = t >> 6, l = t & 63, m = l & 15, quad = l >> 4;
    const int row0 = bx*128 + w*32 + m;
    const int row1 = row0 + 16;
    f32x4 acc[2][8];
    #pragma unroll
    for (int i=0;i<2;i++)
      #pragma unroll
      for (int j=0;j<8;j++) acc[i][j] = (f32x4){0.f,0.f,0.f,0.f};
    frag8 a0 = {}, a1 = {};
    if (quad < 2){
      a0 = *(const frag8*)(ea16 + (size_t)row0*16 + quad*8);   // grid exact: rows < N_EDGES
      a1 = *(const frag8*)(ea16 + (size_t)row1*16 + quad*8);
    }
    #pragma unroll
    for (int nt = 0; nt < 8; nt++){
      frag8 bfr = *(const frag8*)&WS[(nt*64 + l)*8];
      acc[0][nt] = __builtin_amdgcn_mfma_f32_16x16x32_bf16(a0, bfr, acc[0][nt], 0,0,0);
      acc[1][nt] = __builtin_amdgcn_mfma_f32_16x16x32_bf16(a1, bfr, acc[1][nt], 0,0,0);
    }
    __syncthreads();
    const int sXor = quad << 4;
    #pragma unroll
    for (int rt = 0; rt < 2; rt++){
      #pragma unroll
      for (int r = 0; r < 4; r++){
        const int row = w*32 + rt*16 + quad*4 + r;
        #pragma unroll
        for (int nt = 0; nt < 8; nt++){
          const int col = nt*16 + m;
          WS[row*128 + (col ^ sXor)] = f2bu(acc[rt][nt][r]);
        }
      }
    }
    __syncthreads();
    #pragma unroll
    for (int i = 0; i < 8; i++){
      const int idx = i*256 + t;
      const int row = idx >> 4, k16 = idx & 15;
      const int grp = (k16*8) ^ (((row>>2)&3)<<4);
      *(uint4*)(eproj + ((size_t)(bx*128 + row))*128 + k16*8) = *(const uint4*)&WS[row*128 + grp];
    }
  }
}

__global__ __launch_bounds__(512) void k_scan1(const int* __restrict__ counts,
                                               int* __restrict__ incl,
                                               int* __restrict__ bsum){
  __shared__ int s[512];
  const int t = threadIdx.x;
  int i = blockIdx.x*512 + t;
  int v = (i < N_NODES) ? counts[i] : 0;
  s[t] = v;
  __syncthreads();
  for (int off = 1; off < 512; off <<= 1){
    int x = (t >= off) ? s[t - off] : 0;
    __syncthreads();
    s[t] += x;
    __syncthreads();
  }
  if (i < N_NODES) incl[i] = s[t];
  if (t == 511) bsum[blockIdx.x] = s[511];
}

// scan3 with in-block redundant scan of bsum (replaces old scan2+scan3)
__global__ __launch_bounds__(512) void k_scan3(const int* __restrict__ counts,
                                               const int* __restrict__ incl,
                                               const int* __restrict__ bsum, int nb,
                                               int* __restrict__ offsets,
                                               int* __restrict__ cursor){
  __shared__ int sb[256];
  const int t = threadIdx.x;
  if (t < 256) sb[t] = (t < nb) ? bsum[t] : 0;
  __syncthreads();
  for (int off = 1; off < 256; off <<= 1){
    int x = 0;
    if (t < 256 && t >= off) x = sb[t - off];
    __syncthreads();
    if (t < 256) sb[t] += x;
    __syncthreads();
  }
  int i = blockIdx.x*512 + t;
  if (i >= N_NODES) return;
  int pre = (blockIdx.x == 0) ? 0 : sb[blockIdx.x - 1];
  int o = pre + incl[i];
  offsets[i + 1] = o;
  cursor[i]      = o - counts[i];
  if (i == 0) offsets[0] = 0;
}

// scatter: src index + bf16 edge features into CSR order ([E][16] bf16)
__global__ __launch_bounds__(256) void k_scatter(const int* __restrict__ ei,
                                                 int* __restrict__ cursor,
                                                 int* __restrict__ ssrc,
                                                 const float* __restrict__ ea,
                                                 u16* __restrict__ ea16){
  int e = blockIdx.x*256 + threadIdx.x;
  if (e >= N_EDGES) return;
  int dst = ei[N_EDGES + e];
  int pos = atomicAdd(&cursor[dst], 1);
  ssrc[pos] = ei[e];
  const float* s = ea + (size_t)e*F_EDGE_;
  unsigned p[8];
  #pragma unroll
  for (int k=0;k<8;k++) p[k] = packbf(s[2*k], s[2*k+1]);
  uint4* d4 = (uint4*)(ea16 + (size_t)pos*16);
  d4[0] = make_uint4(p[0],p[1],p[2],p[3]);
  d4[1] = make_uint4(p[4],p[5],p[6],p[7]);
}

// ---------------- Fused GAT v15: 2 nodes/wave + BN-stats fused (grid-stride, LDS reduce) ----------------
#define GAT_TILES (N_NODES/16)            // 6250 tiles of 16 nodes
#define GAT_BLOCKS ((GAT_TILES + 3)/4)    // 1563
__global__ __launch_bounds__(256) void k_gat_ep(const u16* __restrict__ xl,
                                                unsigned* xr_aggr,
                                                const u16* __restrict__ eproj,
                                                const float* __restrict__ att,
                                                const int* __restrict__ offsets,
                                                const int* __restrict__ ssrc,
                                                float* __restrict__ stats){
  __shared__ float red[8][264];           // [group][0..127 sum | 128..255 sq], padded
  const int t = threadIdx.x;
  const int wave = t >> 6, lane = t & 63;
  const int half = lane >> 5, l32 = lane & 31;
  const int c0 = l32*4;                   // 4 channels per lane
  const float4 av = *(const float4*)(att + c0);
  float ss0=0.f, ss1=0.f, ss2=0.f, ss3=0.f;
  float qq0=0.f, qq1=0.f, qq2=0.f, qq3=0.f;

  for (int j = 0; j < 4; j++){
    const int tile = blockIdx.x*4 + j;
    if (tile >= GAT_TILES) break;         // block-uniform
    for (int k = 0; k < 2; k++){
      const int node = tile*16 + wave*4 + k*2 + half;
      const uint2 xru = *(const uint2*)(xr_aggr + (size_t)node*64 + l32*2);
      const f32x2 xr0 = bp2v(xru.x), xr1 = bp2v(xru.y);
      f32x2 acc0 = {0.f,0.f}, acc1 = {0.f,0.f};
      float den = 0.f;
      const int beg = offsets[node], end = offsets[node+1];
      int it = (end - beg + 3) >> 2;
      int oit = __shfl_xor(it, 32);
      const int maxit = it > oit ? it : oit;
      int i = beg;
      for (int n = 0; n < maxit; n++, i += 4){
        const int mm = end - i;
        int ib = (mm > 0) ? i : beg;
        ib = ib < N_EDGES ? ib : N_EDGES - 1;
        const int i0 = ib;
        const int i1 = (mm > 1) ? i+1 : ib;
        const int i2 = (mm > 2) ? i+2 : ib;
        const int i3 = (mm > 3) ? i+3 : ib;
        const int s0 = ssrc[i0], s1 = ssrc[i1], s2 = ssrc[i2], s3 = ssrc[i3];
        const uint2 e0 = *(const uint2*)(eproj + (size_t)i0*128 + c0);
        const uint2 e1 = *(const uint2*)(eproj + (size_t)i1*128 + c0);
        const uint2 e2 = *(const uint2*)(eproj + (size_t)i2*128 + c0);
        const uint2 e3 = *(const uint2*)(eproj + (size_t)i3*128 + c0);
        const uint2 x0 = *(const uint2*)(xl + (size_t)s0*HID_ + c0);
        const uint2 x1 = *(const uint2*)(xl + (size_t)s1*HID_ + c0);
        const uint2 x2 = *(const uint2*)(xl + (size_t)s2*HID_ + c0);
        const uint2 x3 = *(const uint2*)(xl + (size_t)s3*HID_ + c0);
        const f32x2 vl00 = bp2v(x0.x), vl01 = bp2v(x0.y);
        const f32x2 vl10 = bp2v(x1.x), vl11 = bp2v(x1.y);
        const f32x2 vl20 = bp2v(x2.x), vl21 = bp2v(x2.y);
        const f32x2 vl30 = bp2v(x3.x), vl31 = bp2v(x3.y);
        f32x2 v00 = vl00 + xr0 + bp2v(e0.x), v01 = vl01 + xr1 + bp2v(e0.y);
        f32x2 v10 = vl10 + xr0 + bp2v(e1.x), v11 = vl11 + xr1 + bp2v(e1.y);
        f32x2 v20 = vl20 + xr0 + bp2v(e2.x), v21 = vl21 + xr1 + bp2v(e2.y);
        f32x2 v30 = vl30 + xr0 + bp2v(e3.x), v31 = vl31 + xr1 + bp2v(e3.y);
        f32x2 w;
        w = v00*0.2f; v00.x = fmaxf(v00.x,w.x); v00.y = fmaxf(v00.y,w.y);
        w = v01*0.2f; v01.x = fmaxf(v01.x,w.x); v01.y = fmaxf(v01.y,w.y);
        w = v10*0.2f; v10.x = fmaxf(v10.x,w.x); v10.y = fmaxf(v10.y,w.y);
        w = v11*0.2f; v11.x = fmaxf(v11.x,w.x); v11.y = fmaxf(v11.y,w.y);
        w = v20*0.2f; v20.x = fmaxf(v20.x,w.x); v20.y = fmaxf(v20.y,w.y);
        w = v21*0.2f; v21.x = fmaxf(v21.x,w.x); v21.y = fmaxf(v21.y,w.y);
        w = v30*0.2f; v30.x = fmaxf(v30.x,w.x); v30.y = fmaxf(v30.y,w.y);
        w = v31*0.2f; v31.x = fmaxf(v31.x,w.x); v31.y = fmaxf(v31.y,w.y);
        float sc0 = v00.x*av.x + v00.y*av.y + v01.x*av.z + v01.y*av.w;
        float sc1 = v10.x*av.x + v10.y*av.y + v11.x*av.z + v11.y*av.w;
        float sc2 = v20.x*av.x + v20.y*av.y + v21.x*av.z + v21.y*av.w;
        float sc3 = v30.x*av.x + v30.y*av.y + v31.x*av.z + v31.y*av.w;
        sc0 += __shfl_xor(sc0, 1); sc1 += __shfl_xor(sc1, 1); sc2 += __shfl_xor(sc2, 1); sc3 += __shfl_xor(sc3, 1);
        sc0 += __shfl_xor(sc0, 2); sc1 += __shfl_xor(sc1, 2); sc2 += __shfl_xor(sc2, 2); sc3 += __shfl_xor(sc3, 2);
        sc0 += __shfl_xor(sc0, 4); sc1 += __shfl_xor(sc1, 4); sc2 += __shfl_xor(sc2, 4); sc3 += __shfl_xor(sc3, 4);
        const float p0 = (mm > 0) ? __expf(sc0) : 0.f;
        const float p1 = (mm > 1) ? __expf(sc1) : 0.f;
        const float p2 = (mm > 2) ? __expf(sc2) : 0.f;
        const float p3 = (mm > 3) ? __expf(sc3) : 0.f;
        acc0 += p0*vl00 + p1*vl10 + p2*vl20 + p3*vl30;
        acc1 += p0*vl01 + p1*vl11 + p2*vl21 + p3*vl31;
        den  += p0 + p1 + p2 + p3;
      }
      const float inv = 1.0f / (den + 1e-16f);
      uint2 outv;
      outv.x = packbf(acc0.x*inv, acc0.y*inv);
      outv.y = packbf(acc1.x*inv, acc1.y*inv);
      *(uint2*)(xr_aggr + (size_t)node*64 + l32*2) = outv;
      // stats from the packed (bf16-rounded) values: bit-identical to old bn_stats input
      const float2 o0 = bp2f(outv.x), o1 = bp2f(outv.y);
      ss0 += o0.x; ss1 += o0.y; ss2 += o1.x; ss3 += o1.y;
      qq0 += o0.x*o0.x; qq1 += o0.y*o0.y; qq2 += o1.x*o1.x; qq3 += o1.y*o1.y;
    }
  }
  const int g = wave*2 + half;
  red[g][c0+0] = ss0; red[g][c0+1] = ss1; red[g][c0+2] = ss2; red[g][c0+3] = ss3;
  red[g][128+c0+0] = qq0; red[g][128+c0+1] = qq1; red[g][128+c0+2] = qq2; red[g][128+c0+3] = qq3;
  __syncthreads();
  {
    float a = 0.f;
    #pragma unroll
    for (int gg = 0; gg < 8; gg++) a += red[gg][t];
    atomicAdd(&stats[t], a);
  }
}

// ---------------- BN apply + ELU (+ residual), uint4-vectorized ----------------
__global__ __launch_bounds__(256) void k_bn_apply(const unsigned* __restrict__ aggr_b,
                                                  const float* __restrict__ stats,
                                                  const float* __restrict__ gamma,
                                                  const float* __restrict__ beta,
                                                  u16* __restrict__ h, int residual){
  size_t i = (size_t)blockIdx.x*256 + threadIdx.x;   // uint4-group index (8 channels)
  if (i >= (size_t)N_NODES*16) return;
  const int c = (int)((i & 15) * 8);
  const float invn = 1.0f / (float)N_NODES;
  uint4 v4 = ((const uint4*)aggr_b)[i];
  uint4* hp = (uint4*)h + i;
  uint4 hv4 = make_uint4(0,0,0,0);
  if (residual) hv4 = *hp;
  unsigned vin[4]  = {v4.x, v4.y, v4.z, v4.w};
  unsigned hin[4]  = {hv4.x, hv4.y, hv4.z, hv4.w};
  unsigned outw[4];
  #pragma unroll
  for (int j=0;j<4;j++){
    int cc = c + j*2;
    float mu0  = stats[cc]   * invn,  mu1  = stats[cc+1]   * invn;
    float var0 = stats[128+cc]*invn - mu0*mu0;
    float var1 = stats[129+cc]*invn - mu1*mu1;
    float sc0 = rsqrtf(var0 + 1e-5f) * gamma[cc];
    float sc1 = rsqrtf(var1 + 1e-5f) * gamma[cc+1];
    float2 v = bp2f(vin[j]);
    float val0 = (v.x - mu0) * sc0 + beta[cc];
    float val1 = (v.y - mu1) * sc1 + beta[cc+1];
    val0 = val0 > 0.f ? val0 : expm1f(val0);
    val1 = val1 > 0.f ? val1 : expm1f(val1);
    if (residual){
      float2 hv = bp2f(hin[j]);
      val0 += hv.x; val1 += hv.y;
    }
    outw[j] = packbf(val0, val1);
  }
  *hp = make_uint4(outw[0], outw[1], outw[2], outw[3]);
}

// ---------------- Pool: segmented mean ----------------
__global__ __launch_bounds__(256) void k_pool_seg(const unsigned* __restrict__ h2,
                                                  const int* __restrict__ goff,
                                                  float* __restrict__ emb){
  __shared__ float redS[4][128];
  const int g = blockIdx.x, t = threadIdx.x;
  const int p = t & 63, rg = t >> 6;
  const int beg = goff[g], end = goff[g+1];
  float a0 = 0.f, a1 = 0.f;
  for (int r = beg + rg; r < end; r += 4){
    float2 v = bp2f(h2[(size_t)r*64 + p]);
    a0 += v.x; a1 += v.y;
  }
  redS[rg][p*2] = a0; redS[rg][p*2+1] = a1;
  __syncthreads();
  if (rg == 0){
    #pragma unroll
    for (int k=1;k<4;k++){ a0 += redS[k][p*2]; a1 += redS[k][p*2+1]; }
    float n = fmaxf((float)(end - beg), 1.f);
    emb[(size_t)g*HID_ + p*2]     = a0 / n;
    emb[(size_t)g*HID_ + p*2 + 1] = a1 / n;
  }
}

// ---------------- Per-task heads: 8 graphs per block ----------------
#define HG 8
__global__ __launch_bounds__(128) void k_heads(const float* __restrict__ emb,
                                               const float* __restrict__ mf,
                                               const int* __restrict__ fpi,
                                               const float* __restrict__ tw1,
                                               const float* __restrict__ tb1,
                                               const float* __restrict__ tw2,
                                               const float* __restrict__ tb2,
                                               float* __restrict__ out){
  const int task = blockIdx.y, g0 = blockIdx.x*HG;
  const int j = threadIdx.x;
  __shared__ float fused[HG][160];
  __shared__ float red[HG][128];
  for (int idx = j; idx < HG*160; idx += 128){
    int g = idx / 160, i = idx % 160;
    float v;
    if (i < 128) v = emb[(size_t)(g0+g)*HID_ + i];
    else         v = mf[(size_t)(g0+g)*2048 + fpi[task*32 + (i-128)]];
    fused[g][i] = v;
  }
  __syncthreads();
  const float* w1 = tw1 + (size_t)task*160*128;
  float acc[HG];
  float b1 = tb1[task*128 + j];
  #pragma unroll
  for (int g=0; g<HG; g++) acc[g] = b1;
  for (int i=0; i<160; i++){
    float wv = w1[(size_t)i*128 + j];
    #pragma unroll
    for (int g=0; g<HG; g++) acc[g] += fused[g][i] * wv;
  }
  float t2 = tw2[task*128 + j];
  #pragma unroll
  for (int g=0; g<HG; g++){
    float v = acc[g] > 0.f ? acc[g] : 0.f;
    red[g][j] = v * t2;
  }
  __syncthreads();
  int g = j >> 4, l16 = j & 15;
  float s = 0.f;
  #pragma unroll
  for (int k=0;k<8;k++) s += red[g][l16 + k*16];
  s += __shfl_xor(s, 1, 16);
  s += __shfl_xor(s, 2, 16);
  s += __shfl_xor(s, 4, 16);
  s += __shfl_xor(s, 8, 16);
  if (l16 == 0) out[(size_t)(g0+g)*N_TASK + task] = s + tb2[task];
}

extern "C" void kernel_launch(void* const* d_in, const int* in_sizes, int n_in,
                              void* d_out, int out_size, void* d_ws, size_t ws_size,
                              hipStream_t stream){
  const float* x    = (const float*)d_in[0];
  const int*   ei   = (const int*)  d_in[1];
  const float* ea   = (const float*)d_in[2];
  const int*   batch= (const int*)  d_in[3];
  const float* mf   = (const float*)d_in[4];
  const int*   fpi  = (const int*)  d_in[5];
  const float* Wl0  = (const float*)d_in[6];
  const float* bl0  = (const float*)d_in[7];
  const float* Wr0  = (const float*)d_in[8];
  const float* br0  = (const float*)d_in[9];
  const float* We0  = (const float*)d_in[10];
  const float* att0 = (const float*)d_in[11];
  const float* g0   = (const float*)d_in[13];
  const float* b0   = (const float*)d_in[14];
  const float* Wl   = (const float*)d_in[15];
  const float* bl   = (const float*)d_in[16];
  const float* Wr   = (const float*)d_in[17];
  const float* br   = (const float*)d_in[18];
  const float* We   = (const float*)d_in[19];
  const float* att  = (const float*)d_in[20];
  const float* gg   = (const float*)d_in[22];
  const float* bb   = (const float*)d_in[23];
  const float* tw1  = (const float*)d_in[24];
  const float* tb1  = (const float*)d_in[25];
  const float* tw2  = (const float*)d_in[26];
  const float* tb2  = (const float*)d_in[27];
  float* out = (float*)d_out;

  char* w = (char*)d_ws;
  auto alloc = [&](size_t bytes)->char*{ char* r = w; w += (bytes + 255) & ~(size_t)255; return r; };
  u16*   xl     = (u16*)  alloc((size_t)N_NODES*HID_*2);
  unsigned* xr_aggr = (unsigned*)alloc((size_t)N_NODES*64*4);
  u16*   h      = (u16*)  alloc((size_t)N_NODES*HID_*2);
  u16*   ea16   = (u16*)  alloc((size_t)N_EDGES*16*2);
  int*   counts = (int*)  alloc((size_t)N_NODES*4);
  float* stats4 = (float*)alloc(4*256*4);
  int*   offsets= (int*)  alloc((size_t)(N_NODES+1)*4);
  int*   cursor = (int*)  alloc((size_t)N_NODES*4);
  int*   incl   = (int*)  alloc((size_t)N_NODES*4);
  int*   bsum   = (int*)  alloc(256*4);
  int*   ssrc   = (int*)  alloc((size_t)N_EDGES*4);
  int*   goff   = (int*)  alloc((size_t)(N_GRAPH+1)*4);
  float* emb    = (float*)alloc((size_t)N_GRAPH*HID_*4);
  u16*   Wzl0   = (u16*)  alloc((size_t)F_NODE_*128*2);
  u16*   Wzr0   = (u16*)  alloc((size_t)F_NODE_*128*2);
  u16*   Wzl123 = (u16*)  alloc((size_t)3*HID_*128*2);
  u16*   Wzr123 = (u16*)  alloc((size_t)3*HID_*128*2);
  u16*   Wez4   = (u16*)  alloc((size_t)4*32*128*2);
  u16*   eproj  = (u16*)  alloc((size_t)N_EDGES*HID_*2);
  u16*   xbf    = (u16*)  alloc((size_t)N_NODES*F_NODE_*2);  // separate from eproj (no race)

  const size_t zlen = (size_t)((char*)(stats4 + 4*256) - (char*)counts);
  const int nscan = (N_NODES + 511)/512;

  WZ12 p;
  p.src[0] = Wl0; p.dst[0] = Wzl0; p.Ks[0] = F_NODE_; p.Kd[0] = F_NODE_;
  p.src[1] = Wr0; p.dst[1] = Wzr0; p.Ks[1] = F_NODE_; p.Kd[1] = F_NODE_;
  for (int i=0;i<3;i++){
    p.src[2+i] = Wl + (size_t)i*HID_*HID_; p.dst[2+i] = Wzl123 + (size_t)i*HID_*128; p.Ks[2+i] = HID_; p.Kd[2+i] = HID_;
    p.src[5+i] = Wr + (size_t)i*HID_*HID_; p.dst[5+i] = Wzr123 + (size_t)i*HID_*128; p.Ks[5+i] = HID_; p.Kd[5+i] = HID_;
  }
  p.src[8] = We0; p.dst[8] = Wez4; p.Ks[8] = F_EDGE_; p.Kd[8] = 32;
  for (int i=0;i<3;i++){
    p.src[9+i] = We + (size_t)i*F_EDGE_*HID_; p.dst[9+i] = Wez4 + (size_t)(i+1)*32*128; p.Ks[9+i] = F_EDGE_; p.Kd[9+i] = 32;
  }

  hipMemsetAsync(counts, 0, zlen, stream);
  hipLaunchKernelGGL(k_cast_hist, dim3(CAST_BLKS + EG256 + GOFF_BLKS + WSWZ_BLKS), dim3(256), 0, stream,
                     x, xbf, ei, counts, batch, goff, p);
  hipLaunchKernelGGL(k_scan1,  dim3(nscan), dim3(512), 0, stream, counts, incl, bsum);
  hipLaunchKernelGGL(k_scan3,  dim3(nscan), dim3(512), 0, stream, counts, incl, bsum, nscan, offsets, cursor);
  hipLaunchKernelGGL(k_scatter,dim3(EG256), dim3(256), 0, stream, ei, cursor, ssrc, ea, ea16);

  for (int layer = 0; layer < 4; layer++){
    const float *bl_, *br_, *att_, *g_, *b_;
    const u16 *Wzl_, *Wzr_, *Ain;
    int K;
    if (layer == 0){
      bl_=bl0; br_=br0; att_=att0; g_=g0; b_=b0;
      Wzl_ = Wzl0; Wzr_ = Wzr0; Ain = xbf; K = F_NODE_;
    } else {
      int i = layer - 1;
      bl_ = bl + (size_t)i*HID_;  br_ = br + (size_t)i*HID_;
      att_= att + (size_t)i*HID_;
      g_  = gg + (size_t)i*HID_;  b_  = bb + (size_t)i*HID_;
      Wzl_ = Wzl123 + (size_t)i*HID_*128;
      Wzr_ = Wzr123 + (size_t)i*HID_*128;
      Ain = h; K = HID_;
    }
    float* stats = stats4 + layer*256;
    hipLaunchKernelGGL(k_gemm_eproj, dim3(2*GEMM_GRID + EPROJ_GRID), dim3(256), 0, stream,
                       Ain, Wzl_, Wzr_, bl_, br_, xl, (u16*)xr_aggr, N_NODES, K,
                       ea16, Wez4 + (size_t)layer*32*128, eproj);
    hipLaunchKernelGGL(k_gat_ep, dim3(GAT_BLOCKS), dim3(256), 0, stream,
                       xl, xr_aggr, eproj, att_, offsets, ssrc, stats);
    hipLaunchKernelGGL(k_bn_apply, dim3((N_NODES*16 + 255)/256), dim3(256), 0, stream,
                       xr_aggr, stats, g_, b_, h, layer > 0 ? 1 : 0);
  }
  hipLaunchKernelGGL(k_pool_seg, dim3(N_GRAPH), dim3(256), 0, stream, (const unsigned*)h, goff, emb);
  hipLaunchKernelGGL(k_heads, dim3(N_GRAPH/HG, N_TASK), dim3(128), 0, stream, emb, mf, fpi, tw1, tb1, tw2, tb2, out);
}

// Round 8
// 743.059 us; speedup vs baseline: 2.1429x; 1.0249x over previous
//
#include <hip/hip_runtime.h>
#include <hip/hip_bf16.h>

#define N_NODES 100000
#define N_EDGES 400000
#define F_NODE_ 64
#define F_EDGE_ 16
#define HID_ 128
#define N_GRAPH 1024
#define N_TASK 5

typedef unsigned short u16;
typedef __attribute__((ext_vector_type(8))) short frag8;   // 8 bf16 = 4 VGPRs
typedef __attribute__((ext_vector_type(4))) float f32x4;   // MFMA C/D
typedef __attribute__((ext_vector_type(2))) float f32x2;

__device__ __forceinline__ float bu2f(u16 v){ return __uint_as_float(((unsigned)v) << 16); }
__device__ __forceinline__ float2 bp2f(unsigned u){
  return make_float2(__uint_as_float(u << 16), __uint_as_float(u & 0xFFFF0000u));
}
__device__ __forceinline__ f32x2 bp2v(unsigned u){
  f32x2 r; r.x = __uint_as_float(u << 16); r.y = __uint_as_float(u & 0xFFFF0000u); return r;
}
__device__ __forceinline__ u16 f2bu(float f){
  __hip_bfloat16 h = __float2bfloat16(f);
  return *(u16*)&h;
}
__device__ __forceinline__ unsigned packbf(float a, float b){
  return (unsigned)f2bu(a) | ((unsigned)f2bu(b) << 16);
}

struct WZ12 { const float* src[12]; u16* dst[12]; int Ks[12]; int Kd[12]; };

// ---------------- cast f32->bf16 + edge histogram + graph offsets + W pre-swizzle (flat grid) ----------------
#define CAST_BLKS ((N_NODES*F_NODE_ + 255)/256)
#define EG256 ((N_EDGES + 255)/256)
#define GOFF_BLKS ((N_GRAPH + 1 + 255)/256)
#define WSWZ_BLKS (12*64)
__global__ __launch_bounds__(256) void k_cast_hist(const float* __restrict__ s, u16* __restrict__ d,
                                                   const int* __restrict__ ei, int* __restrict__ counts,
                                                   const int* __restrict__ batch, int* __restrict__ goff,
                                                   WZ12 p){
  int b = blockIdx.x;
  if (b < CAST_BLKS){
    int i = b*256 + threadIdx.x;
    if (i < N_NODES*F_NODE_) d[i] = f2bu(s[i]);
  } else if (b < CAST_BLKS + EG256){
    int e = (b - CAST_BLKS)*256 + threadIdx.x;
    if (e < N_EDGES) atomicAdd(&counts[ei[N_EDGES + e]], 1);
  } else if (b < CAST_BLKS + EG256 + GOFF_BLKS){
    int g = (b - CAST_BLKS - EG256)*256 + threadIdx.x;
    if (g <= N_GRAPH){
      int lo = 0, hi = N_NODES;
      while (lo < hi){
        int mid = (lo + hi) >> 1;
        if (batch[mid] < g) lo = mid + 1; else hi = mid;
      }
      goff[g] = lo;
    }
  } else {
    int bb = b - CAST_BLKS - EG256 - GOFF_BLKS;   // 0..767
    const int sW = bb >> 6;
    const int Kd = p.Kd[sW], Ks = p.Ks[sW];
    int i = (bb & 63)*256 + threadIdx.x;
    if (i >= Kd*128) return;
    int k = i >> 7, n = i & 127;
    float v = (k < Ks) ? p.src[sW][k*128 + n] : 0.f;
    int kk = k & 31, c = k >> 5;
    int quad = kk >> 3, j = kk & 7;
    int nt = n >> 4;
    int lane = quad*16 + (n & 15);
    p.dst[sW][(((c*8 + nt)*64) + lane)*8 + j] = f2bu(v);
  }
}

// ---------------- fused: paired MFMA GEMMs + eproj MFMA GEMM (flat grid) ----------------
// C-write: stage tile in LDS (quad-XOR swizzle, conflict-free) then coalesced uint4 stores.
#define GEMM_GRID ((N_NODES + 127)/128)   // 782
#define EPROJ_GRID ((N_EDGES + 127)/128)  // 3125
__global__ __launch_bounds__(256) void k_gemm_eproj(const u16* __restrict__ A,
                                                    const u16* __restrict__ Wzl,
                                                    const u16* __restrict__ Wzr,
                                                    const float* __restrict__ bl,
                                                    const float* __restrict__ br,
                                                    u16* __restrict__ Cl,
                                                    u16* Cr,
                                                    int M, int K,
                                                    const u16* __restrict__ ea16,
                                                    const u16* __restrict__ Wez,
                                                    u16* __restrict__ eproj){
  __shared__ u16 WS[128*128];
  const int t = threadIdx.x;
  const int b = blockIdx.x;
  if (b < 2*GEMM_GRID){
    const int which = (b >= GEMM_GRID);
    const int bx = which ? b - GEMM_GRID : b;
    const u16*   Wz   = which ? Wzr : Wzl;
    const float* bias = which ? br  : bl;
    u16*         C    = which ? Cr  : Cl;
    {
      const uint4* src = (const uint4*)Wz;
      uint4* dst = (uint4*)WS;
      const int n = (K*128) >> 3;
      for (int i = t; i < n; i += 256) dst[i] = src[i];
    }
    __syncthreads();
    const int w = t >> 6, l = t & 63;
    const int m = l & 15, quad = l >> 4;
    const int rowA0 = bx*128 + w*32 + m;
    const int rowA1 = rowA0 + 16;
    f32x4 acc[2][8];
    #pragma unroll
    for (int i=0;i<2;i++)
      #pragma unroll
      for (int j=0;j<8;j++) acc[i][j] = (f32x4){0.f,0.f,0.f,0.f};
    const int KC = K >> 5;
    for (int c = 0; c < KC; c++){
      frag8 a0 = {}, a1 = {};
      if (rowA0 < M) a0 = *(const frag8*)(A + (size_t)rowA0*K + c*32 + quad*8);
      if (rowA1 < M) a1 = *(const frag8*)(A + (size_t)rowA1*K + c*32 + quad*8);
      #pragma unroll
      for (int nt = 0; nt < 8; nt++){
        frag8 bfr = *(const frag8*)&WS[(((c*8 + nt)*64) + l)*8];
        acc[0][nt] = __builtin_amdgcn_mfma_f32_16x16x32_bf16(a0, bfr, acc[0][nt], 0,0,0);
        acc[1][nt] = __builtin_amdgcn_mfma_f32_16x16x32_bf16(a1, bfr, acc[1][nt], 0,0,0);
      }
    }
    float bcv[8];
    #pragma unroll
    for (int nt=0; nt<8; nt++) bcv[nt] = bias[nt*16 + m];
    __syncthreads();          // all WS reads (MFMA) done
    const int sXor = quad << 4;   // quads -> disjoint bank groups
    #pragma unroll
    for (int rt = 0; rt < 2; rt++){
      #pragma unroll
      for (int r = 0; r < 4; r++){
        const int row = w*32 + rt*16 + quad*4 + r;
        #pragma unroll
        for (int nt = 0; nt < 8; nt++){
          const int col = nt*16 + m;
          WS[row*128 + (col ^ sXor)] = f2bu(acc[rt][nt][r] + bcv[nt]);
        }
      }
    }
    __syncthreads();
    #pragma unroll
    for (int i = 0; i < 8; i++){
      const int idx = i*256 + t;
      const int row = idx >> 4, k16 = idx & 15;
      const int grp = (k16*8) ^ (((row>>2)&3)<<4);
      const int grow = bx*128 + row;
      if (grow < M)
        *(uint4*)(C + (size_t)grow*128 + k16*8) = *(const uint4*)&WS[row*128 + grp];
    }
  } else {
    // eproj GEMM: 128 edges/block, K=32 via fragment zero-padding
    const int bx = b - 2*GEMM_GRID;
    {
      const uint4* s4 = (const uint4*)Wez;
      uint4* d4 = (uint4*)WS;
      for (int i = t; i < 512; i += 256) d4[i] = s4[i];
    }
    __syncthreads();
    const int w = t >> 6, l = t & 63, m = l & 15, quad = l >> 4;
    const int row0 = bx*128 + w*32 + m;
    const int row1 = row0 + 16;
    f32x4 acc[2][8];
    #pragma unroll
    for (int i=0;i<2;i++)
      #pragma unroll
      for (int j=0;j<8;j++) acc[i][j] = (f32x4){0.f,0.f,0.f,0.f};
    frag8 a0 = {}, a1 = {};
    if (quad < 2){
      a0 = *(const frag8*)(ea16 + (size_t)row0*16 + quad*8);   // grid exact: rows < N_EDGES
      a1 = *(const frag8*)(ea16 + (size_t)row1*16 + quad*8);
    }
    #pragma unroll
    for (int nt = 0; nt < 8; nt++){
      frag8 bfr = *(const frag8*)&WS[(nt*64 + l)*8];
      acc[0][nt] = __builtin_amdgcn_mfma_f32_16x16x32_bf16(a0, bfr, acc[0][nt], 0,0,0);
      acc[1][nt] = __builtin_amdgcn_mfma_f32_16x16x32_bf16(a1, bfr, acc[1][nt], 0,0,0);
    }
    __syncthreads();
    const int sXor = quad << 4;
    #pragma unroll
    for (int rt = 0; rt < 2; rt++){
      #pragma unroll
      for (int r = 0; r < 4; r++){
        const int row = w*32 + rt*16 + quad*4 + r;
        #pragma unroll
        for (int nt = 0; nt < 8; nt++){
          const int col = nt*16 + m;
          WS[row*128 + (col ^ sXor)] = f2bu(acc[rt][nt][r]);
        }
      }
    }
    __syncthreads();
    #pragma unroll
    for (int i = 0; i < 8; i++){
      const int idx = i*256 + t;
      const int row = idx >> 4, k16 = idx & 15;
      const int grp = (k16*8) ^ (((row>>2)&3)<<4);
      *(uint4*)(eproj + ((size_t)(bx*128 + row))*128 + k16*8) = *(const uint4*)&WS[row*128 + grp];
    }
  }
}

__global__ __launch_bounds__(512) void k_scan1(const int* __restrict__ counts,
                                               int* __restrict__ incl,
                                               int* __restrict__ bsum){
  __shared__ int s[512];
  const int t = threadIdx.x;
  int i = blockIdx.x*512 + t;
  int v = (i < N_NODES) ? counts[i] : 0;
  s[t] = v;
  __syncthreads();
  for (int off = 1; off < 512; off <<= 1){
    int x = (t >= off) ? s[t - off] : 0;
    __syncthreads();
    s[t] += x;
    __syncthreads();
  }
  if (i < N_NODES) incl[i] = s[t];
  if (t == 511) bsum[blockIdx.x] = s[511];
}

// scan3 with in-block redundant scan of bsum (replaces old scan2+scan3)
__global__ __launch_bounds__(512) void k_scan3(const int* __restrict__ counts,
                                               const int* __restrict__ incl,
                                               const int* __restrict__ bsum, int nb,
                                               int* __restrict__ offsets,
                                               int* __restrict__ cursor){
  __shared__ int sb[256];
  const int t = threadIdx.x;
  if (t < 256) sb[t] = (t < nb) ? bsum[t] : 0;
  __syncthreads();
  for (int off = 1; off < 256; off <<= 1){
    int x = 0;
    if (t < 256 && t >= off) x = sb[t - off];
    __syncthreads();
    if (t < 256) sb[t] += x;
    __syncthreads();
  }
  int i = blockIdx.x*512 + t;
  if (i >= N_NODES) return;
  int pre = (blockIdx.x == 0) ? 0 : sb[blockIdx.x - 1];
  int o = pre + incl[i];
  offsets[i + 1] = o;
  cursor[i]      = o - counts[i];
  if (i == 0) offsets[0] = 0;
}

// scatter: src index + bf16 edge features into CSR order ([E][16] bf16)
__global__ __launch_bounds__(256) void k_scatter(const int* __restrict__ ei,
                                                 int* __restrict__ cursor,
                                                 int* __restrict__ ssrc,
                                                 const float* __restrict__ ea,
                                                 u16* __restrict__ ea16){
  int e = blockIdx.x*256 + threadIdx.x;
  if (e >= N_EDGES) return;
  int dst = ei[N_EDGES + e];
  int pos = atomicAdd(&cursor[dst], 1);
  ssrc[pos] = ei[e];
  const float* s = ea + (size_t)e*F_EDGE_;
  unsigned p[8];
  #pragma unroll
  for (int k=0;k<8;k++) p[k] = packbf(s[2*k], s[2*k+1]);
  uint4* d4 = (uint4*)(ea16 + (size_t)pos*16);
  d4[0] = make_uint4(p[0],p[1],p[2],p[3]);
  d4[1] = make_uint4(p[4],p[5],p[6],p[7]);
}

// ---------------- Fused GAT v16: 2 nodes/wave, 1 tile/block (full grid) + BN-stats tail ----------------
// Stats striped 4-way by blockIdx to spread atomic traffic across cache lines.
#define GAT_GRID (N_NODES/16)   // 6250, exact: 4 waves x 2 halves x 2 k-iters = 16 nodes/block
__global__ __launch_bounds__(256) void k_gat_ep(const u16* __restrict__ xl,
                                                unsigned* xr_aggr,
                                                const u16* __restrict__ eproj,
                                                const float* __restrict__ att,
                                                const int* __restrict__ offsets,
                                                const int* __restrict__ ssrc,
                                                float* __restrict__ stats){
  __shared__ float red[8][264];           // [group][0..127 sum | 128..255 sq]
  const int t = threadIdx.x;
  const int wave = t >> 6, lane = t & 63;
  const int half = lane >> 5, l32 = lane & 31;
  const int c0 = l32*4;                   // 4 channels per lane
  const float4 av = *(const float4*)(att + c0);
  float ss0=0.f, ss1=0.f, ss2=0.f, ss3=0.f;
  float qq0=0.f, qq1=0.f, qq2=0.f, qq3=0.f;

  for (int k = 0; k < 2; k++){
    const int node = blockIdx.x*16 + wave*4 + k*2 + half;   // < N_NODES (grid exact)
    const uint2 xru = *(const uint2*)(xr_aggr + (size_t)node*64 + l32*2);
    const f32x2 xr0 = bp2v(xru.x), xr1 = bp2v(xru.y);
    f32x2 acc0 = {0.f,0.f}, acc1 = {0.f,0.f};
    float den = 0.f;
    const int beg = offsets[node], end = offsets[node+1];
    int it = (end - beg + 3) >> 2;
    int oit = __shfl_xor(it, 32);
    const int maxit = it > oit ? it : oit;
    int i = beg;
    for (int n = 0; n < maxit; n++, i += 4){
      const int mm = end - i;
      int ib = (mm > 0) ? i : beg;
      ib = ib < N_EDGES ? ib : N_EDGES - 1;
      const int i0 = ib;
      const int i1 = (mm > 1) ? i+1 : ib;
      const int i2 = (mm > 2) ? i+2 : ib;
      const int i3 = (mm > 3) ? i+3 : ib;
      const int s0 = ssrc[i0], s1 = ssrc[i1], s2 = ssrc[i2], s3 = ssrc[i3];
      const uint2 e0 = *(const uint2*)(eproj + (size_t)i0*128 + c0);
      const uint2 e1 = *(const uint2*)(eproj + (size_t)i1*128 + c0);
      const uint2 e2 = *(const uint2*)(eproj + (size_t)i2*128 + c0);
      const uint2 e3 = *(const uint2*)(eproj + (size_t)i3*128 + c0);
      const uint2 x0 = *(const uint2*)(xl + (size_t)s0*HID_ + c0);
      const uint2 x1 = *(const uint2*)(xl + (size_t)s1*HID_ + c0);
      const uint2 x2 = *(const uint2*)(xl + (size_t)s2*HID_ + c0);
      const uint2 x3 = *(const uint2*)(xl + (size_t)s3*HID_ + c0);
      const f32x2 vl00 = bp2v(x0.x), vl01 = bp2v(x0.y);
      const f32x2 vl10 = bp2v(x1.x), vl11 = bp2v(x1.y);
      const f32x2 vl20 = bp2v(x2.x), vl21 = bp2v(x2.y);
      const f32x2 vl30 = bp2v(x3.x), vl31 = bp2v(x3.y);
      f32x2 v00 = vl00 + xr0 + bp2v(e0.x), v01 = vl01 + xr1 + bp2v(e0.y);
      f32x2 v10 = vl10 + xr0 + bp2v(e1.x), v11 = vl11 + xr1 + bp2v(e1.y);
      f32x2 v20 = vl20 + xr0 + bp2v(e2.x), v21 = vl21 + xr1 + bp2v(e2.y);
      f32x2 v30 = vl30 + xr0 + bp2v(e3.x), v31 = vl31 + xr1 + bp2v(e3.y);
      f32x2 w;
      w = v00*0.2f; v00.x = fmaxf(v00.x,w.x); v00.y = fmaxf(v00.y,w.y);
      w = v01*0.2f; v01.x = fmaxf(v01.x,w.x); v01.y = fmaxf(v01.y,w.y);
      w = v10*0.2f; v10.x = fmaxf(v10.x,w.x); v10.y = fmaxf(v10.y,w.y);
      w = v11*0.2f; v11.x = fmaxf(v11.x,w.x); v11.y = fmaxf(v11.y,w.y);
      w = v20*0.2f; v20.x = fmaxf(v20.x,w.x); v20.y = fmaxf(v20.y,w.y);
      w = v21*0.2f; v21.x = fmaxf(v21.x,w.x); v21.y = fmaxf(v21.y,w.y);
      w = v30*0.2f; v30.x = fmaxf(v30.x,w.x); v30.y = fmaxf(v30.y,w.y);
      w = v31*0.2f; v31.x = fmaxf(v31.x,w.x); v31.y = fmaxf(v31.y,w.y);
      float sc0 = v00.x*av.x + v00.y*av.y + v01.x*av.z + v01.y*av.w;
      float sc1 = v10.x*av.x + v10.y*av.y + v11.x*av.z + v11.y*av.w;
      float sc2 = v20.x*av.x + v20.y*av.y + v21.x*av.z + v21.y*av.w;
      float sc3 = v30.x*av.x + v30.y*av.y + v31.x*av.z + v31.y*av.w;
      sc0 += __shfl_xor(sc0, 1); sc1 += __shfl_xor(sc1, 1); sc2 += __shfl_xor(sc2, 1); sc3 += __shfl_xor(sc3, 1);
      sc0 += __shfl_xor(sc0, 2); sc1 += __shfl_xor(sc1, 2); sc2 += __shfl_xor(sc2, 2); sc3 += __shfl_xor(sc3, 2);
      sc0 += __shfl_xor(sc0, 4); sc1 += __shfl_xor(sc1, 4); sc2 += __shfl_xor(sc2, 4); sc3 += __shfl_xor(sc3, 4);
      const float p0 = (mm > 0) ? __expf(sc0) : 0.f;
      const float p1 = (mm > 1) ? __expf(sc1) : 0.f;
      const float p2 = (mm > 2) ? __expf(sc2) : 0.f;
      const float p3 = (mm > 3) ? __expf(sc3) : 0.f;
      acc0 += p0*vl00 + p1*vl10 + p2*vl20 + p3*vl30;
      acc1 += p0*vl01 + p1*vl11 + p2*vl21 + p3*vl31;
      den  += p0 + p1 + p2 + p3;
    }
    const float inv = 1.0f / (den + 1e-16f);
    uint2 outv;
    outv.x = packbf(acc0.x*inv, acc0.y*inv);
    outv.y = packbf(acc1.x*inv, acc1.y*inv);
    *(uint2*)(xr_aggr + (size_t)node*64 + l32*2) = outv;
    // stats from the packed (bf16-rounded) values: identical to old bn_stats input
    const float2 o0 = bp2f(outv.x), o1 = bp2f(outv.y);
    ss0 += o0.x; ss1 += o0.y; ss2 += o1.x; ss3 += o1.y;
    qq0 += o0.x*o0.x; qq1 += o0.y*o0.y; qq2 += o1.x*o1.x; qq3 += o1.y*o1.y;
  }
  const int g = wave*2 + half;
  red[g][c0+0] = ss0; red[g][c0+1] = ss1; red[g][c0+2] = ss2; red[g][c0+3] = ss3;
  red[g][128+c0+0] = qq0; red[g][128+c0+1] = qq1; red[g][128+c0+2] = qq2; red[g][128+c0+3] = qq3;
  __syncthreads();
  {
    float a = 0.f;
    #pragma unroll
    for (int gg = 0; gg < 8; gg++) a += red[gg][t];
    atomicAdd(&stats[(blockIdx.x & 3)*256 + t], a);   // 4-way stripe
  }
}

// ---------------- BN apply + ELU (+ residual), uint4-vectorized; sums 4 stats stripes ----------------
__global__ __launch_bounds__(256) void k_bn_apply(const unsigned* __restrict__ aggr_b,
                                                  const float* __restrict__ stats,
                                                  const float* __restrict__ gamma,
                                                  const float* __restrict__ beta,
                                                  u16* __restrict__ h, int residual){
  size_t i = (size_t)blockIdx.x*256 + threadIdx.x;   // uint4-group index (8 channels)
  if (i >= (size_t)N_NODES*16) return;
  const int c = (int)((i & 15) * 8);
  const float invn = 1.0f / (float)N_NODES;
  uint4 v4 = ((const uint4*)aggr_b)[i];
  uint4* hp = (uint4*)h + i;
  uint4 hv4 = make_uint4(0,0,0,0);
  if (residual) hv4 = *hp;
  unsigned vin[4]  = {v4.x, v4.y, v4.z, v4.w};
  unsigned hin[4]  = {hv4.x, hv4.y, hv4.z, hv4.w};
  unsigned outw[4];
  #pragma unroll
  for (int j=0;j<4;j++){
    int cc = c + j*2;
    float s_c0 = stats[cc]     + stats[256+cc]     + stats[512+cc]     + stats[768+cc];
    float s_c1 = stats[cc+1]   + stats[256+cc+1]   + stats[512+cc+1]   + stats[768+cc+1];
    float q_c0 = stats[128+cc]   + stats[384+cc]   + stats[640+cc]   + stats[896+cc];
    float q_c1 = stats[128+cc+1] + stats[384+cc+1] + stats[640+cc+1] + stats[896+cc+1];
    float mu0  = s_c0 * invn,  mu1  = s_c1 * invn;
    float var0 = q_c0*invn - mu0*mu0;
    float var1 = q_c1*invn - mu1*mu1;
    float sc0 = rsqrtf(var0 + 1e-5f) * gamma[cc];
    float sc1 = rsqrtf(var1 + 1e-5f) * gamma[cc+1];
    float2 v = bp2f(vin[j]);
    float val0 = (v.x - mu0) * sc0 + beta[cc];
    float val1 = (v.y - mu1) * sc1 + beta[cc+1];
    val0 = val0 > 0.f ? val0 : expm1f(val0);
    val1 = val1 > 0.f ? val1 : expm1f(val1);
    if (residual){
      float2 hv = bp2f(hin[j]);
      val0 += hv.x; val1 += hv.y;
    }
    outw[j] = packbf(val0, val1);
  }
  *hp = make_uint4(outw[0], outw[1], outw[2], outw[3]);
}

// ---------------- Pool: segmented mean ----------------
__global__ __launch_bounds__(256) void k_pool_seg(const unsigned* __restrict__ h2,
                                                  const int* __restrict__ goff,
                                                  float* __restrict__ emb){
  __shared__ float redS[4][128];
  const int g = blockIdx.x, t = threadIdx.x;
  const int p = t & 63, rg = t >> 6;
  const int beg = goff[g], end = goff[g+1];
  float a0 = 0.f, a1 = 0.f;
  for (int r = beg + rg; r < end; r += 4){
    float2 v = bp2f(h2[(size_t)r*64 + p]);
    a0 += v.x; a1 += v.y;
  }
  redS[rg][p*2] = a0; redS[rg][p*2+1] = a1;
  __syncthreads();
  if (rg == 0){
    #pragma unroll
    for (int k=1;k<4;k++){ a0 += redS[k][p*2]; a1 += redS[k][p*2+1]; }
    float n = fmaxf((float)(end - beg), 1.f);
    emb[(size_t)g*HID_ + p*2]     = a0 / n;
    emb[(size_t)g*HID_ + p*2 + 1] = a1 / n;
  }
}

// ---------------- Per-task heads: 8 graphs per block ----------------
#define HG 8
__global__ __launch_bounds__(128) void k_heads(const float* __restrict__ emb,
                                               const float* __restrict__ mf,
                                               const int* __restrict__ fpi,
                                               const float* __restrict__ tw1,
                                               const float* __restrict__ tb1,
                                               const float* __restrict__ tw2,
                                               const float* __restrict__ tb2,
                                               float* __restrict__ out){
  const int task = blockIdx.y, g0 = blockIdx.x*HG;
  const int j = threadIdx.x;
  __shared__ float fused[HG][160];
  __shared__ float red[HG][128];
  for (int idx = j; idx < HG*160; idx += 128){
    int g = idx / 160, i = idx % 160;
    float v;
    if (i < 128) v = emb[(size_t)(g0+g)*HID_ + i];
    else         v = mf[(size_t)(g0+g)*2048 + fpi[task*32 + (i-128)]];
    fused[g][i] = v;
  }
  __syncthreads();
  const float* w1 = tw1 + (size_t)task*160*128;
  float acc[HG];
  float b1 = tb1[task*128 + j];
  #pragma unroll
  for (int g=0; g<HG; g++) acc[g] = b1;
  for (int i=0; i<160; i++){
    float wv = w1[(size_t)i*128 + j];
    #pragma unroll
    for (int g=0; g<HG; g++) acc[g] += fused[g][i] * wv;
  }
  float t2 = tw2[task*128 + j];
  #pragma unroll
  for (int g=0; g<HG; g++){
    float v = acc[g] > 0.f ? acc[g] : 0.f;
    red[g][j] = v * t2;
  }
  __syncthreads();
  int g = j >> 4, l16 = j & 15;
  float s = 0.f;
  #pragma unroll
  for (int k=0;k<8;k++) s += red[g][l16 + k*16];
  s += __shfl_xor(s, 1, 16);
  s += __shfl_xor(s, 2, 16);
  s += __shfl_xor(s, 4, 16);
  s += __shfl_xor(s, 8, 16);
  if (l16 == 0) out[(size_t)(g0+g)*N_TASK + task] = s + tb2[task];
}

extern "C" void kernel_launch(void* const* d_in, const int* in_sizes, int n_in,
                              void* d_out, int out_size, void* d_ws, size_t ws_size,
                              hipStream_t stream){
  const float* x    = (const float*)d_in[0];
  const int*   ei   = (const int*)  d_in[1];
  const float* ea   = (const float*)d_in[2];
  const int*   batch= (const int*)  d_in[3];
  const float* mf   = (const float*)d_in[4];
  const int*   fpi  = (const int*)  d_in[5];
  const float* Wl0  = (const float*)d_in[6];
  const float* bl0  = (const float*)d_in[7];
  const float* Wr0  = (const float*)d_in[8];
  const float* br0  = (const float*)d_in[9];
  const float* We0  = (const float*)d_in[10];
  const float* att0 = (const float*)d_in[11];
  const float* g0   = (const float*)d_in[13];
  const float* b0   = (const float*)d_in[14];
  const float* Wl   = (const float*)d_in[15];
  const float* bl   = (const float*)d_in[16];
  const float* Wr   = (const float*)d_in[17];
  const float* br   = (const float*)d_in[18];
  const float* We   = (const float*)d_in[19];
  const float* att  = (const float*)d_in[20];
  const float* gg   = (const float*)d_in[22];
  const float* bb   = (const float*)d_in[23];
  const float* tw1  = (const float*)d_in[24];
  const float* tb1  = (const float*)d_in[25];
  const float* tw2  = (const float*)d_in[26];
  const float* tb2  = (const float*)d_in[27];
  float* out = (float*)d_out;

  char* w = (char*)d_ws;
  auto alloc = [&](size_t bytes)->char*{ char* r = w; w += (bytes + 255) & ~(size_t)255; return r; };
  u16*   xl     = (u16*)  alloc((size_t)N_NODES*HID_*2);
  unsigned* xr_aggr = (unsigned*)alloc((size_t)N_NODES*64*4);
  u16*   h      = (u16*)  alloc((size_t)N_NODES*HID_*2);
  u16*   ea16   = (u16*)  alloc((size_t)N_EDGES*16*2);
  int*   counts = (int*)  alloc((size_t)N_NODES*4);
  float* stats4 = (float*)alloc(4*1024*4);            // 4 layers x 4 stripes x 256 floats
  int*   offsets= (int*)  alloc((size_t)(N_NODES+1)*4);
  int*   cursor = (int*)  alloc((size_t)N_NODES*4);
  int*   incl   = (int*)  alloc((size_t)N_NODES*4);
  int*   bsum   = (int*)  alloc(256*4);
  int*   ssrc   = (int*)  alloc((size_t)N_EDGES*4);
  int*   goff   = (int*)  alloc((size_t)(N_GRAPH+1)*4);
  float* emb    = (float*)alloc((size_t)N_GRAPH*HID_*4);
  u16*   Wzl0   = (u16*)  alloc((size_t)F_NODE_*128*2);
  u16*   Wzr0   = (u16*)  alloc((size_t)F_NODE_*128*2);
  u16*   Wzl123 = (u16*)  alloc((size_t)3*HID_*128*2);
  u16*   Wzr123 = (u16*)  alloc((size_t)3*HID_*128*2);
  u16*   Wez4   = (u16*)  alloc((size_t)4*32*128*2);
  u16*   eproj  = (u16*)  alloc((size_t)N_EDGES*HID_*2);
  u16*   xbf    = (u16*)  alloc((size_t)N_NODES*F_NODE_*2);  // separate from eproj (no race)

  const size_t zlen = (size_t)((char*)(stats4 + 4*1024) - (char*)counts);
  const int nscan = (N_NODES + 511)/512;

  WZ12 p;
  p.src[0] = Wl0; p.dst[0] = Wzl0; p.Ks[0] = F_NODE_; p.Kd[0] = F_NODE_;
  p.src[1] = Wr0; p.dst[1] = Wzr0; p.Ks[1] = F_NODE_; p.Kd[1] = F_NODE_;
  for (int i=0;i<3;i++){
    p.src[2+i] = Wl + (size_t)i*HID_*HID_; p.dst[2+i] = Wzl123 + (size_t)i*HID_*128; p.Ks[2+i] = HID_; p.Kd[2+i] = HID_;
    p.src[5+i] = Wr + (size_t)i*HID_*HID_; p.dst[5+i] = Wzr123 + (size_t)i*HID_*128; p.Ks[5+i] = HID_; p.Kd[5+i] = HID_;
  }
  p.src[8] = We0; p.dst[8] = Wez4; p.Ks[8] = F_EDGE_; p.Kd[8] = 32;
  for (int i=0;i<3;i++){
    p.src[9+i] = We + (size_t)i*F_EDGE_*HID_; p.dst[9+i] = Wez4 + (size_t)(i+1)*32*128; p.Ks[9+i] = F_EDGE_; p.Kd[9+i] = 32;
  }

  hipMemsetAsync(counts, 0, zlen, stream);
  hipLaunchKernelGGL(k_cast_hist, dim3(CAST_BLKS + EG256 + GOFF_BLKS + WSWZ_BLKS), dim3(256), 0, stream,
                     x, xbf, ei, counts, batch, goff, p);
  hipLaunchKernelGGL(k_scan1,  dim3(nscan), dim3(512), 0, stream, counts, incl, bsum);
  hipLaunchKernelGGL(k_scan3,  dim3(nscan), dim3(512), 0, stream, counts, incl, bsum, nscan, offsets, cursor);
  hipLaunchKernelGGL(k_scatter,dim3(EG256), dim3(256), 0, stream, ei, cursor, ssrc, ea, ea16);

  for (int layer = 0; layer < 4; layer++){
    const float *bl_, *br_, *att_, *g_, *b_;
    const u16 *Wzl_, *Wzr_, *Ain;
    int K;
    if (layer == 0){
      bl_=bl0; br_=br0; att_=att0; g_=g0; b_=b0;
      Wzl_ = Wzl0; Wzr_ = Wzr0; Ain = xbf; K = F_NODE_;
    } else {
      int i = layer - 1;
      bl_ = bl + (size_t)i*HID_;  br_ = br + (size_t)i*HID_;
      att_= att + (size_t)i*HID_;
      g_  = gg + (size_t)i*HID_;  b_  = bb + (size_t)i*HID_;
      Wzl_ = Wzl123 + (size_t)i*HID_*128;
      Wzr_ = Wzr123 + (size_t)i*HID_*128;
      Ain = h; K = HID_;
    }
    float* stats = stats4 + layer*1024;
    hipLaunchKernelGGL(k_gemm_eproj, dim3(2*GEMM_GRID + EPROJ_GRID), dim3(256), 0, stream,
                       Ain, Wzl_, Wzr_, bl_, br_, xl, (u16*)xr_aggr, N_NODES, K,
                       ea16, Wez4 + (size_t)layer*32*128, eproj);
    hipLaunchKernelGGL(k_gat_ep, dim3(GAT_GRID), dim3(256), 0, stream,
                       xl, xr_aggr, eproj, att_, offsets, ssrc, stats);
    hipLaunchKernelGGL(k_bn_apply, dim3((N_NODES*16 + 255)/256), dim3(256), 0, stream,
                       xr_aggr, stats, g_, b_, h, layer > 0 ? 1 : 0);
  }
  hipLaunchKernelGGL(k_pool_seg, dim3(N_GRAPH), dim3(256), 0, stream, (const unsigned*)h, goff, emb);
  hipLaunchKernelGGL(k_heads, dim3(N_GRAPH/HG, N_TASK), dim3(128), 0, stream, emb, mf, fpi, tw1, tb1, tw2, tb2, out);
}

// Round 9
// 730.220 us; speedup vs baseline: 2.1806x; 1.0176x over previous
//
#include <hip/hip_runtime.h>
#include <hip/hip_bf16.h>

#define N_NODES 100000
#define N_EDGES 400000
#define F_NODE_ 64
#define F_EDGE_ 16
#define HID_ 128
#define N_GRAPH 1024
#define N_TASK 5

typedef unsigned short u16;
typedef __attribute__((ext_vector_type(8))) short frag8;   // 8 bf16 = 4 VGPRs
typedef __attribute__((ext_vector_type(4))) float f32x4;   // MFMA C/D
typedef __attribute__((ext_vector_type(2))) float f32x2;

__device__ __forceinline__ float bu2f(u16 v){ return __uint_as_float(((unsigned)v) << 16); }
__device__ __forceinline__ float2 bp2f(unsigned u){
  return make_float2(__uint_as_float(u << 16), __uint_as_float(u & 0xFFFF0000u));
}
__device__ __forceinline__ f32x2 bp2v(unsigned u){
  f32x2 r; r.x = __uint_as_float(u << 16); r.y = __uint_as_float(u & 0xFFFF0000u); return r;
}
__device__ __forceinline__ u16 f2bu(float f){
  __hip_bfloat16 h = __float2bfloat16(f);
  return *(u16*)&h;
}
__device__ __forceinline__ unsigned packbf(float a, float b){
  return (unsigned)f2bu(a) | ((unsigned)f2bu(b) << 16);
}

struct WZ12 { const float* src[12]; u16* dst[12]; int Ks[12]; int Kd[12]; };

// ---------------- cast f32->bf16 + edge histogram + graph offsets + W pre-swizzle (flat grid) ----------------
#define CAST_BLKS ((N_NODES*F_NODE_ + 255)/256)
#define EG256 ((N_EDGES + 255)/256)
#define GOFF_BLKS ((N_GRAPH + 1 + 255)/256)
#define WSWZ_BLKS (12*64)
__global__ __launch_bounds__(256) void k_cast_hist(const float* __restrict__ s, u16* __restrict__ d,
                                                   const int* __restrict__ ei, int* __restrict__ counts,
                                                   const int* __restrict__ batch, int* __restrict__ goff,
                                                   WZ12 p){
  int b = blockIdx.x;
  if (b < CAST_BLKS){
    int i = b*256 + threadIdx.x;
    if (i < N_NODES*F_NODE_) d[i] = f2bu(s[i]);
  } else if (b < CAST_BLKS + EG256){
    int e = (b - CAST_BLKS)*256 + threadIdx.x;
    if (e < N_EDGES) atomicAdd(&counts[ei[N_EDGES + e]], 1);
  } else if (b < CAST_BLKS + EG256 + GOFF_BLKS){
    int g = (b - CAST_BLKS - EG256)*256 + threadIdx.x;
    if (g <= N_GRAPH){
      int lo = 0, hi = N_NODES;
      while (lo < hi){
        int mid = (lo + hi) >> 1;
        if (batch[mid] < g) lo = mid + 1; else hi = mid;
      }
      goff[g] = lo;
    }
  } else {
    int bb = b - CAST_BLKS - EG256 - GOFF_BLKS;   // 0..767
    const int sW = bb >> 6;
    const int Kd = p.Kd[sW], Ks = p.Ks[sW];
    int i = (bb & 63)*256 + threadIdx.x;
    if (i >= Kd*128) return;
    int k = i >> 7, n = i & 127;
    float v = (k < Ks) ? p.src[sW][k*128 + n] : 0.f;
    int kk = k & 31, c = k >> 5;
    int quad = kk >> 3, j = kk & 7;
    int nt = n >> 4;
    int lane = quad*16 + (n & 15);
    p.dst[sW][(((c*8 + nt)*64) + lane)*8 + j] = f2bu(v);
  }
}

// ---------------- fused: paired MFMA GEMMs + eproj MFMA GEMM (flat grid) ----------------
// C-write: stage tile in LDS (quad-XOR swizzle, conflict-free) then coalesced uint4 stores.
#define GEMM_GRID ((N_NODES + 127)/128)   // 782
#define EPROJ_GRID ((N_EDGES + 127)/128)  // 3125
__global__ __launch_bounds__(256) void k_gemm_eproj(const u16* __restrict__ A,
                                                    const u16* __restrict__ Wzl,
                                                    const u16* __restrict__ Wzr,
                                                    const float* __restrict__ bl,
                                                    const float* __restrict__ br,
                                                    u16* __restrict__ Cl,
                                                    u16* Cr,
                                                    int M, int K,
                                                    const u16* __restrict__ ea16,
                                                    const u16* __restrict__ Wez,
                                                    u16* __restrict__ eproj){
  __shared__ u16 WS[128*128];
  const int t = threadIdx.x;
  const int b = blockIdx.x;
  if (b < 2*GEMM_GRID){
    const int which = (b >= GEMM_GRID);
    const int bx = which ? b - GEMM_GRID : b;
    const u16*   Wz   = which ? Wzr : Wzl;
    const float* bias = which ? br  : bl;
    u16*         C    = which ? Cr  : Cl;
    {
      const uint4* src = (const uint4*)Wz;
      uint4* dst = (uint4*)WS;
      const int n = (K*128) >> 3;
      for (int i = t; i < n; i += 256) dst[i] = src[i];
    }
    __syncthreads();
    const int w = t >> 6, l = t & 63;
    const int m = l & 15, quad = l >> 4;
    const int rowA0 = bx*128 + w*32 + m;
    const int rowA1 = rowA0 + 16;
    f32x4 acc[2][8];
    #pragma unroll
    for (int i=0;i<2;i++)
      #pragma unroll
      for (int j=0;j<8;j++) acc[i][j] = (f32x4){0.f,0.f,0.f,0.f};
    const int KC = K >> 5;
    for (int c = 0; c < KC; c++){
      frag8 a0 = {}, a1 = {};
      if (rowA0 < M) a0 = *(const frag8*)(A + (size_t)rowA0*K + c*32 + quad*8);
      if (rowA1 < M) a1 = *(const frag8*)(A + (size_t)rowA1*K + c*32 + quad*8);
      #pragma unroll
      for (int nt = 0; nt < 8; nt++){
        frag8 bfr = *(const frag8*)&WS[(((c*8 + nt)*64) + l)*8];
        acc[0][nt] = __builtin_amdgcn_mfma_f32_16x16x32_bf16(a0, bfr, acc[0][nt], 0,0,0);
        acc[1][nt] = __builtin_amdgcn_mfma_f32_16x16x32_bf16(a1, bfr, acc[1][nt], 0,0,0);
      }
    }
    float bcv[8];
    #pragma unroll
    for (int nt=0; nt<8; nt++) bcv[nt] = bias[nt*16 + m];
    __syncthreads();          // all WS reads (MFMA) done
    const int sXor = quad << 4;   // quads -> disjoint bank groups
    #pragma unroll
    for (int rt = 0; rt < 2; rt++){
      #pragma unroll
      for (int r = 0; r < 4; r++){
        const int row = w*32 + rt*16 + quad*4 + r;
        #pragma unroll
        for (int nt = 0; nt < 8; nt++){
          const int col = nt*16 + m;
          WS[row*128 + (col ^ sXor)] = f2bu(acc[rt][nt][r] + bcv[nt]);
        }
      }
    }
    __syncthreads();
    #pragma unroll
    for (int i = 0; i < 8; i++){
      const int idx = i*256 + t;
      const int row = idx >> 4, k16 = idx & 15;
      const int grp = (k16*8) ^ (((row>>2)&3)<<4);
      const int grow = bx*128 + row;
      if (grow < M)
        *(uint4*)(C + (size_t)grow*128 + k16*8) = *(const uint4*)&WS[row*128 + grp];
    }
  } else {
    // eproj GEMM: 128 edges/block, K=32 via fragment zero-padding
    const int bx = b - 2*GEMM_GRID;
    {
      const uint4* s4 = (const uint4*)Wez;
      uint4* d4 = (uint4*)WS;
      for (int i = t; i < 512; i += 256) d4[i] = s4[i];
    }
    __syncthreads();
    const int w = t >> 6, l = t & 63, m = l & 15, quad = l >> 4;
    const int row0 = bx*128 + w*32 + m;
    const int row1 = row0 + 16;
    f32x4 acc[2][8];
    #pragma unroll
    for (int i=0;i<2;i++)
      #pragma unroll
      for (int j=0;j<8;j++) acc[i][j] = (f32x4){0.f,0.f,0.f,0.f};
    frag8 a0 = {}, a1 = {};
    if (quad < 2){
      a0 = *(const frag8*)(ea16 + (size_t)row0*16 + quad*8);   // grid exact: rows < N_EDGES
      a1 = *(const frag8*)(ea16 + (size_t)row1*16 + quad*8);
    }
    #pragma unroll
    for (int nt = 0; nt < 8; nt++){
      frag8 bfr = *(const frag8*)&WS[(nt*64 + l)*8];
      acc[0][nt] = __builtin_amdgcn_mfma_f32_16x16x32_bf16(a0, bfr, acc[0][nt], 0,0,0);
      acc[1][nt] = __builtin_amdgcn_mfma_f32_16x16x32_bf16(a1, bfr, acc[1][nt], 0,0,0);
    }
    __syncthreads();
    const int sXor = quad << 4;
    #pragma unroll
    for (int rt = 0; rt < 2; rt++){
      #pragma unroll
      for (int r = 0; r < 4; r++){
        const int row = w*32 + rt*16 + quad*4 + r;
        #pragma unroll
        for (int nt = 0; nt < 8; nt++){
          const int col = nt*16 + m;
          WS[row*128 + (col ^ sXor)] = f2bu(acc[rt][nt][r]);
        }
      }
    }
    __syncthreads();
    #pragma unroll
    for (int i = 0; i < 8; i++){
      const int idx = i*256 + t;
      const int row = idx >> 4, k16 = idx & 15;
      const int grp = (k16*8) ^ (((row>>2)&3)<<4);
      *(uint4*)(eproj + ((size_t)(bx*128 + row))*128 + k16*8) = *(const uint4*)&WS[row*128 + grp];
    }
  }
}

__global__ __launch_bounds__(512) void k_scan1(const int* __restrict__ counts,
                                               int* __restrict__ incl,
                                               int* __restrict__ bsum){
  __shared__ int s[512];
  const int t = threadIdx.x;
  int i = blockIdx.x*512 + t;
  int v = (i < N_NODES) ? counts[i] : 0;
  s[t] = v;
  __syncthreads();
  for (int off = 1; off < 512; off <<= 1){
    int x = (t >= off) ? s[t - off] : 0;
    __syncthreads();
    s[t] += x;
    __syncthreads();
  }
  if (i < N_NODES) incl[i] = s[t];
  if (t == 511) bsum[blockIdx.x] = s[511];
}

// scan3 with in-block redundant scan of bsum
__global__ __launch_bounds__(512) void k_scan3(const int* __restrict__ counts,
                                               const int* __restrict__ incl,
                                               const int* __restrict__ bsum, int nb,
                                               int* __restrict__ offsets,
                                               int* __restrict__ cursor){
  __shared__ int sb[256];
  const int t = threadIdx.x;
  if (t < 256) sb[t] = (t < nb) ? bsum[t] : 0;
  __syncthreads();
  for (int off = 1; off < 256; off <<= 1){
    int x = 0;
    if (t < 256 && t >= off) x = sb[t - off];
    __syncthreads();
    if (t < 256) sb[t] += x;
    __syncthreads();
  }
  int i = blockIdx.x*512 + t;
  if (i >= N_NODES) return;
  int pre = (blockIdx.x == 0) ? 0 : sb[blockIdx.x - 1];
  int o = pre + incl[i];
  offsets[i + 1] = o;
  cursor[i]      = o - counts[i];
  if (i == 0) offsets[0] = 0;
}

// scatter: src index + bf16 edge features into CSR order ([E][16] bf16)
__global__ __launch_bounds__(256) void k_scatter(const int* __restrict__ ei,
                                                 int* __restrict__ cursor,
                                                 int* __restrict__ ssrc,
                                                 const float* __restrict__ ea,
                                                 u16* __restrict__ ea16){
  int e = blockIdx.x*256 + threadIdx.x;
  if (e >= N_EDGES) return;
  int dst = ei[N_EDGES + e];
  int pos = atomicAdd(&cursor[dst], 1);
  ssrc[pos] = ei[e];
  const float* s = ea + (size_t)e*F_EDGE_;
  unsigned p[8];
  #pragma unroll
  for (int k=0;k<8;k++) p[k] = packbf(s[2*k], s[2*k+1]);
  uint4* d4 = (uint4*)(ea16 + (size_t)pos*16);
  d4[0] = make_uint4(p[0],p[1],p[2],p[3]);
  d4[1] = make_uint4(p[4],p[5],p[6],p[7]);
}

// ---------------- Fused GAT v17: 2 nodes/wave, 128-thr blocks (8 nodes), BN-stats tail ----------------
// Finer block granularity -> better dynamic occupancy under degree imbalance.
// Stats striped 8-way by blockIdx to spread atomic traffic.
#define GAT_GRID (N_NODES/8)   // 12500 blocks of 128 threads
__global__ __launch_bounds__(128) void k_gat_ep(const u16* __restrict__ xl,
                                                unsigned* xr_aggr,
                                                const u16* __restrict__ eproj,
                                                const float* __restrict__ att,
                                                const int* __restrict__ offsets,
                                                const int* __restrict__ ssrc,
                                                float* __restrict__ stats){
  __shared__ float red[4][264];           // [group][0..127 sum | 128..255 sq]
  const int t = threadIdx.x;              // 0..127
  const int wave = t >> 6, lane = t & 63;
  const int half = lane >> 5, l32 = lane & 31;
  const int c0 = l32*4;                   // 4 channels per lane
  const float4 av = *(const float4*)(att + c0);
  float ss0=0.f, ss1=0.f, ss2=0.f, ss3=0.f;
  float qq0=0.f, qq1=0.f, qq2=0.f, qq3=0.f;

  for (int k = 0; k < 2; k++){
    const int node = blockIdx.x*8 + wave*4 + k*2 + half;    // < N_NODES (grid exact)
    const uint2 xru = *(const uint2*)(xr_aggr + (size_t)node*64 + l32*2);
    const f32x2 xr0 = bp2v(xru.x), xr1 = bp2v(xru.y);
    f32x2 acc0 = {0.f,0.f}, acc1 = {0.f,0.f};
    float den = 0.f;
    const int beg = offsets[node], end = offsets[node+1];
    int it = (end - beg + 3) >> 2;
    int oit = __shfl_xor(it, 32);
    const int maxit = it > oit ? it : oit;
    int i = beg;
    for (int n = 0; n < maxit; n++, i += 4){
      const int mm = end - i;
      int ib = (mm > 0) ? i : beg;
      ib = ib < N_EDGES ? ib : N_EDGES - 1;
      const int i0 = ib;
      const int i1 = (mm > 1) ? i+1 : ib;
      const int i2 = (mm > 2) ? i+2 : ib;
      const int i3 = (mm > 3) ? i+3 : ib;
      const int s0 = ssrc[i0], s1 = ssrc[i1], s2 = ssrc[i2], s3 = ssrc[i3];
      const uint2 e0 = *(const uint2*)(eproj + (size_t)i0*128 + c0);
      const uint2 e1 = *(const uint2*)(eproj + (size_t)i1*128 + c0);
      const uint2 e2 = *(const uint2*)(eproj + (size_t)i2*128 + c0);
      const uint2 e3 = *(const uint2*)(eproj + (size_t)i3*128 + c0);
      const uint2 x0 = *(const uint2*)(xl + (size_t)s0*HID_ + c0);
      const uint2 x1 = *(const uint2*)(xl + (size_t)s1*HID_ + c0);
      const uint2 x2 = *(const uint2*)(xl + (size_t)s2*HID_ + c0);
      const uint2 x3 = *(const uint2*)(xl + (size_t)s3*HID_ + c0);
      const f32x2 vl00 = bp2v(x0.x), vl01 = bp2v(x0.y);
      const f32x2 vl10 = bp2v(x1.x), vl11 = bp2v(x1.y);
      const f32x2 vl20 = bp2v(x2.x), vl21 = bp2v(x2.y);
      const f32x2 vl30 = bp2v(x3.x), vl31 = bp2v(x3.y);
      f32x2 v00 = vl00 + xr0 + bp2v(e0.x), v01 = vl01 + xr1 + bp2v(e0.y);
      f32x2 v10 = vl10 + xr0 + bp2v(e1.x), v11 = vl11 + xr1 + bp2v(e1.y);
      f32x2 v20 = vl20 + xr0 + bp2v(e2.x), v21 = vl21 + xr1 + bp2v(e2.y);
      f32x2 v30 = vl30 + xr0 + bp2v(e3.x), v31 = vl31 + xr1 + bp2v(e3.y);
      f32x2 w;
      w = v00*0.2f; v00.x = fmaxf(v00.x,w.x); v00.y = fmaxf(v00.y,w.y);
      w = v01*0.2f; v01.x = fmaxf(v01.x,w.x); v01.y = fmaxf(v01.y,w.y);
      w = v10*0.2f; v10.x = fmaxf(v10.x,w.x); v10.y = fmaxf(v10.y,w.y);
      w = v11*0.2f; v11.x = fmaxf(v11.x,w.x); v11.y = fmaxf(v11.y,w.y);
      w = v20*0.2f; v20.x = fmaxf(v20.x,w.x); v20.y = fmaxf(v20.y,w.y);
      w = v21*0.2f; v21.x = fmaxf(v21.x,w.x); v21.y = fmaxf(v21.y,w.y);
      w = v30*0.2f; v30.x = fmaxf(v30.x,w.x); v30.y = fmaxf(v30.y,w.y);
      w = v31*0.2f; v31.x = fmaxf(v31.x,w.x); v31.y = fmaxf(v31.y,w.y);
      float sc0 = v00.x*av.x + v00.y*av.y + v01.x*av.z + v01.y*av.w;
      float sc1 = v10.x*av.x + v10.y*av.y + v11.x*av.z + v11.y*av.w;
      float sc2 = v20.x*av.x + v20.y*av.y + v21.x*av.z + v21.y*av.w;
      float sc3 = v30.x*av.x + v30.y*av.y + v31.x*av.z + v31.y*av.w;
      sc0 += __shfl_xor(sc0, 1); sc1 += __shfl_xor(sc1, 1); sc2 += __shfl_xor(sc2, 1); sc3 += __shfl_xor(sc3, 1);
      sc0 += __shfl_xor(sc0, 2); sc1 += __shfl_xor(sc1, 2); sc2 += __shfl_xor(sc2, 2); sc3 += __shfl_xor(sc3, 2);
      sc0 += __shfl_xor(sc0, 4); sc1 += __shfl_xor(sc1, 4); sc2 += __shfl_xor(sc2, 4); sc3 += __shfl_xor(sc3, 4);
      const float p0 = (mm > 0) ? __expf(sc0) : 0.f;
      const float p1 = (mm > 1) ? __expf(sc1) : 0.f;
      const float p2 = (mm > 2) ? __expf(sc2) : 0.f;
      const float p3 = (mm > 3) ? __expf(sc3) : 0.f;
      acc0 += p0*vl00 + p1*vl10 + p2*vl20 + p3*vl30;
      acc1 += p0*vl01 + p1*vl11 + p2*vl21 + p3*vl31;
      den  += p0 + p1 + p2 + p3;
    }
    const float inv = 1.0f / (den + 1e-16f);
    uint2 outv;
    outv.x = packbf(acc0.x*inv, acc0.y*inv);
    outv.y = packbf(acc1.x*inv, acc1.y*inv);
    *(uint2*)(xr_aggr + (size_t)node*64 + l32*2) = outv;
    // stats from the packed (bf16-rounded) values
    const float2 o0 = bp2f(outv.x), o1 = bp2f(outv.y);
    ss0 += o0.x; ss1 += o0.y; ss2 += o1.x; ss3 += o1.y;
    qq0 += o0.x*o0.x; qq1 += o0.y*o0.y; qq2 += o1.x*o1.x; qq3 += o1.y*o1.y;
  }
  const int g = wave*2 + half;            // 0..3
  red[g][c0+0] = ss0; red[g][c0+1] = ss1; red[g][c0+2] = ss2; red[g][c0+3] = ss3;
  red[g][128+c0+0] = qq0; red[g][128+c0+1] = qq1; red[g][128+c0+2] = qq2; red[g][128+c0+3] = qq3;
  __syncthreads();
  {
    float a = 0.f, b2 = 0.f;
    #pragma unroll
    for (int gg = 0; gg < 4; gg++){ a += red[gg][t]; b2 += red[gg][128+t]; }
    const int base = (blockIdx.x & 7)*256;   // 8-way stripe
    atomicAdd(&stats[base + t],       a);
    atomicAdd(&stats[base + 128 + t], b2);
  }
}

// ---------------- BN apply + ELU (+ residual): pre-reduce 8 stripes + scale/shift in LDS ----------------
__global__ __launch_bounds__(256) void k_bn_apply(const unsigned* __restrict__ aggr_b,
                                                  const float* __restrict__ stats,
                                                  const float* __restrict__ gamma,
                                                  const float* __restrict__ beta,
                                                  u16* __restrict__ h, int residual){
  __shared__ float sc_sh[128], sh_sh[128];
  const int t = threadIdx.x;
  if (t < 128){
    float s = 0.f, q = 0.f;
    #pragma unroll
    for (int st = 0; st < 8; st++){
      s += stats[st*256 + t];
      q += stats[st*256 + 128 + t];
    }
    const float invn = 1.0f / (float)N_NODES;
    float mu = s * invn;
    float var = q * invn - mu*mu;
    float sc = rsqrtf(var + 1e-5f) * gamma[t];
    sc_sh[t] = sc;
    sh_sh[t] = beta[t] - mu * sc;
  }
  __syncthreads();
  size_t i = (size_t)blockIdx.x*256 + t;   // uint4-group index (8 channels)
  if (i >= (size_t)N_NODES*16) return;
  const int c = (int)((i & 15) * 8);
  uint4 v4 = ((const uint4*)aggr_b)[i];
  uint4* hp = (uint4*)h + i;
  uint4 hv4 = make_uint4(0,0,0,0);
  if (residual) hv4 = *hp;
  unsigned vin[4]  = {v4.x, v4.y, v4.z, v4.w};
  unsigned hin[4]  = {hv4.x, hv4.y, hv4.z, hv4.w};
  unsigned outw[4];
  #pragma unroll
  for (int j=0;j<4;j++){
    int cc = c + j*2;
    float2 v = bp2f(vin[j]);
    float val0 = v.x * sc_sh[cc]   + sh_sh[cc];
    float val1 = v.y * sc_sh[cc+1] + sh_sh[cc+1];
    val0 = val0 > 0.f ? val0 : expm1f(val0);
    val1 = val1 > 0.f ? val1 : expm1f(val1);
    if (residual){
      float2 hv = bp2f(hin[j]);
      val0 += hv.x; val1 += hv.y;
    }
    outw[j] = packbf(val0, val1);
  }
  *hp = make_uint4(outw[0], outw[1], outw[2], outw[3]);
}

// ---------------- Pool + heads fused: 8 graphs per block, emb kept in LDS ----------------
#define HG 8
__global__ __launch_bounds__(256) void k_pool_heads(const unsigned* __restrict__ h2,
                                                    const int* __restrict__ goff,
                                                    const float* __restrict__ mf,
                                                    const int* __restrict__ fpi,
                                                    const float* __restrict__ tw1,
                                                    const float* __restrict__ tb1,
                                                    const float* __restrict__ tw2,
                                                    const float* __restrict__ tb2,
                                                    float* __restrict__ out){
  __shared__ float emb_sh[HG][128];
  __shared__ float fp_sh[HG][32];
  __shared__ float red[HG][128];
  __shared__ float redS[4][128];
  const int t = threadIdx.x;
  const int g0 = blockIdx.x*HG;
  const int p = t & 63, rg = t >> 6;
  // pool: per-graph segmented mean into LDS
  for (int gl = 0; gl < HG; gl++){
    const int beg = goff[g0+gl], end = goff[g0+gl+1];
    float a0 = 0.f, a1 = 0.f;
    for (int r = beg + rg; r < end; r += 4){
      float2 v = bp2f(h2[(size_t)r*64 + p]);
      a0 += v.x; a1 += v.y;
    }
    redS[rg][p*2] = a0; redS[rg][p*2+1] = a1;
    __syncthreads();
    if (rg == 0){
      #pragma unroll
      for (int k=1;k<4;k++){ a0 += redS[k][p*2]; a1 += redS[k][p*2+1]; }
      float n = fmaxf((float)(end - beg), 1.f);
      emb_sh[gl][p*2]     = a0 / n;
      emb_sh[gl][p*2 + 1] = a1 / n;
    }
    __syncthreads();
  }
  // heads: graphs split across thread halves
  const int th = t >> 7, j = t & 127;
  for (int task = 0; task < N_TASK; task++){
    {
      int g = t >> 5, i = t & 31;
      fp_sh[g][i] = mf[(size_t)(g0+g)*2048 + fpi[task*32 + i]];
    }
    __syncthreads();
    const float* w1 = tw1 + (size_t)task*160*128;
    float acc[4];
    float b1 = tb1[task*128 + j];
    #pragma unroll
    for (int g=0;g<4;g++) acc[g] = b1;
    for (int i=0;i<128;i++){
      float wv = w1[(size_t)i*128 + j];
      #pragma unroll
      for (int g=0;g<4;g++) acc[g] += emb_sh[th*4+g][i] * wv;
    }
    for (int i=0;i<32;i++){
      float wv = w1[(size_t)(128+i)*128 + j];
      #pragma unroll
      for (int g=0;g<4;g++) acc[g] += fp_sh[th*4+g][i] * wv;
    }
    float t2 = tw2[task*128 + j];
    #pragma unroll
    for (int g=0;g<4;g++){
      float v = acc[g] > 0.f ? acc[g] : 0.f;
      red[th*4+g][j] = v * t2;
    }
    __syncthreads();
    if (t < 128){
      int g = t >> 4, l16 = t & 15;
      float s = 0.f;
      #pragma unroll
      for (int k=0;k<8;k++) s += red[g][l16 + k*16];
      s += __shfl_xor(s, 1, 16);
      s += __shfl_xor(s, 2, 16);
      s += __shfl_xor(s, 4, 16);
      s += __shfl_xor(s, 8, 16);
      if (l16 == 0) out[(size_t)(g0+g)*N_TASK + task] = s + tb2[task];
    }
    __syncthreads();
  }
}

extern "C" void kernel_launch(void* const* d_in, const int* in_sizes, int n_in,
                              void* d_out, int out_size, void* d_ws, size_t ws_size,
                              hipStream_t stream){
  const float* x    = (const float*)d_in[0];
  const int*   ei   = (const int*)  d_in[1];
  const float* ea   = (const float*)d_in[2];
  const int*   batch= (const int*)  d_in[3];
  const float* mf   = (const float*)d_in[4];
  const int*   fpi  = (const int*)  d_in[5];
  const float* Wl0  = (const float*)d_in[6];
  const float* bl0  = (const float*)d_in[7];
  const float* Wr0  = (const float*)d_in[8];
  const float* br0  = (const float*)d_in[9];
  const float* We0  = (const float*)d_in[10];
  const float* att0 = (const float*)d_in[11];
  const float* g0   = (const float*)d_in[13];
  const float* b0   = (const float*)d_in[14];
  const float* Wl   = (const float*)d_in[15];
  const float* bl   = (const float*)d_in[16];
  const float* Wr   = (const float*)d_in[17];
  const float* br   = (const float*)d_in[18];
  const float* We   = (const float*)d_in[19];
  const float* att  = (const float*)d_in[20];
  const float* gg   = (const float*)d_in[22];
  const float* bb   = (const float*)d_in[23];
  const float* tw1  = (const float*)d_in[24];
  const float* tb1  = (const float*)d_in[25];
  const float* tw2  = (const float*)d_in[26];
  const float* tb2  = (const float*)d_in[27];
  float* out = (float*)d_out;

  char* w = (char*)d_ws;
  auto alloc = [&](size_t bytes)->char*{ char* r = w; w += (bytes + 255) & ~(size_t)255; return r; };
  u16*   xl     = (u16*)  alloc((size_t)N_NODES*HID_*2);
  unsigned* xr_aggr = (unsigned*)alloc((size_t)N_NODES*64*4);
  u16*   h      = (u16*)  alloc((size_t)N_NODES*HID_*2);
  u16*   ea16   = (u16*)  alloc((size_t)N_EDGES*16*2);
  int*   counts = (int*)  alloc((size_t)N_NODES*4);
  float* stats4 = (float*)alloc(4*2048*4);            // 4 layers x 8 stripes x 256 floats
  int*   offsets= (int*)  alloc((size_t)(N_NODES+1)*4);
  int*   cursor = (int*)  alloc((size_t)N_NODES*4);
  int*   incl   = (int*)  alloc((size_t)N_NODES*4);
  int*   bsum   = (int*)  alloc(256*4);
  int*   ssrc   = (int*)  alloc((size_t)N_EDGES*4);
  int*   goff   = (int*)  alloc((size_t)(N_GRAPH+1)*4);
  float* emb    = (float*)alloc((size_t)N_GRAPH*HID_*4);
  u16*   Wzl0   = (u16*)  alloc((size_t)F_NODE_*128*2);
  u16*   Wzr0   = (u16*)  alloc((size_t)F_NODE_*128*2);
  u16*   Wzl123 = (u16*)  alloc((size_t)3*HID_*128*2);
  u16*   Wzr123 = (u16*)  alloc((size_t)3*HID_*128*2);
  u16*   Wez4   = (u16*)  alloc((size_t)4*32*128*2);
  u16*   eproj  = (u16*)  alloc((size_t)N_EDGES*HID_*2);
  u16*   xbf    = (u16*)  alloc((size_t)N_NODES*F_NODE_*2);  // separate from eproj (no race)

  const size_t zlen = (size_t)((char*)(stats4 + 4*2048) - (char*)counts);
  const int nscan = (N_NODES + 511)/512;

  WZ12 p;
  p.src[0] = Wl0; p.dst[0] = Wzl0; p.Ks[0] = F_NODE_; p.Kd[0] = F_NODE_;
  p.src[1] = Wr0; p.dst[1] = Wzr0; p.Ks[1] = F_NODE_; p.Kd[1] = F_NODE_;
  for (int i=0;i<3;i++){
    p.src[2+i] = Wl + (size_t)i*HID_*HID_; p.dst[2+i] = Wzl123 + (size_t)i*HID_*128; p.Ks[2+i] = HID_; p.Kd[2+i] = HID_;
    p.src[5+i] = Wr + (size_t)i*HID_*HID_; p.dst[5+i] = Wzr123 + (size_t)i*HID_*128; p.Ks[5+i] = HID_; p.Kd[5+i] = HID_;
  }
  p.src[8] = We0; p.dst[8] = Wez4; p.Ks[8] = F_EDGE_; p.Kd[8] = 32;
  for (int i=0;i<3;i++){
    p.src[9+i] = We + (size_t)i*F_EDGE_*HID_; p.dst[9+i] = Wez4 + (size_t)(i+1)*32*128; p.Ks[9+i] = F_EDGE_; p.Kd[9+i] = 32;
  }

  hipMemsetAsync(counts, 0, zlen, stream);
  hipLaunchKernelGGL(k_cast_hist, dim3(CAST_BLKS + EG256 + GOFF_BLKS + WSWZ_BLKS), dim3(256), 0, stream,
                     x, xbf, ei, counts, batch, goff, p);
  hipLaunchKernelGGL(k_scan1,  dim3(nscan), dim3(512), 0, stream, counts, incl, bsum);
  hipLaunchKernelGGL(k_scan3,  dim3(nscan), dim3(512), 0, stream, counts, incl, bsum, nscan, offsets, cursor);
  hipLaunchKernelGGL(k_scatter,dim3(EG256), dim3(256), 0, stream, ei, cursor, ssrc, ea, ea16);

  for (int layer = 0; layer < 4; layer++){
    const float *bl_, *br_, *att_, *g_, *b_;
    const u16 *Wzl_, *Wzr_, *Ain;
    int K;
    if (layer == 0){
      bl_=bl0; br_=br0; att_=att0; g_=g0; b_=b0;
      Wzl_ = Wzl0; Wzr_ = Wzr0; Ain = xbf; K = F_NODE_;
    } else {
      int i = layer - 1;
      bl_ = bl + (size_t)i*HID_;  br_ = br + (size_t)i*HID_;
      att_= att + (size_t)i*HID_;
      g_  = gg + (size_t)i*HID_;  b_  = bb + (size_t)i*HID_;
      Wzl_ = Wzl123 + (size_t)i*HID_*128;
      Wzr_ = Wzr123 + (size_t)i*HID_*128;
      Ain = h; K = HID_;
    }
    float* stats = stats4 + layer*2048;
    hipLaunchKernelGGL(k_gemm_eproj, dim3(2*GEMM_GRID + EPROJ_GRID), dim3(256), 0, stream,
                       Ain, Wzl_, Wzr_, bl_, br_, xl, (u16*)xr_aggr, N_NODES, K,
                       ea16, Wez4 + (size_t)layer*32*128, eproj);
    hipLaunchKernelGGL(k_gat_ep, dim3(GAT_GRID), dim3(128), 0, stream,
                       xl, xr_aggr, eproj, att_, offsets, ssrc, stats);
    hipLaunchKernelGGL(k_bn_apply, dim3((N_NODES*16 + 255)/256), dim3(256), 0, stream,
                       xr_aggr, stats, g_, b_, h, layer > 0 ? 1 : 0);
  }
  hipLaunchKernelGGL(k_pool_heads, dim3(N_GRAPH/HG), dim3(256), 0, stream,
                     (const unsigned*)h, goff, mf, fpi, tw1, tb1, tw2, tb2, out);
}

// Round 10
// 667.489 us; speedup vs baseline: 2.3855x; 1.0940x over previous
//
#include <hip/hip_runtime.h>
#include <hip/hip_bf16.h>

#define N_NODES 100000
#define N_EDGES 400000
#define F_NODE_ 64
#define F_EDGE_ 16
#define HID_ 128
#define N_GRAPH 1024
#define N_TASK 5

typedef unsigned short u16;
typedef __attribute__((ext_vector_type(8))) short frag8;   // 8 bf16 = 4 VGPRs
typedef __attribute__((ext_vector_type(4))) float f32x4;   // MFMA C/D
typedef __attribute__((ext_vector_type(2))) float f32x2;

__device__ __forceinline__ float bu2f(u16 v){ return __uint_as_float(((unsigned)v) << 16); }
__device__ __forceinline__ float2 bp2f(unsigned u){
  return make_float2(__uint_as_float(u << 16), __uint_as_float(u & 0xFFFF0000u));
}
__device__ __forceinline__ f32x2 bp2v(unsigned u){
  f32x2 r; r.x = __uint_as_float(u << 16); r.y = __uint_as_float(u & 0xFFFF0000u); return r;
}
__device__ __forceinline__ u16 f2bu(float f){
  __hip_bfloat16 h = __float2bfloat16(f);
  return *(u16*)&h;
}
__device__ __forceinline__ unsigned packbf(float a, float b){
  return (unsigned)f2bu(a) | ((unsigned)f2bu(b) << 16);
}

struct WZ12 { const float* src[12]; u16* dst[12]; int Ks[12]; int Kd[12]; };

// ---------------- cast f32->bf16 + edge histogram + graph offsets + W pre-swizzle (flat grid) ----------------
#define CAST_BLKS ((N_NODES*F_NODE_ + 255)/256)
#define EG256 ((N_EDGES + 255)/256)
#define GOFF_BLKS ((N_GRAPH + 1 + 255)/256)
#define WSWZ_BLKS (12*64)
__global__ __launch_bounds__(256) void k_cast_hist(const float* __restrict__ s, u16* __restrict__ d,
                                                   const int* __restrict__ ei, int* __restrict__ counts,
                                                   const int* __restrict__ batch, int* __restrict__ goff,
                                                   WZ12 p){
  int b = blockIdx.x;
  if (b < CAST_BLKS){
    int i = b*256 + threadIdx.x;
    if (i < N_NODES*F_NODE_) d[i] = f2bu(s[i]);
  } else if (b < CAST_BLKS + EG256){
    int e = (b - CAST_BLKS)*256 + threadIdx.x;
    if (e < N_EDGES) atomicAdd(&counts[ei[N_EDGES + e]], 1);
  } else if (b < CAST_BLKS + EG256 + GOFF_BLKS){
    int g = (b - CAST_BLKS - EG256)*256 + threadIdx.x;
    if (g <= N_GRAPH){
      int lo = 0, hi = N_NODES;
      while (lo < hi){
        int mid = (lo + hi) >> 1;
        if (batch[mid] < g) lo = mid + 1; else hi = mid;
      }
      goff[g] = lo;
    }
  } else {
    int bb = b - CAST_BLKS - EG256 - GOFF_BLKS;   // 0..767
    const int sW = bb >> 6;
    const int Kd = p.Kd[sW], Ks = p.Ks[sW];
    int i = (bb & 63)*256 + threadIdx.x;
    if (i >= Kd*128) return;
    int k = i >> 7, n = i & 127;
    float v = (k < Ks) ? p.src[sW][k*128 + n] : 0.f;
    int kk = k & 31, c = k >> 5;
    int quad = kk >> 3, j = kk & 7;
    int nt = n >> 4;
    int lane = quad*16 + (n & 15);
    p.dst[sW][(((c*8 + nt)*64) + lane)*8 + j] = f2bu(v);
  }
}

// ---------------- fused: paired MFMA GEMMs + eproj MFMA GEMM (flat grid) ----------------
// C-write: stage tile in LDS (quad-XOR swizzle, conflict-free) then coalesced uint4 stores.
#define GEMM_GRID ((N_NODES + 127)/128)   // 782
#define EPROJ_GRID ((N_EDGES + 127)/128)  // 3125
__global__ __launch_bounds__(256) void k_gemm_eproj(const u16* __restrict__ A,
                                                    const u16* __restrict__ Wzl,
                                                    const u16* __restrict__ Wzr,
                                                    const float* __restrict__ bl,
                                                    const float* __restrict__ br,
                                                    u16* __restrict__ Cl,
                                                    u16* Cr,
                                                    int M, int K,
                                                    const u16* __restrict__ ea16,
                                                    const u16* __restrict__ Wez,
                                                    u16* __restrict__ eproj){
  __shared__ u16 WS[128*128];
  const int t = threadIdx.x;
  const int b = blockIdx.x;
  if (b < 2*GEMM_GRID){
    const int which = (b >= GEMM_GRID);
    const int bx = which ? b - GEMM_GRID : b;
    const u16*   Wz   = which ? Wzr : Wzl;
    const float* bias = which ? br  : bl;
    u16*         C    = which ? Cr  : Cl;
    {
      const uint4* src = (const uint4*)Wz;
      uint4* dst = (uint4*)WS;
      const int n = (K*128) >> 3;
      for (int i = t; i < n; i += 256) dst[i] = src[i];
    }
    __syncthreads();
    const int w = t >> 6, l = t & 63;
    const int m = l & 15, quad = l >> 4;
    const int rowA0 = bx*128 + w*32 + m;
    const int rowA1 = rowA0 + 16;
    f32x4 acc[2][8];
    #pragma unroll
    for (int i=0;i<2;i++)
      #pragma unroll
      for (int j=0;j<8;j++) acc[i][j] = (f32x4){0.f,0.f,0.f,0.f};
    const int KC = K >> 5;
    for (int c = 0; c < KC; c++){
      frag8 a0 = {}, a1 = {};
      if (rowA0 < M) a0 = *(const frag8*)(A + (size_t)rowA0*K + c*32 + quad*8);
      if (rowA1 < M) a1 = *(const frag8*)(A + (size_t)rowA1*K + c*32 + quad*8);
      #pragma unroll
      for (int nt = 0; nt < 8; nt++){
        frag8 bfr = *(const frag8*)&WS[(((c*8 + nt)*64) + l)*8];
        acc[0][nt] = __builtin_amdgcn_mfma_f32_16x16x32_bf16(a0, bfr, acc[0][nt], 0,0,0);
        acc[1][nt] = __builtin_amdgcn_mfma_f32_16x16x32_bf16(a1, bfr, acc[1][nt], 0,0,0);
      }
    }
    float bcv[8];
    #pragma unroll
    for (int nt=0; nt<8; nt++) bcv[nt] = bias[nt*16 + m];
    __syncthreads();          // all WS reads (MFMA) done
    const int sXor = quad << 4;   // quads -> disjoint bank groups
    #pragma unroll
    for (int rt = 0; rt < 2; rt++){
      #pragma unroll
      for (int r = 0; r < 4; r++){
        const int row = w*32 + rt*16 + quad*4 + r;
        #pragma unroll
        for (int nt = 0; nt < 8; nt++){
          const int col = nt*16 + m;
          WS[row*128 + (col ^ sXor)] = f2bu(acc[rt][nt][r] + bcv[nt]);
        }
      }
    }
    __syncthreads();
    #pragma unroll
    for (int i = 0; i < 8; i++){
      const int idx = i*256 + t;
      const int row = idx >> 4, k16 = idx & 15;
      const int grp = (k16*8) ^ (((row>>2)&3)<<4);
      const int grow = bx*128 + row;
      if (grow < M)
        *(uint4*)(C + (size_t)grow*128 + k16*8) = *(const uint4*)&WS[row*128 + grp];
    }
  } else {
    // eproj GEMM: 128 edges/block, K=32 via fragment zero-padding
    const int bx = b - 2*GEMM_GRID;
    {
      const uint4* s4 = (const uint4*)Wez;
      uint4* d4 = (uint4*)WS;
      for (int i = t; i < 512; i += 256) d4[i] = s4[i];
    }
    __syncthreads();
    const int w = t >> 6, l = t & 63, m = l & 15, quad = l >> 4;
    const int row0 = bx*128 + w*32 + m;
    const int row1 = row0 + 16;
    f32x4 acc[2][8];
    #pragma unroll
    for (int i=0;i<2;i++)
      #pragma unroll
      for (int j=0;j<8;j++) acc[i][j] = (f32x4){0.f,0.f,0.f,0.f};
    frag8 a0 = {}, a1 = {};
    if (quad < 2){
      a0 = *(const frag8*)(ea16 + (size_t)row0*16 + quad*8);   // grid exact: rows < N_EDGES
      a1 = *(const frag8*)(ea16 + (size_t)row1*16 + quad*8);
    }
    #pragma unroll
    for (int nt = 0; nt < 8; nt++){
      frag8 bfr = *(const frag8*)&WS[(nt*64 + l)*8];
      acc[0][nt] = __builtin_amdgcn_mfma_f32_16x16x32_bf16(a0, bfr, acc[0][nt], 0,0,0);
      acc[1][nt] = __builtin_amdgcn_mfma_f32_16x16x32_bf16(a1, bfr, acc[1][nt], 0,0,0);
    }
    __syncthreads();
    const int sXor = quad << 4;
    #pragma unroll
    for (int rt = 0; rt < 2; rt++){
      #pragma unroll
      for (int r = 0; r < 4; r++){
        const int row = w*32 + rt*16 + quad*4 + r;
        #pragma unroll
        for (int nt = 0; nt < 8; nt++){
          const int col = nt*16 + m;
          WS[row*128 + (col ^ sXor)] = f2bu(acc[rt][nt][r]);
        }
      }
    }
    __syncthreads();
    #pragma unroll
    for (int i = 0; i < 8; i++){
      const int idx = i*256 + t;
      const int row = idx >> 4, k16 = idx & 15;
      const int grp = (k16*8) ^ (((row>>2)&3)<<4);
      *(uint4*)(eproj + ((size_t)(bx*128 + row))*128 + k16*8) = *(const uint4*)&WS[row*128 + grp];
    }
  }
}

__global__ __launch_bounds__(512) void k_scan1(const int* __restrict__ counts,
                                               int* __restrict__ incl,
                                               int* __restrict__ bsum){
  __shared__ int s[512];
  const int t = threadIdx.x;
  int i = blockIdx.x*512 + t;
  int v = (i < N_NODES) ? counts[i] : 0;
  s[t] = v;
  __syncthreads();
  for (int off = 1; off < 512; off <<= 1){
    int x = (t >= off) ? s[t - off] : 0;
    __syncthreads();
    s[t] += x;
    __syncthreads();
  }
  if (i < N_NODES) incl[i] = s[t];
  if (t == 511) bsum[blockIdx.x] = s[511];
}

// scan3 with in-block redundant scan of bsum
__global__ __launch_bounds__(512) void k_scan3(const int* __restrict__ counts,
                                               const int* __restrict__ incl,
                                               const int* __restrict__ bsum, int nb,
                                               int* __restrict__ offsets,
                                               int* __restrict__ cursor){
  __shared__ int sb[256];
  const int t = threadIdx.x;
  if (t < 256) sb[t] = (t < nb) ? bsum[t] : 0;
  __syncthreads();
  for (int off = 1; off < 256; off <<= 1){
    int x = 0;
    if (t < 256 && t >= off) x = sb[t - off];
    __syncthreads();
    if (t < 256) sb[t] += x;
    __syncthreads();
  }
  int i = blockIdx.x*512 + t;
  if (i >= N_NODES) return;
  int pre = (blockIdx.x == 0) ? 0 : sb[blockIdx.x - 1];
  int o = pre + incl[i];
  offsets[i + 1] = o;
  cursor[i]      = o - counts[i];
  if (i == 0) offsets[0] = 0;
}

// scatter: src index + bf16 edge features into CSR order ([E][16] bf16)
__global__ __launch_bounds__(256) void k_scatter(const int* __restrict__ ei,
                                                 int* __restrict__ cursor,
                                                 int* __restrict__ ssrc,
                                                 const float* __restrict__ ea,
                                                 u16* __restrict__ ea16){
  int e = blockIdx.x*256 + threadIdx.x;
  if (e >= N_EDGES) return;
  int dst = ei[N_EDGES + e];
  int pos = atomicAdd(&cursor[dst], 1);
  ssrc[pos] = ei[e];
  const float* s = ea + (size_t)e*F_EDGE_;
  unsigned p[8];
  #pragma unroll
  for (int k=0;k<8;k++) p[k] = packbf(s[2*k], s[2*k+1]);
  uint4* d4 = (uint4*)(ea16 + (size_t)pos*16);
  d4[0] = make_uint4(p[0],p[1],p[2],p[3]);
  d4[1] = make_uint4(p[4],p[5],p[6],p[7]);
}

// ---------------- Fused GAT v17: 2 nodes/wave, 128-thr blocks (8 nodes), BN-stats tail ----------------
#define GAT_GRID (N_NODES/8)   // 12500 blocks of 128 threads
__global__ __launch_bounds__(128) void k_gat_ep(const u16* __restrict__ xl,
                                                unsigned* xr_aggr,
                                                const u16* __restrict__ eproj,
                                                const float* __restrict__ att,
                                                const int* __restrict__ offsets,
                                                const int* __restrict__ ssrc,
                                                float* __restrict__ stats){
  __shared__ float red[4][264];           // [group][0..127 sum | 128..255 sq]
  const int t = threadIdx.x;              // 0..127
  const int wave = t >> 6, lane = t & 63;
  const int half = lane >> 5, l32 = lane & 31;
  const int c0 = l32*4;                   // 4 channels per lane
  const float4 av = *(const float4*)(att + c0);
  float ss0=0.f, ss1=0.f, ss2=0.f, ss3=0.f;
  float qq0=0.f, qq1=0.f, qq2=0.f, qq3=0.f;

  for (int k = 0; k < 2; k++){
    const int node = blockIdx.x*8 + wave*4 + k*2 + half;    // < N_NODES (grid exact)
    const uint2 xru = *(const uint2*)(xr_aggr + (size_t)node*64 + l32*2);
    const f32x2 xr0 = bp2v(xru.x), xr1 = bp2v(xru.y);
    f32x2 acc0 = {0.f,0.f}, acc1 = {0.f,0.f};
    float den = 0.f;
    const int beg = offsets[node], end = offsets[node+1];
    int it = (end - beg + 3) >> 2;
    int oit = __shfl_xor(it, 32);
    const int maxit = it > oit ? it : oit;
    int i = beg;
    for (int n = 0; n < maxit; n++, i += 4){
      const int mm = end - i;
      int ib = (mm > 0) ? i : beg;
      ib = ib < N_EDGES ? ib : N_EDGES - 1;
      const int i0 = ib;
      const int i1 = (mm > 1) ? i+1 : ib;
      const int i2 = (mm > 2) ? i+2 : ib;
      const int i3 = (mm > 3) ? i+3 : ib;
      const int s0 = ssrc[i0], s1 = ssrc[i1], s2 = ssrc[i2], s3 = ssrc[i3];
      const uint2 e0 = *(const uint2*)(eproj + (size_t)i0*128 + c0);
      const uint2 e1 = *(const uint2*)(eproj + (size_t)i1*128 + c0);
      const uint2 e2 = *(const uint2*)(eproj + (size_t)i2*128 + c0);
      const uint2 e3 = *(const uint2*)(eproj + (size_t)i3*128 + c0);
      const uint2 x0 = *(const uint2*)(xl + (size_t)s0*HID_ + c0);
      const uint2 x1 = *(const uint2*)(xl + (size_t)s1*HID_ + c0);
      const uint2 x2 = *(const uint2*)(xl + (size_t)s2*HID_ + c0);
      const uint2 x3 = *(const uint2*)(xl + (size_t)s3*HID_ + c0);
      const f32x2 vl00 = bp2v(x0.x), vl01 = bp2v(x0.y);
      const f32x2 vl10 = bp2v(x1.x), vl11 = bp2v(x1.y);
      const f32x2 vl20 = bp2v(x2.x), vl21 = bp2v(x2.y);
      const f32x2 vl30 = bp2v(x3.x), vl31 = bp2v(x3.y);
      f32x2 v00 = vl00 + xr0 + bp2v(e0.x), v01 = vl01 + xr1 + bp2v(e0.y);
      f32x2 v10 = vl10 + xr0 + bp2v(e1.x), v11 = vl11 + xr1 + bp2v(e1.y);
      f32x2 v20 = vl20 + xr0 + bp2v(e2.x), v21 = vl21 + xr1 + bp2v(e2.y);
      f32x2 v30 = vl30 + xr0 + bp2v(e3.x), v31 = vl31 + xr1 + bp2v(e3.y);
      f32x2 w;
      w = v00*0.2f; v00.x = fmaxf(v00.x,w.x); v00.y = fmaxf(v00.y,w.y);
      w = v01*0.2f; v01.x = fmaxf(v01.x,w.x); v01.y = fmaxf(v01.y,w.y);
      w = v10*0.2f; v10.x = fmaxf(v10.x,w.x); v10.y = fmaxf(v10.y,w.y);
      w = v11*0.2f; v11.x = fmaxf(v11.x,w.x); v11.y = fmaxf(v11.y,w.y);
      w = v20*0.2f; v20.x = fmaxf(v20.x,w.x); v20.y = fmaxf(v20.y,w.y);
      w = v21*0.2f; v21.x = fmaxf(v21.x,w.x); v21.y = fmaxf(v21.y,w.y);
      w = v30*0.2f; v30.x = fmaxf(v30.x,w.x); v30.y = fmaxf(v30.y,w.y);
      w = v31*0.2f; v31.x = fmaxf(v31.x,w.x); v31.y = fmaxf(v31.y,w.y);
      float sc0 = v00.x*av.x + v00.y*av.y + v01.x*av.z + v01.y*av.w;
      float sc1 = v10.x*av.x + v10.y*av.y + v11.x*av.z + v11.y*av.w;
      float sc2 = v20.x*av.x + v20.y*av.y + v21.x*av.z + v21.y*av.w;
      float sc3 = v30.x*av.x + v30.y*av.y + v31.x*av.z + v31.y*av.w;
      sc0 += __shfl_xor(sc0, 1); sc1 += __shfl_xor(sc1, 1); sc2 += __shfl_xor(sc2, 1); sc3 += __shfl_xor(sc3, 1);
      sc0 += __shfl_xor(sc0, 2); sc1 += __shfl_xor(sc1, 2); sc2 += __shfl_xor(sc2, 2); sc3 += __shfl_xor(sc3, 2);
      sc0 += __shfl_xor(sc0, 4); sc1 += __shfl_xor(sc1, 4); sc2 += __shfl_xor(sc2, 4); sc3 += __shfl_xor(sc3, 4);
      const float p0 = (mm > 0) ? __expf(sc0) : 0.f;
      const float p1 = (mm > 1) ? __expf(sc1) : 0.f;
      const float p2 = (mm > 2) ? __expf(sc2) : 0.f;
      const float p3 = (mm > 3) ? __expf(sc3) : 0.f;
      acc0 += p0*vl00 + p1*vl10 + p2*vl20 + p3*vl30;
      acc1 += p0*vl01 + p1*vl11 + p2*vl21 + p3*vl31;
      den  += p0 + p1 + p2 + p3;
    }
    const float inv = 1.0f / (den + 1e-16f);
    uint2 outv;
    outv.x = packbf(acc0.x*inv, acc0.y*inv);
    outv.y = packbf(acc1.x*inv, acc1.y*inv);
    *(uint2*)(xr_aggr + (size_t)node*64 + l32*2) = outv;
    const float2 o0 = bp2f(outv.x), o1 = bp2f(outv.y);
    ss0 += o0.x; ss1 += o0.y; ss2 += o1.x; ss3 += o1.y;
    qq0 += o0.x*o0.x; qq1 += o0.y*o0.y; qq2 += o1.x*o1.x; qq3 += o1.y*o1.y;
  }
  const int g = wave*2 + half;            // 0..3
  red[g][c0+0] = ss0; red[g][c0+1] = ss1; red[g][c0+2] = ss2; red[g][c0+3] = ss3;
  red[g][128+c0+0] = qq0; red[g][128+c0+1] = qq1; red[g][128+c0+2] = qq2; red[g][128+c0+3] = qq3;
  __syncthreads();
  {
    float a = 0.f, b2 = 0.f;
    #pragma unroll
    for (int gg = 0; gg < 4; gg++){ a += red[gg][t]; b2 += red[gg][128+t]; }
    const int base = (blockIdx.x & 7)*256;   // 8-way stripe
    atomicAdd(&stats[base + t],       a);
    atomicAdd(&stats[base + 128 + t], b2);
  }
}

// ---------------- BN apply + ELU (+ residual): pre-reduce 8 stripes + scale/shift in LDS ----------------
__global__ __launch_bounds__(256) void k_bn_apply(const unsigned* __restrict__ aggr_b,
                                                  const float* __restrict__ stats,
                                                  const float* __restrict__ gamma,
                                                  const float* __restrict__ beta,
                                                  u16* __restrict__ h, int residual){
  __shared__ float sc_sh[128], sh_sh[128];
  const int t = threadIdx.x;
  if (t < 128){
    float s = 0.f, q = 0.f;
    #pragma unroll
    for (int st = 0; st < 8; st++){
      s += stats[st*256 + t];
      q += stats[st*256 + 128 + t];
    }
    const float invn = 1.0f / (float)N_NODES;
    float mu = s * invn;
    float var = q * invn - mu*mu;
    float sc = rsqrtf(var + 1e-5f) * gamma[t];
    sc_sh[t] = sc;
    sh_sh[t] = beta[t] - mu * sc;
  }
  __syncthreads();
  size_t i = (size_t)blockIdx.x*256 + t;   // uint4-group index (8 channels)
  if (i >= (size_t)N_NODES*16) return;
  const int c = (int)((i & 15) * 8);
  uint4 v4 = ((const uint4*)aggr_b)[i];
  uint4* hp = (uint4*)h + i;
  uint4 hv4 = make_uint4(0,0,0,0);
  if (residual) hv4 = *hp;
  unsigned vin[4]  = {v4.x, v4.y, v4.z, v4.w};
  unsigned hin[4]  = {hv4.x, hv4.y, hv4.z, hv4.w};
  unsigned outw[4];
  #pragma unroll
  for (int j=0;j<4;j++){
    int cc = c + j*2;
    float2 v = bp2f(vin[j]);
    float val0 = v.x * sc_sh[cc]   + sh_sh[cc];
    float val1 = v.y * sc_sh[cc+1] + sh_sh[cc+1];
    val0 = val0 > 0.f ? val0 : expm1f(val0);
    val1 = val1 > 0.f ? val1 : expm1f(val1);
    if (residual){
      float2 hv = bp2f(hin[j]);
      val0 += hv.x; val1 += hv.y;
    }
    outw[j] = packbf(val0, val1);
  }
  *hp = make_uint4(outw[0], outw[1], outw[2], outw[3]);
}

// ---------------- Pool: segmented mean (1024 blocks) ----------------
__global__ __launch_bounds__(256) void k_pool_seg(const unsigned* __restrict__ h2,
                                                  const int* __restrict__ goff,
                                                  float* __restrict__ emb){
  __shared__ float redS[4][128];
  const int g = blockIdx.x, t = threadIdx.x;
  const int p = t & 63, rg = t >> 6;
  const int beg = goff[g], end = goff[g+1];
  float a0 = 0.f, a1 = 0.f;
  for (int r = beg + rg; r < end; r += 4){
    float2 v = bp2f(h2[(size_t)r*64 + p]);
    a0 += v.x; a1 += v.y;
  }
  redS[rg][p*2] = a0; redS[rg][p*2+1] = a1;
  __syncthreads();
  if (rg == 0){
    #pragma unroll
    for (int k=1;k<4;k++){ a0 += redS[k][p*2]; a1 += redS[k][p*2+1]; }
    float n = fmaxf((float)(end - beg), 1.f);
    emb[(size_t)g*HID_ + p*2]     = a0 / n;
    emb[(size_t)g*HID_ + p*2 + 1] = a1 / n;
  }
}

// ---------------- Per-task heads: 8 graphs per block, (128,5) grid ----------------
#define HG 8
__global__ __launch_bounds__(128) void k_heads(const float* __restrict__ emb,
                                               const float* __restrict__ mf,
                                               const int* __restrict__ fpi,
                                               const float* __restrict__ tw1,
                                               const float* __restrict__ tb1,
                                               const float* __restrict__ tw2,
                                               const float* __restrict__ tb2,
                                               float* __restrict__ out){
  const int task = blockIdx.y, g0 = blockIdx.x*HG;
  const int j = threadIdx.x;
  __shared__ float fused[HG][160];
  __shared__ float red[HG][128];
  for (int idx = j; idx < HG*160; idx += 128){
    int g = idx / 160, i = idx % 160;
    float v;
    if (i < 128) v = emb[(size_t)(g0+g)*HID_ + i];
    else         v = mf[(size_t)(g0+g)*2048 + fpi[task*32 + (i-128)]];
    fused[g][i] = v;
  }
  __syncthreads();
  const float* w1 = tw1 + (size_t)task*160*128;
  float acc[HG];
  float b1 = tb1[task*128 + j];
  #pragma unroll
  for (int g=0; g<HG; g++) acc[g] = b1;
  for (int i=0; i<160; i++){
    float wv = w1[(size_t)i*128 + j];
    #pragma unroll
    for (int g=0; g<HG; g++) acc[g] += fused[g][i] * wv;
  }
  float t2 = tw2[task*128 + j];
  #pragma unroll
  for (int g=0; g<HG; g++){
    float v = acc[g] > 0.f ? acc[g] : 0.f;
    red[g][j] = v * t2;
  }
  __syncthreads();
  int g = j >> 4, l16 = j & 15;
  float s = 0.f;
  #pragma unroll
  for (int k=0;k<8;k++) s += red[g][l16 + k*16];
  s += __shfl_xor(s, 1, 16);
  s += __shfl_xor(s, 2, 16);
  s += __shfl_xor(s, 4, 16);
  s += __shfl_xor(s, 8, 16);
  if (l16 == 0) out[(size_t)(g0+g)*N_TASK + task] = s + tb2[task];
}

extern "C" void kernel_launch(void* const* d_in, const int* in_sizes, int n_in,
                              void* d_out, int out_size, void* d_ws, size_t ws_size,
                              hipStream_t stream){
  const float* x    = (const float*)d_in[0];
  const int*   ei   = (const int*)  d_in[1];
  const float* ea   = (const float*)d_in[2];
  const int*   batch= (const int*)  d_in[3];
  const float* mf   = (const float*)d_in[4];
  const int*   fpi  = (const int*)  d_in[5];
  const float* Wl0  = (const float*)d_in[6];
  const float* bl0  = (const float*)d_in[7];
  const float* Wr0  = (const float*)d_in[8];
  const float* br0  = (const float*)d_in[9];
  const float* We0  = (const float*)d_in[10];
  const float* att0 = (const float*)d_in[11];
  const float* g0   = (const float*)d_in[13];
  const float* b0   = (const float*)d_in[14];
  const float* Wl   = (const float*)d_in[15];
  const float* bl   = (const float*)d_in[16];
  const float* Wr   = (const float*)d_in[17];
  const float* br   = (const float*)d_in[18];
  const float* We   = (const float*)d_in[19];
  const float* att  = (const float*)d_in[20];
  const float* gg   = (const float*)d_in[22];
  const float* bb   = (const float*)d_in[23];
  const float* tw1  = (const float*)d_in[24];
  const float* tb1  = (const float*)d_in[25];
  const float* tw2  = (const float*)d_in[26];
  const float* tb2  = (const float*)d_in[27];
  float* out = (float*)d_out;

  char* w = (char*)d_ws;
  auto alloc = [&](size_t bytes)->char*{ char* r = w; w += (bytes + 255) & ~(size_t)255; return r; };
  u16*   xl     = (u16*)  alloc((size_t)N_NODES*HID_*2);
  unsigned* xr_aggr = (unsigned*)alloc((size_t)N_NODES*64*4);
  u16*   h      = (u16*)  alloc((size_t)N_NODES*HID_*2);
  u16*   ea16   = (u16*)  alloc((size_t)N_EDGES*16*2);
  int*   counts = (int*)  alloc((size_t)N_NODES*4);
  float* stats4 = (float*)alloc(4*2048*4);            // 4 layers x 8 stripes x 256 floats
  int*   offsets= (int*)  alloc((size_t)(N_NODES+1)*4);
  int*   cursor = (int*)  alloc((size_t)N_NODES*4);
  int*   incl   = (int*)  alloc((size_t)N_NODES*4);
  int*   bsum   = (int*)  alloc(256*4);
  int*   ssrc   = (int*)  alloc((size_t)N_EDGES*4);
  int*   goff   = (int*)  alloc((size_t)(N_GRAPH+1)*4);
  float* emb    = (float*)alloc((size_t)N_GRAPH*HID_*4);
  u16*   Wzl0   = (u16*)  alloc((size_t)F_NODE_*128*2);
  u16*   Wzr0   = (u16*)  alloc((size_t)F_NODE_*128*2);
  u16*   Wzl123 = (u16*)  alloc((size_t)3*HID_*128*2);
  u16*   Wzr123 = (u16*)  alloc((size_t)3*HID_*128*2);
  u16*   Wez4   = (u16*)  alloc((size_t)4*32*128*2);
  u16*   eproj  = (u16*)  alloc((size_t)N_EDGES*HID_*2);
  u16*   xbf    = (u16*)  alloc((size_t)N_NODES*F_NODE_*2);  // separate from eproj (no race)

  const size_t zlen = (size_t)((char*)(stats4 + 4*2048) - (char*)counts);
  const int nscan = (N_NODES + 511)/512;

  WZ12 p;
  p.src[0] = Wl0; p.dst[0] = Wzl0; p.Ks[0] = F_NODE_; p.Kd[0] = F_NODE_;
  p.src[1] = Wr0; p.dst[1] = Wzr0; p.Ks[1] = F_NODE_; p.Kd[1] = F_NODE_;
  for (int i=0;i<3;i++){
    p.src[2+i] = Wl + (size_t)i*HID_*HID_; p.dst[2+i] = Wzl123 + (size_t)i*HID_*128; p.Ks[2+i] = HID_; p.Kd[2+i] = HID_;
    p.src[5+i] = Wr + (size_t)i*HID_*HID_; p.dst[5+i] = Wzr123 + (size_t)i*HID_*128; p.Ks[5+i] = HID_; p.Kd[5+i] = HID_;
  }
  p.src[8] = We0; p.dst[8] = Wez4; p.Ks[8] = F_EDGE_; p.Kd[8] = 32;
  for (int i=0;i<3;i++){
    p.src[9+i] = We + (size_t)i*F_EDGE_*HID_; p.dst[9+i] = Wez4 + (size_t)(i+1)*32*128; p.Ks[9+i] = F_EDGE_; p.Kd[9+i] = 32;
  }

  hipMemsetAsync(counts, 0, zlen, stream);
  hipLaunchKernelGGL(k_cast_hist, dim3(CAST_BLKS + EG256 + GOFF_BLKS + WSWZ_BLKS), dim3(256), 0, stream,
                     x, xbf, ei, counts, batch, goff, p);
  hipLaunchKernelGGL(k_scan1,  dim3(nscan), dim3(512), 0, stream, counts, incl, bsum);
  hipLaunchKernelGGL(k_scan3,  dim3(nscan), dim3(512), 0, stream, counts, incl, bsum, nscan, offsets, cursor);
  hipLaunchKernelGGL(k_scatter,dim3(EG256), dim3(256), 0, stream, ei, cursor, ssrc, ea, ea16);

  for (int layer = 0; layer < 4; layer++){
    const float *bl_, *br_, *att_, *g_, *b_;
    const u16 *Wzl_, *Wzr_, *Ain;
    int K;
    if (layer == 0){
      bl_=bl0; br_=br0; att_=att0; g_=g0; b_=b0;
      Wzl_ = Wzl0; Wzr_ = Wzr0; Ain = xbf; K = F_NODE_;
    } else {
      int i = layer - 1;
      bl_ = bl + (size_t)i*HID_;  br_ = br + (size_t)i*HID_;
      att_= att + (size_t)i*HID_;
      g_  = gg + (size_t)i*HID_;  b_  = bb + (size_t)i*HID_;
      Wzl_ = Wzl123 + (size_t)i*HID_*128;
      Wzr_ = Wzr123 + (size_t)i*HID_*128;
      Ain = h; K = HID_;
    }
    float* stats = stats4 + layer*2048;
    hipLaunchKernelGGL(k_gemm_eproj, dim3(2*GEMM_GRID + EPROJ_GRID), dim3(256), 0, stream,
                       Ain, Wzl_, Wzr_, bl_, br_, xl, (u16*)xr_aggr, N_NODES, K,
                       ea16, Wez4 + (size_t)layer*32*128, eproj);
    hipLaunchKernelGGL(k_gat_ep, dim3(GAT_GRID), dim3(128), 0, stream,
                       xl, xr_aggr, eproj, att_, offsets, ssrc, stats);
    hipLaunchKernelGGL(k_bn_apply, dim3((N_NODES*16 + 255)/256), dim3(256), 0, stream,
                       xr_aggr, stats, g_, b_, h, layer > 0 ? 1 : 0);
  }
  hipLaunchKernelGGL(k_pool_seg, dim3(N_GRAPH), dim3(256), 0, stream, (const unsigned*)h, goff, emb);
  hipLaunchKernelGGL(k_heads, dim3(N_GRAPH/HG, N_TASK), dim3(128), 0, stream, emb, mf, fpi, tw1, tb1, tw2, tb2, out);
}

// Round 11
// 640.821 us; speedup vs baseline: 2.4848x; 1.0416x over previous
//
#include <hip/hip_runtime.h>
#include <hip/hip_bf16.h>

#define N_NODES 100000
#define N_EDGES 400000
#define F_NODE_ 64
#define F_EDGE_ 16
#define HID_ 128
#define N_GRAPH 1024
#define N_TASK 5
#define NSTRIPE 32

typedef unsigned short u16;
typedef __attribute__((ext_vector_type(8))) short frag8;   // 8 bf16 = 4 VGPRs
typedef __attribute__((ext_vector_type(4))) float f32x4;   // MFMA C/D
typedef __attribute__((ext_vector_type(2))) float f32x2;

__device__ __forceinline__ float bu2f(u16 v){ return __uint_as_float(((unsigned)v) << 16); }
__device__ __forceinline__ float2 bp2f(unsigned u){
  return make_float2(__uint_as_float(u << 16), __uint_as_float(u & 0xFFFF0000u));
}
__device__ __forceinline__ f32x2 bp2v(unsigned u){
  f32x2 r; r.x = __uint_as_float(u << 16); r.y = __uint_as_float(u & 0xFFFF0000u); return r;
}
__device__ __forceinline__ u16 f2bu(float f){
  __hip_bfloat16 h = __float2bfloat16(f);
  return *(u16*)&h;
}
__device__ __forceinline__ unsigned packbf(float a, float b){
  return (unsigned)f2bu(a) | ((unsigned)f2bu(b) << 16);
}
// packed 2-lane max (emits v_pk_max_f32 where available)
__device__ __forceinline__ f32x2 pmax2(f32x2 a, f32x2 b){
#if defined(__has_builtin)
#if __has_builtin(__builtin_elementwise_max)
  return __builtin_elementwise_max(a, b);
#else
  f32x2 r; r.x = fmaxf(a.x,b.x); r.y = fmaxf(a.y,b.y); return r;
#endif
#else
  f32x2 r; r.x = fmaxf(a.x,b.x); r.y = fmaxf(a.y,b.y); return r;
#endif
}

struct WZ12 { const float* src[12]; u16* dst[12]; int Ks[12]; int Kd[12]; };

// ---------------- cast f32->bf16 + edge histogram + graph offsets + W pre-swizzle (flat grid) ----------------
#define CAST_BLKS ((N_NODES*F_NODE_ + 255)/256)
#define EG256 ((N_EDGES + 255)/256)
#define GOFF_BLKS ((N_GRAPH + 1 + 255)/256)
#define WSWZ_BLKS (12*64)
__global__ __launch_bounds__(256) void k_cast_hist(const float* __restrict__ s, u16* __restrict__ d,
                                                   const int* __restrict__ ei, int* __restrict__ counts,
                                                   const int* __restrict__ batch, int* __restrict__ goff,
                                                   WZ12 p){
  int b = blockIdx.x;
  if (b < CAST_BLKS){
    int i = b*256 + threadIdx.x;
    if (i < N_NODES*F_NODE_) d[i] = f2bu(s[i]);
  } else if (b < CAST_BLKS + EG256){
    int e = (b - CAST_BLKS)*256 + threadIdx.x;
    if (e < N_EDGES) atomicAdd(&counts[ei[N_EDGES + e]], 1);
  } else if (b < CAST_BLKS + EG256 + GOFF_BLKS){
    int g = (b - CAST_BLKS - EG256)*256 + threadIdx.x;
    if (g <= N_GRAPH){
      int lo = 0, hi = N_NODES;
      while (lo < hi){
        int mid = (lo + hi) >> 1;
        if (batch[mid] < g) lo = mid + 1; else hi = mid;
      }
      goff[g] = lo;
    }
  } else {
    int bb = b - CAST_BLKS - EG256 - GOFF_BLKS;   // 0..767
    const int sW = bb >> 6;
    const int Kd = p.Kd[sW], Ks = p.Ks[sW];
    int i = (bb & 63)*256 + threadIdx.x;
    if (i >= Kd*128) return;
    int k = i >> 7, n = i & 127;
    float v = (k < Ks) ? p.src[sW][k*128 + n] : 0.f;
    int kk = k & 31, c = k >> 5;
    int quad = kk >> 3, j = kk & 7;
    int nt = n >> 4;
    int lane = quad*16 + (n & 15);
    p.dst[sW][(((c*8 + nt)*64) + lane)*8 + j] = f2bu(v);
  }
}

// ---------------- fused: paired MFMA GEMMs + eproj MFMA GEMM (flat grid) ----------------
// C-write: stage tile in LDS (quad-XOR swizzle, conflict-free) then coalesced uint4 stores.
#define GEMM_GRID ((N_NODES + 127)/128)   // 782
#define EPROJ_GRID ((N_EDGES + 127)/128)  // 3125
__global__ __launch_bounds__(256) void k_gemm_eproj(const u16* __restrict__ A,
                                                    const u16* __restrict__ Wzl,
                                                    const u16* __restrict__ Wzr,
                                                    const float* __restrict__ bl,
                                                    const float* __restrict__ br,
                                                    u16* __restrict__ Cl,
                                                    u16* Cr,
                                                    int M, int K,
                                                    const u16* __restrict__ ea16,
                                                    const u16* __restrict__ Wez,
                                                    u16* __restrict__ eproj){
  __shared__ u16 WS[128*128];
  const int t = threadIdx.x;
  const int b = blockIdx.x;
  if (b < 2*GEMM_GRID){
    const int which = (b >= GEMM_GRID);
    const int bx = which ? b - GEMM_GRID : b;
    const u16*   Wz   = which ? Wzr : Wzl;
    const float* bias = which ? br  : bl;
    u16*         C    = which ? Cr  : Cl;
    {
      const uint4* src = (const uint4*)Wz;
      uint4* dst = (uint4*)WS;
      const int n = (K*128) >> 3;
      for (int i = t; i < n; i += 256) dst[i] = src[i];
    }
    __syncthreads();
    const int w = t >> 6, l = t & 63;
    const int m = l & 15, quad = l >> 4;
    const int rowA0 = bx*128 + w*32 + m;
    const int rowA1 = rowA0 + 16;
    f32x4 acc[2][8];
    #pragma unroll
    for (int i=0;i<2;i++)
      #pragma unroll
      for (int j=0;j<8;j++) acc[i][j] = (f32x4){0.f,0.f,0.f,0.f};
    const int KC = K >> 5;
    for (int c = 0; c < KC; c++){
      frag8 a0 = {}, a1 = {};
      if (rowA0 < M) a0 = *(const frag8*)(A + (size_t)rowA0*K + c*32 + quad*8);
      if (rowA1 < M) a1 = *(const frag8*)(A + (size_t)rowA1*K + c*32 + quad*8);
      #pragma unroll
      for (int nt = 0; nt < 8; nt++){
        frag8 bfr = *(const frag8*)&WS[(((c*8 + nt)*64) + l)*8];
        acc[0][nt] = __builtin_amdgcn_mfma_f32_16x16x32_bf16(a0, bfr, acc[0][nt], 0,0,0);
        acc[1][nt] = __builtin_amdgcn_mfma_f32_16x16x32_bf16(a1, bfr, acc[1][nt], 0,0,0);
      }
    }
    float bcv[8];
    #pragma unroll
    for (int nt=0; nt<8; nt++) bcv[nt] = bias[nt*16 + m];
    __syncthreads();          // all WS reads (MFMA) done
    const int sXor = quad << 4;   // quads -> disjoint bank groups
    #pragma unroll
    for (int rt = 0; rt < 2; rt++){
      #pragma unroll
      for (int r = 0; r < 4; r++){
        const int row = w*32 + rt*16 + quad*4 + r;
        #pragma unroll
        for (int nt = 0; nt < 8; nt++){
          const int col = nt*16 + m;
          WS[row*128 + (col ^ sXor)] = f2bu(acc[rt][nt][r] + bcv[nt]);
        }
      }
    }
    __syncthreads();
    #pragma unroll
    for (int i = 0; i < 8; i++){
      const int idx = i*256 + t;
      const int row = idx >> 4, k16 = idx & 15;
      const int grp = (k16*8) ^ (((row>>2)&3)<<4);
      const int grow = bx*128 + row;
      if (grow < M)
        *(uint4*)(C + (size_t)grow*128 + k16*8) = *(const uint4*)&WS[row*128 + grp];
    }
  } else {
    // eproj GEMM: 128 edges/block, K=32 via fragment zero-padding
    const int bx = b - 2*GEMM_GRID;
    {
      const uint4* s4 = (const uint4*)Wez;
      uint4* d4 = (uint4*)WS;
      for (int i = t; i < 512; i += 256) d4[i] = s4[i];
    }
    __syncthreads();
    const int w = t >> 6, l = t & 63, m = l & 15, quad = l >> 4;
    const int row0 = bx*128 + w*32 + m;
    const int row1 = row0 + 16;
    f32x4 acc[2][8];
    #pragma unroll
    for (int i=0;i<2;i++)
      #pragma unroll
      for (int j=0;j<8;j++) acc[i][j] = (f32x4){0.f,0.f,0.f,0.f};
    frag8 a0 = {}, a1 = {};
    if (quad < 2){
      a0 = *(const frag8*)(ea16 + (size_t)row0*16 + quad*8);   // grid exact: rows < N_EDGES
      a1 = *(const frag8*)(ea16 + (size_t)row1*16 + quad*8);
    }
    #pragma unroll
    for (int nt = 0; nt < 8; nt++){
      frag8 bfr = *(const frag8*)&WS[(nt*64 + l)*8];
      acc[0][nt] = __builtin_amdgcn_mfma_f32_16x16x32_bf16(a0, bfr, acc[0][nt], 0,0,0);
      acc[1][nt] = __builtin_amdgcn_mfma_f32_16x16x32_bf16(a1, bfr, acc[1][nt], 0,0,0);
    }
    __syncthreads();
    const int sXor = quad << 4;
    #pragma unroll
    for (int rt = 0; rt < 2; rt++){
      #pragma unroll
      for (int r = 0; r < 4; r++){
        const int row = w*32 + rt*16 + quad*4 + r;
        #pragma unroll
        for (int nt = 0; nt < 8; nt++){
          const int col = nt*16 + m;
          WS[row*128 + (col ^ sXor)] = f2bu(acc[rt][nt][r]);
        }
      }
    }
    __syncthreads();
    #pragma unroll
    for (int i = 0; i < 8; i++){
      const int idx = i*256 + t;
      const int row = idx >> 4, k16 = idx & 15;
      const int grp = (k16*8) ^ (((row>>2)&3)<<4);
      *(uint4*)(eproj + ((size_t)(bx*128 + row))*128 + k16*8) = *(const uint4*)&WS[row*128 + grp];
    }
  }
}

__global__ __launch_bounds__(512) void k_scan1(const int* __restrict__ counts,
                                               int* __restrict__ incl,
                                               int* __restrict__ bsum){
  __shared__ int s[512];
  const int t = threadIdx.x;
  int i = blockIdx.x*512 + t;
  int v = (i < N_NODES) ? counts[i] : 0;
  s[t] = v;
  __syncthreads();
  for (int off = 1; off < 512; off <<= 1){
    int x = (t >= off) ? s[t - off] : 0;
    __syncthreads();
    s[t] += x;
    __syncthreads();
  }
  if (i < N_NODES) incl[i] = s[t];
  if (t == 511) bsum[blockIdx.x] = s[511];
}

// scan3 with in-block redundant scan of bsum
__global__ __launch_bounds__(512) void k_scan3(const int* __restrict__ counts,
                                               const int* __restrict__ incl,
                                               const int* __restrict__ bsum, int nb,
                                               int* __restrict__ offsets,
                                               int* __restrict__ cursor){
  __shared__ int sb[256];
  const int t = threadIdx.x;
  if (t < 256) sb[t] = (t < nb) ? bsum[t] : 0;
  __syncthreads();
  for (int off = 1; off < 256; off <<= 1){
    int x = 0;
    if (t < 256 && t >= off) x = sb[t - off];
    __syncthreads();
    if (t < 256) sb[t] += x;
    __syncthreads();
  }
  int i = blockIdx.x*512 + t;
  if (i >= N_NODES) return;
  int pre = (blockIdx.x == 0) ? 0 : sb[blockIdx.x - 1];
  int o = pre + incl[i];
  offsets[i + 1] = o;
  cursor[i]      = o - counts[i];
  if (i == 0) offsets[0] = 0;
}

// scatter: src index + bf16 edge features into CSR order ([E][16] bf16)
__global__ __launch_bounds__(256) void k_scatter(const int* __restrict__ ei,
                                                 int* __restrict__ cursor,
                                                 int* __restrict__ ssrc,
                                                 const float* __restrict__ ea,
                                                 u16* __restrict__ ea16){
  int e = blockIdx.x*256 + threadIdx.x;
  if (e >= N_EDGES) return;
  int dst = ei[N_EDGES + e];
  int pos = atomicAdd(&cursor[dst], 1);
  ssrc[pos] = ei[e];
  const float* s = ea + (size_t)e*F_EDGE_;
  unsigned p[8];
  #pragma unroll
  for (int k=0;k<8;k++) p[k] = packbf(s[2*k], s[2*k+1]);
  uint4* d4 = (uint4*)(ea16 + (size_t)pos*16);
  d4[0] = make_uint4(p[0],p[1],p[2],p[3]);
  d4[1] = make_uint4(p[4],p[5],p[6],p[7]);
}

// ---------------- Fused GAT v18: 2 nodes/wave, 128-thr blocks, BN-stats tail (32-way stripe) ----------------
#define GAT_GRID (N_NODES/8)   // 12500 blocks of 128 threads
__global__ __launch_bounds__(128) void k_gat_ep(const u16* __restrict__ xl,
                                                unsigned* xr_aggr,
                                                const u16* __restrict__ eproj,
                                                const float* __restrict__ att,
                                                const int* __restrict__ offsets,
                                                const int* __restrict__ ssrc,
                                                float* __restrict__ stats){
  __shared__ float red[4][264];           // [group][0..127 sum | 128..255 sq]
  const int t = threadIdx.x;              // 0..127
  const int wave = t >> 6, lane = t & 63;
  const int half = lane >> 5, l32 = lane & 31;
  const int c0 = l32*4;                   // 4 channels per lane
  const float4 av = *(const float4*)(att + c0);
  const f32x2 avlo = {av.x, av.y}, avhi = {av.z, av.w};
  float ss0=0.f, ss1=0.f, ss2=0.f, ss3=0.f;
  float qq0=0.f, qq1=0.f, qq2=0.f, qq3=0.f;

  for (int k = 0; k < 2; k++){
    const int node = blockIdx.x*8 + wave*4 + k*2 + half;    // < N_NODES (grid exact)
    const uint2 xru = *(const uint2*)(xr_aggr + (size_t)node*64 + l32*2);
    const f32x2 xr0 = bp2v(xru.x), xr1 = bp2v(xru.y);
    f32x2 acc0 = {0.f,0.f}, acc1 = {0.f,0.f};
    float den = 0.f;
    const int beg = offsets[node], end = offsets[node+1];
    int it = (end - beg + 3) >> 2;
    int oit = __shfl_xor(it, 32);
    const int maxit = it > oit ? it : oit;
    int i = beg;
    for (int n = 0; n < maxit; n++, i += 4){
      const int mm = end - i;
      int ib = (mm > 0) ? i : beg;
      ib = ib < N_EDGES ? ib : N_EDGES - 1;
      const int i0 = ib;
      const int i1 = (mm > 1) ? i+1 : ib;
      const int i2 = (mm > 2) ? i+2 : ib;
      const int i3 = (mm > 3) ? i+3 : ib;
      const int s0 = ssrc[i0], s1 = ssrc[i1], s2 = ssrc[i2], s3 = ssrc[i3];
      const uint2 e0 = *(const uint2*)(eproj + (size_t)i0*128 + c0);
      const uint2 e1 = *(const uint2*)(eproj + (size_t)i1*128 + c0);
      const uint2 e2 = *(const uint2*)(eproj + (size_t)i2*128 + c0);
      const uint2 e3 = *(const uint2*)(eproj + (size_t)i3*128 + c0);
      const uint2 x0 = *(const uint2*)(xl + (size_t)s0*HID_ + c0);
      const uint2 x1 = *(const uint2*)(xl + (size_t)s1*HID_ + c0);
      const uint2 x2 = *(const uint2*)(xl + (size_t)s2*HID_ + c0);
      const uint2 x3 = *(const uint2*)(xl + (size_t)s3*HID_ + c0);
      const f32x2 vl00 = bp2v(x0.x), vl01 = bp2v(x0.y);
      const f32x2 vl10 = bp2v(x1.x), vl11 = bp2v(x1.y);
      const f32x2 vl20 = bp2v(x2.x), vl21 = bp2v(x2.y);
      const f32x2 vl30 = bp2v(x3.x), vl31 = bp2v(x3.y);
      f32x2 v00 = vl00 + xr0 + bp2v(e0.x), v01 = vl01 + xr1 + bp2v(e0.y);
      f32x2 v10 = vl10 + xr0 + bp2v(e1.x), v11 = vl11 + xr1 + bp2v(e1.y);
      f32x2 v20 = vl20 + xr0 + bp2v(e2.x), v21 = vl21 + xr1 + bp2v(e2.y);
      f32x2 v30 = vl30 + xr0 + bp2v(e3.x), v31 = vl31 + xr1 + bp2v(e3.y);
      v00 = pmax2(v00, v00*0.2f); v01 = pmax2(v01, v01*0.2f);
      v10 = pmax2(v10, v10*0.2f); v11 = pmax2(v11, v11*0.2f);
      v20 = pmax2(v20, v20*0.2f); v21 = pmax2(v21, v21*0.2f);
      v30 = pmax2(v30, v30*0.2f); v31 = pmax2(v31, v31*0.2f);
      f32x2 ps0 = v00*avlo + v01*avhi;
      f32x2 ps1 = v10*avlo + v11*avhi;
      f32x2 ps2 = v20*avlo + v21*avhi;
      f32x2 ps3 = v30*avlo + v31*avhi;
      float sc0 = ps0.x + ps0.y;
      float sc1 = ps1.x + ps1.y;
      float sc2 = ps2.x + ps2.y;
      float sc3 = ps3.x + ps3.y;
      sc0 += __shfl_xor(sc0, 1); sc1 += __shfl_xor(sc1, 1); sc2 += __shfl_xor(sc2, 1); sc3 += __shfl_xor(sc3, 1);
      sc0 += __shfl_xor(sc0, 2); sc1 += __shfl_xor(sc1, 2); sc2 += __shfl_xor(sc2, 2); sc3 += __shfl_xor(sc3, 2);
      sc0 += __shfl_xor(sc0, 4); sc1 += __shfl_xor(sc1, 4); sc2 += __shfl_xor(sc2, 4); sc3 += __shfl_xor(sc3, 4);
      const float p0 = (mm > 0) ? __expf(sc0) : 0.f;
      const float p1 = (mm > 1) ? __expf(sc1) : 0.f;
      const float p2 = (mm > 2) ? __expf(sc2) : 0.f;
      const float p3 = (mm > 3) ? __expf(sc3) : 0.f;
      acc0 += p0*vl00 + p1*vl10 + p2*vl20 + p3*vl30;
      acc1 += p0*vl01 + p1*vl11 + p2*vl21 + p3*vl31;
      den  += p0 + p1 + p2 + p3;
    }
    const float inv = 1.0f / (den + 1e-16f);
    uint2 outv;
    outv.x = packbf(acc0.x*inv, acc0.y*inv);
    outv.y = packbf(acc1.x*inv, acc1.y*inv);
    *(uint2*)(xr_aggr + (size_t)node*64 + l32*2) = outv;
    const float2 o0 = bp2f(outv.x), o1 = bp2f(outv.y);
    ss0 += o0.x; ss1 += o0.y; ss2 += o1.x; ss3 += o1.y;
    qq0 += o0.x*o0.x; qq1 += o0.y*o0.y; qq2 += o1.x*o1.x; qq3 += o1.y*o1.y;
  }
  const int g = wave*2 + half;            // 0..3
  red[g][c0+0] = ss0; red[g][c0+1] = ss1; red[g][c0+2] = ss2; red[g][c0+3] = ss3;
  red[g][128+c0+0] = qq0; red[g][128+c0+1] = qq1; red[g][128+c0+2] = qq2; red[g][128+c0+3] = qq3;
  __syncthreads();
  {
    float a = 0.f, b2 = 0.f;
    #pragma unroll
    for (int gg = 0; gg < 4; gg++){ a += red[gg][t]; b2 += red[gg][128+t]; }
    const int base = (blockIdx.x & (NSTRIPE-1))*256;   // 32-way stripe
    atomicAdd(&stats[base + t],       a);
    atomicAdd(&stats[base + 128 + t], b2);
  }
}

// ---------------- BN apply + ELU (+ residual): pre-reduce 32 stripes + scale/shift in LDS ----------------
__global__ __launch_bounds__(256) void k_bn_apply(const unsigned* __restrict__ aggr_b,
                                                  const float* __restrict__ stats,
                                                  const float* __restrict__ gamma,
                                                  const float* __restrict__ beta,
                                                  u16* __restrict__ h, int residual){
  __shared__ float sc_sh[128], sh_sh[128];
  const int t = threadIdx.x;
  if (t < 128){
    float s = 0.f, q = 0.f;
    #pragma unroll
    for (int st = 0; st < NSTRIPE; st++){
      s += stats[st*256 + t];
      q += stats[st*256 + 128 + t];
    }
    const float invn = 1.0f / (float)N_NODES;
    float mu = s * invn;
    float var = q * invn - mu*mu;
    float sc = rsqrtf(var + 1e-5f) * gamma[t];
    sc_sh[t] = sc;
    sh_sh[t] = beta[t] - mu * sc;
  }
  __syncthreads();
  size_t i = (size_t)blockIdx.x*256 + t;   // uint4-group index (8 channels)
  if (i >= (size_t)N_NODES*16) return;
  const int c = (int)((i & 15) * 8);
  uint4 v4 = ((const uint4*)aggr_b)[i];
  uint4* hp = (uint4*)h + i;
  uint4 hv4 = make_uint4(0,0,0,0);
  if (residual) hv4 = *hp;
  unsigned vin[4]  = {v4.x, v4.y, v4.z, v4.w};
  unsigned hin[4]  = {hv4.x, hv4.y, hv4.z, hv4.w};
  unsigned outw[4];
  #pragma unroll
  for (int j=0;j<4;j++){
    int cc = c + j*2;
    float2 v = bp2f(vin[j]);
    float val0 = v.x * sc_sh[cc]   + sh_sh[cc];
    float val1 = v.y * sc_sh[cc+1] + sh_sh[cc+1];
    val0 = val0 > 0.f ? val0 : expm1f(val0);
    val1 = val1 > 0.f ? val1 : expm1f(val1);
    if (residual){
      float2 hv = bp2f(hin[j]);
      val0 += hv.x; val1 += hv.y;
    }
    outw[j] = packbf(val0, val1);
  }
  *hp = make_uint4(outw[0], outw[1], outw[2], outw[3]);
}

// ---------------- Pool: segmented mean (1024 blocks) ----------------
__global__ __launch_bounds__(256) void k_pool_seg(const unsigned* __restrict__ h2,
                                                  const int* __restrict__ goff,
                                                  float* __restrict__ emb){
  __shared__ float redS[4][128];
  const int g = blockIdx.x, t = threadIdx.x;
  const int p = t & 63, rg = t >> 6;
  const int beg = goff[g], end = goff[g+1];
  float a0 = 0.f, a1 = 0.f;
  for (int r = beg + rg; r < end; r += 4){
    float2 v = bp2f(h2[(size_t)r*64 + p]);
    a0 += v.x; a1 += v.y;
  }
  redS[rg][p*2] = a0; redS[rg][p*2+1] = a1;
  __syncthreads();
  if (rg == 0){
    #pragma unroll
    for (int k=1;k<4;k++){ a0 += redS[k][p*2]; a1 += redS[k][p*2+1]; }
    float n = fmaxf((float)(end - beg), 1.f);
    emb[(size_t)g*HID_ + p*2]     = a0 / n;
    emb[(size_t)g*HID_ + p*2 + 1] = a1 / n;
  }
}

// ---------------- Per-task heads: 8 graphs per block, (128,5) grid ----------------
#define HG 8
__global__ __launch_bounds__(128) void k_heads(const float* __restrict__ emb,
                                               const float* __restrict__ mf,
                                               const int* __restrict__ fpi,
                                               const float* __restrict__ tw1,
                                               const float* __restrict__ tb1,
                                               const float* __restrict__ tw2,
                                               const float* __restrict__ tb2,
                                               float* __restrict__ out){
  const int task = blockIdx.y, g0 = blockIdx.x*HG;
  const int j = threadIdx.x;
  __shared__ float fused[HG][160];
  __shared__ float red[HG][128];
  for (int idx = j; idx < HG*160; idx += 128){
    int g = idx / 160, i = idx % 160;
    float v;
    if (i < 128) v = emb[(size_t)(g0+g)*HID_ + i];
    else         v = mf[(size_t)(g0+g)*2048 + fpi[task*32 + (i-128)]];
    fused[g][i] = v;
  }
  __syncthreads();
  const float* w1 = tw1 + (size_t)task*160*128;
  float acc[HG];
  float b1 = tb1[task*128 + j];
  #pragma unroll
  for (int g=0; g<HG; g++) acc[g] = b1;
  for (int i=0; i<160; i++){
    float wv = w1[(size_t)i*128 + j];
    #pragma unroll
    for (int g=0; g<HG; g++) acc[g] += fused[g][i] * wv;
  }
  float t2 = tw2[task*128 + j];
  #pragma unroll
  for (int g=0; g<HG; g++){
    float v = acc[g] > 0.f ? acc[g] : 0.f;
    red[g][j] = v * t2;
  }
  __syncthreads();
  int g = j >> 4, l16 = j & 15;
  float s = 0.f;
  #pragma unroll
  for (int k=0;k<8;k++) s += red[g][l16 + k*16];
  s += __shfl_xor(s, 1, 16);
  s += __shfl_xor(s, 2, 16);
  s += __shfl_xor(s, 4, 16);
  s += __shfl_xor(s, 8, 16);
  if (l16 == 0) out[(size_t)(g0+g)*N_TASK + task] = s + tb2[task];
}

extern "C" void kernel_launch(void* const* d_in, const int* in_sizes, int n_in,
                              void* d_out, int out_size, void* d_ws, size_t ws_size,
                              hipStream_t stream){
  const float* x    = (const float*)d_in[0];
  const int*   ei   = (const int*)  d_in[1];
  const float* ea   = (const float*)d_in[2];
  const int*   batch= (const int*)  d_in[3];
  const float* mf   = (const float*)d_in[4];
  const int*   fpi  = (const int*)  d_in[5];
  const float* Wl0  = (const float*)d_in[6];
  const float* bl0  = (const float*)d_in[7];
  const float* Wr0  = (const float*)d_in[8];
  const float* br0  = (const float*)d_in[9];
  const float* We0  = (const float*)d_in[10];
  const float* att0 = (const float*)d_in[11];
  const float* g0   = (const float*)d_in[13];
  const float* b0   = (const float*)d_in[14];
  const float* Wl   = (const float*)d_in[15];
  const float* bl   = (const float*)d_in[16];
  const float* Wr   = (const float*)d_in[17];
  const float* br   = (const float*)d_in[18];
  const float* We   = (const float*)d_in[19];
  const float* att  = (const float*)d_in[20];
  const float* gg   = (const float*)d_in[22];
  const float* bb   = (const float*)d_in[23];
  const float* tw1  = (const float*)d_in[24];
  const float* tb1  = (const float*)d_in[25];
  const float* tw2  = (const float*)d_in[26];
  const float* tb2  = (const float*)d_in[27];
  float* out = (float*)d_out;

  char* w = (char*)d_ws;
  auto alloc = [&](size_t bytes)->char*{ char* r = w; w += (bytes + 255) & ~(size_t)255; return r; };
  u16*   xl     = (u16*)  alloc((size_t)N_NODES*HID_*2);
  unsigned* xr_aggr = (unsigned*)alloc((size_t)N_NODES*64*4);
  u16*   h      = (u16*)  alloc((size_t)N_NODES*HID_*2);
  u16*   ea16   = (u16*)  alloc((size_t)N_EDGES*16*2);
  int*   counts = (int*)  alloc((size_t)N_NODES*4);
  float* stats4 = (float*)alloc(4*NSTRIPE*256*4);      // 4 layers x 32 stripes x 256 floats
  int*   offsets= (int*)  alloc((size_t)(N_NODES+1)*4);
  int*   cursor = (int*)  alloc((size_t)N_NODES*4);
  int*   incl   = (int*)  alloc((size_t)N_NODES*4);
  int*   bsum   = (int*)  alloc(256*4);
  int*   ssrc   = (int*)  alloc((size_t)N_EDGES*4);
  int*   goff   = (int*)  alloc((size_t)(N_GRAPH+1)*4);
  float* emb    = (float*)alloc((size_t)N_GRAPH*HID_*4);
  u16*   Wzl0   = (u16*)  alloc((size_t)F_NODE_*128*2);
  u16*   Wzr0   = (u16*)  alloc((size_t)F_NODE_*128*2);
  u16*   Wzl123 = (u16*)  alloc((size_t)3*HID_*128*2);
  u16*   Wzr123 = (u16*)  alloc((size_t)3*HID_*128*2);
  u16*   Wez4   = (u16*)  alloc((size_t)4*32*128*2);
  u16*   eproj  = (u16*)  alloc((size_t)N_EDGES*HID_*2);
  u16*   xbf    = (u16*)  alloc((size_t)N_NODES*F_NODE_*2);  // separate from eproj (no race)

  const size_t zlen = (size_t)((char*)(stats4 + 4*NSTRIPE*256) - (char*)counts);
  const int nscan = (N_NODES + 511)/512;

  WZ12 p;
  p.src[0] = Wl0; p.dst[0] = Wzl0; p.Ks[0] = F_NODE_; p.Kd[0] = F_NODE_;
  p.src[1] = Wr0; p.dst[1] = Wzr0; p.Ks[1] = F_NODE_; p.Kd[1] = F_NODE_;
  for (int i=0;i<3;i++){
    p.src[2+i] = Wl + (size_t)i*HID_*HID_; p.dst[2+i] = Wzl123 + (size_t)i*HID_*128; p.Ks[2+i] = HID_; p.Kd[2+i] = HID_;
    p.src[5+i] = Wr + (size_t)i*HID_*HID_; p.dst[5+i] = Wzr123 + (size_t)i*HID_*128; p.Ks[5+i] = HID_; p.Kd[5+i] = HID_;
  }
  p.src[8] = We0; p.dst[8] = Wez4; p.Ks[8] = F_EDGE_; p.Kd[8] = 32;
  for (int i=0;i<3;i++){
    p.src[9+i] = We + (size_t)i*F_EDGE_*HID_; p.dst[9+i] = Wez4 + (size_t)(i+1)*32*128; p.Ks[9+i] = F_EDGE_; p.Kd[9+i] = 32;
  }

  hipMemsetAsync(counts, 0, zlen, stream);
  hipLaunchKernelGGL(k_cast_hist, dim3(CAST_BLKS + EG256 + GOFF_BLKS + WSWZ_BLKS), dim3(256), 0, stream,
                     x, xbf, ei, counts, batch, goff, p);
  hipLaunchKernelGGL(k_scan1,  dim3(nscan), dim3(512), 0, stream, counts, incl, bsum);
  hipLaunchKernelGGL(k_scan3,  dim3(nscan), dim3(512), 0, stream, counts, incl, bsum, nscan, offsets, cursor);
  hipLaunchKernelGGL(k_scatter,dim3(EG256), dim3(256), 0, stream, ei, cursor, ssrc, ea, ea16);

  for (int layer = 0; layer < 4; layer++){
    const float *bl_, *br_, *att_, *g_, *b_;
    const u16 *Wzl_, *Wzr_, *Ain;
    int K;
    if (layer == 0){
      bl_=bl0; br_=br0; att_=att0; g_=g0; b_=b0;
      Wzl_ = Wzl0; Wzr_ = Wzr0; Ain = xbf; K = F_NODE_;
    } else {
      int i = layer - 1;
      bl_ = bl + (size_t)i*HID_;  br_ = br + (size_t)i*HID_;
      att_= att + (size_t)i*HID_;
      g_  = gg + (size_t)i*HID_;  b_  = bb + (size_t)i*HID_;
      Wzl_ = Wzl123 + (size_t)i*HID_*128;
      Wzr_ = Wzr123 + (size_t)i*HID_*128;
      Ain = h; K = HID_;
    }
    float* stats = stats4 + (size_t)layer*NSTRIPE*256;
    hipLaunchKernelGGL(k_gemm_eproj, dim3(2*GEMM_GRID + EPROJ_GRID), dim3(256), 0, stream,
                       Ain, Wzl_, Wzr_, bl_, br_, xl, (u16*)xr_aggr, N_NODES, K,
                       ea16, Wez4 + (size_t)layer*32*128, eproj);
    hipLaunchKernelGGL(k_gat_ep, dim3(GAT_GRID), dim3(128), 0, stream,
                       xl, xr_aggr, eproj, att_, offsets, ssrc, stats);
    hipLaunchKernelGGL(k_bn_apply, dim3((N_NODES*16 + 255)/256), dim3(256), 0, stream,
                       xr_aggr, stats, g_, b_, h, layer > 0 ? 1 : 0);
  }
  hipLaunchKernelGGL(k_pool_seg, dim3(N_GRAPH), dim3(256), 0, stream, (const unsigned*)h, goff, emb);
  hipLaunchKernelGGL(k_heads, dim3(N_GRAPH/HG, N_TASK), dim3(128), 0, stream, emb, mf, fpi, tw1, tb1, tw2, tb2, out);
}